// Round 8
// baseline (434.561 us; speedup 1.0000x reference)
//
#include <hip/hip_runtime.h>
#include <hip/hip_bf16.h>

#define DEV __device__ __forceinline__

typedef short bf16x8 __attribute__((ext_vector_type(8)));
typedef float f32x4 __attribute__((ext_vector_type(4)));
typedef unsigned short u16x4 __attribute__((ext_vector_type(4)));

static constexpr int Bsz = 4, Tt = 2048, Cch = 2048, Dd = 128, Ee = 16;
static constexpr int Nn = Bsz * Tt;
static constexpr int CAP = 1280;  // per-expert capacity (mean ~1024, sigma ~30 -> 8.5 sigma)
static constexpr int NSPLIT = 4;  // split-K partials for QKV gather
static constexpr size_t PHALF = (size_t)Ee * CAP * 384;  // elems per split-K partial (15.7MB)
static constexpr int MAXTILES = 320;  // >= 256 buckets + Nn/128

DEV unsigned short f2bf(float v) {
    __hip_bfloat16 h = __float2bfloat16(v);
    return __builtin_bit_cast(unsigned short, h);
}
DEV float bf2f(unsigned short u) {
    unsigned int x = ((unsigned int)u) << 16;
    return __builtin_bit_cast(float, x);
}

// ---------------- sim_matrix column norms ----------------
__global__ __launch_bounds__(256) void colnorm_kernel(const float* __restrict__ sim,
                                                      float* __restrict__ sninv) {
    int e = threadIdx.x & 15, j = threadIdx.x >> 4;
    float ss = 0.f;
    for (int r = j; r < Cch; r += 16) {
        float v = sim[r * Ee + e];
        ss += v * v;
    }
    __shared__ float red[16][17];
    red[j][e] = ss;
    __syncthreads();
    if (threadIdx.x < 16) {
        float s = 0.f;
        for (int t = 0; t < 16; t++) s += red[t][threadIdx.x];
        sninv[threadIdx.x] = 1.f / fmaxf(sqrtf(s), 1e-12f);
    }
}

// ---------------- sim transpose: simT[e][c] = sim[c][e] ----------------
__global__ __launch_bounds__(256) void simt_kernel(const float* __restrict__ sim,
                                                   float* __restrict__ simT) {
    int i = blockIdx.x * 256 + threadIdx.x;  // 16*2048
    int e = i >> 11, c = i & 2047;
    simT[i] = sim[c * 16 + e];
}

// ---------------- gating: 4 tokens per wave, register-tiled simT reuse ----------------
__global__ __launch_bounds__(256) void gating3_kernel(
    const float* __restrict__ x, const float* __restrict__ simT,
    const float* __restrict__ gates, const float* __restrict__ sninv,
    const int* __restrict__ minex,
    float* __restrict__ rw, unsigned short* __restrict__ xb,
    int* __restrict__ onmaskv) {
    const int wave = threadIdx.x >> 6, lane = threadIdx.x & 63;
    const int n0 = (blockIdx.x * 4 + wave) * 4;  // 4 tokens per wave
    const f32x4* st = (const f32x4*)simT;
    float ss[4] = {0.f, 0.f, 0.f, 0.f};
    float d[4][16];
#pragma unroll
    for (int t = 0; t < 4; t++)
#pragma unroll
        for (int e = 0; e < 16; e++) d[t][e] = 0.f;

#pragma unroll
    for (int it = 0; it < 8; it++) {
        const int i = it * 64 + lane;
        f32x4 xv[4];
#pragma unroll
        for (int t = 0; t < 4; t++) {
            xv[t] = ((const f32x4*)(x + (size_t)(n0 + t) * Cch))[i];
            ss[t] += xv[t][0] * xv[t][0] + xv[t][1] * xv[t][1] +
                     xv[t][2] * xv[t][2] + xv[t][3] * xv[t][3];
            u16x4 xc = {f2bf(xv[t][0]), f2bf(xv[t][1]), f2bf(xv[t][2]), f2bf(xv[t][3])};
            ((u16x4*)(xb + (size_t)(n0 + t) * Cch))[i] = xc;
        }
#pragma unroll
        for (int e = 0; e < 16; e++) {
            const f32x4 sv = st[e * 512 + i];
#pragma unroll
            for (int t = 0; t < 4; t++)
                d[t][e] += xv[t][0] * sv[0] + xv[t][1] * sv[1] +
                           xv[t][2] * sv[2] + xv[t][3] * sv[3];
        }
    }
#pragma unroll
    for (int off = 32; off; off >>= 1) {
#pragma unroll
        for (int t = 0; t < 4; t++) {
            ss[t] += __shfl_down(ss[t], off);
#pragma unroll
            for (int e = 0; e < 16; e++) d[t][e] += __shfl_down(d[t][e], off);
        }
    }
    if (lane == 0) {
#pragma unroll
        for (int t = 0; t < 4; t++) {
            const int n = n0 + t;
            float inv = 1.f / fmaxf(sqrtf(ss[t]), 1e-12f);
            float logit[16];
            int onmask = 0;
#pragma unroll
            for (int e = 0; e < 16; e++) {
                float sg = 1.f / (1.f + __expf(-gates[e]));
                float l = d[t][e] * inv * sninv[e] - sg;
                logit[e] = l;
                if (l > 0.f) onmask |= (1 << e);
            }
            if (onmask == 0) {
                int k = *minex;
                int ch = 0;
                for (int kk = 0; kk < k; kk++) {
                    float bv = -1e30f;
                    int be = 0;
#pragma unroll
                    for (int e = 0; e < 16; e++)
                        if (!((ch >> e) & 1) && logit[e] > bv) { bv = logit[e]; be = e; }
                    ch |= (1 << be);
                }
                onmask = ch;
            }
            float mx = -1e30f;
#pragma unroll
            for (int e = 0; e < 16; e++)
                if ((onmask >> e) & 1) mx = fmaxf(mx, fmaxf(logit[e], 0.f));
            float pe[16];
            float sum = 0.f;
#pragma unroll
            for (int e = 0; e < 16; e++) {
                pe[e] = ((onmask >> e) & 1) ? __expf(fmaxf(logit[e], 0.f) - mx) : 0.f;
                sum += pe[e];
            }
            float isum = 1.f / sum;
#pragma unroll
            for (int e = 0; e < 16; e++) rw[(size_t)n * 16 + e] = pe[e] * isum;
            onmaskv[n] = onmask;
        }
    }
}

// ---------------- deterministic expert-list scan (for QKV gather) ----------------
__global__ __launch_bounds__(256) void scan_kernel(
    const int* __restrict__ onmaskv,
    int* __restrict__ idx, int* __restrict__ pos, int* __restrict__ cnt) {
    const int e = blockIdx.x;
    const int tid = threadIdx.x;
    const int base = tid * 32;
    int om[32];
    int c = 0;
#pragma unroll
    for (int i = 0; i < 32; i++) {
        om[i] = (onmaskv[base + i] >> e) & 1;
        c += om[i];
    }
    const int lane = tid & 63, w = tid >> 6;
    int sc = c;
#pragma unroll
    for (int off = 1; off < 64; off <<= 1) {
        int t = __shfl_up(sc, off);
        if (lane >= off) sc += t;
    }
    __shared__ int wsum[4];
    if (lane == 63) wsum[w] = sc;
    __syncthreads();
    int wbase = 0;
    for (int i = 0; i < w; i++) wbase += wsum[i];
    int slot = wbase + sc - c;
#pragma unroll
    for (int i = 0; i < 32; i++) {
        int n = base + i;
        int p = -1;
        if (om[i]) {
            if (slot < CAP) {
                idx[(size_t)e * CAP + slot] = n;
                p = slot;
            }
            slot++;
        }
        pos[(size_t)n * 16 + e] = p;
    }
    if (tid == 255) cnt[e] = slot;
}

// ---------------- pair-bucket scan for output projection ----------------
__global__ __launch_bounds__(256) void scan_pair(
    const int* __restrict__ onmaskv,
    int* __restrict__ ptok, int4* __restrict__ tiledesc, int* __restrict__ ntile_dev,
    int* __restrict__ ocnt, int* __restrict__ olist) {
    __shared__ int hist[256], cursor[256];
    __shared__ int wsum[4], wsum2[4];
    const int tid = threadIdx.x;
    if (tid == 0) *ocnt = 0;
    hist[tid] = 0;
    __syncthreads();
    for (int i = 0; i < 32; i++) {
        int n = tid * 32 + i;
        int m = onmaskv[n];
        if (!m) m = 1;
        int e0 = __ffs(m) - 1;
        int m2 = m & (m - 1);
        int e1 = m2 ? (__ffs(m2) - 1) : e0;
        atomicAdd(&hist[e0 * 16 + e1], 1);
        int mrest = m2 & (m2 - 1);
        while (mrest) {
            int e = __ffs(mrest) - 1;
            int s = atomicAdd(ocnt, 1);
            olist[2 * s] = n;
            olist[2 * s + 1] = e;
            mrest &= (mrest - 1);
        }
    }
    __syncthreads();
    const int lane = tid & 63, w = tid >> 6;
    int v = hist[tid];
    int s = v;
#pragma unroll
    for (int off = 1; off < 64; off <<= 1) {
        int t = __shfl_up(s, off);
        if (lane >= off) s += t;
    }
    if (lane == 63) wsum[w] = s;
    __syncthreads();
    int add = 0;
    for (int i = 0; i < w; i++) add += wsum[i];
    int excl = s + add - v;
    cursor[tid] = excl;
    int nt = (v + 127) >> 7;
    int s2 = nt;
#pragma unroll
    for (int off = 1; off < 64; off <<= 1) {
        int t = __shfl_up(s2, off);
        if (lane >= off) s2 += t;
    }
    if (lane == 63) wsum2[w] = s2;
    __syncthreads();
    int add2 = 0;
    for (int i = 0; i < w; i++) add2 += wsum2[i];
    int texcl = s2 + add2 - nt;
    for (int m = 0; m < nt; m++)
        tiledesc[texcl + m] = make_int4(tid, excl + m * 128, min(128, v - m * 128), 0);
    if (tid == 255) *ntile_dev = texcl + nt;
    __syncthreads();
    for (int i = 0; i < 32; i++) {
        int n = tid * 32 + i;
        int m = onmaskv[n];
        if (!m) m = 1;
        int e0 = __ffs(m) - 1;
        int m2 = m & (m - 1);
        int e1 = m2 ? (__ffs(m2) - 1) : e0;
        int slot = atomicAdd(&cursor[e0 * 16 + e1], 1);
        ptok[slot] = n;
    }
}

// ---------------- transposes ----------------
__global__ __launch_bounds__(256) void transpose_f32_bf16(
    const float* __restrict__ src, unsigned short* __restrict__ dst,
    int R, int Ccol, long ss, long ds) {
    __shared__ float tile[32][33];
    src += (size_t)blockIdx.z * ss;
    dst += (size_t)blockIdx.z * ds;
    int bx = blockIdx.x * 32, by = blockIdx.y * 32;
    int tx = threadIdx.x & 31, ty = threadIdx.x >> 5;
#pragma unroll
    for (int i = 0; i < 4; i++)
        tile[ty + i * 8][tx] = src[(size_t)(by + ty + i * 8) * Ccol + bx + tx];
    __syncthreads();
#pragma unroll
    for (int i = 0; i < 4; i++)
        dst[(size_t)(bx + ty + i * 8) * R + by + tx] = f2bf(tile[tx][ty + i * 8]);
}

__global__ __launch_bounds__(256) void transpose_u16(
    const unsigned short* __restrict__ src, unsigned short* __restrict__ dst,
    int R, int Ccol, long ss, long ds) {
    __shared__ unsigned short tile[32][33];
    src += (size_t)blockIdx.z * ss;
    dst += (size_t)blockIdx.z * ds;
    int bx = blockIdx.x * 32, by = blockIdx.y * 32;
    int tx = threadIdx.x & 31, ty = threadIdx.x >> 5;
#pragma unroll
    for (int i = 0; i < 4; i++)
        tile[ty + i * 8][tx] = src[(size_t)(by + ty + i * 8) * Ccol + bx + tx];
    __syncthreads();
#pragma unroll
    for (int i = 0; i < 4; i++)
        dst[(size_t)(bx + ty + i * 8) * R + by + tx] = tile[tx][ty + i * 8];
}

// ---------------- NT GEMM: Out[M,N] = A[M,K] * BT[N,K]^T (bf16 in, f32 out) ----------------
template <int CAUSAL>
__global__ __launch_bounds__(256) void gemm_nt(
    const unsigned short* __restrict__ A, long strideA, int lda,
    const unsigned short* __restrict__ BT, long strideB, int ldb,
    float* __restrict__ Out, long strideO, int ldo,
    int K, float scale) {
    __shared__ alignas(16) unsigned short As[128 * 64];
    __shared__ alignas(16) unsigned short Bs[128 * 64];
    const int bm = blockIdx.x * 128;
    const int bn = blockIdx.y * 128;
    if (CAUSAL && bn > bm + 127) return;
    A += (size_t)blockIdx.z * strideA;
    BT += (size_t)blockIdx.z * strideB;
    Out += (size_t)blockIdx.z * strideO;
    const int tid = threadIdx.x;
    const int wave = tid >> 6, lane = tid & 63;
    const int lr = lane & 15, lg = lane >> 4;
    const int wr = (wave >> 1) * 64, wc = (wave & 1) * 64;
    f32x4 acc[4][4] = {};

    for (int k0 = 0; k0 < K; k0 += 64) {
        __syncthreads();
#pragma unroll
        for (int i = 0; i < 4; i++) {
            int t = i * 256 + tid;
            int row = t >> 3;
            int kc = (t & 7) << 3;
            __builtin_amdgcn_global_load_lds(
                (const __attribute__((address_space(1))) void*)(A + (size_t)(bm + row) * lda + k0 + kc),
                (__attribute__((address_space(3))) void*)(As + (i * 4 + wave) * 512),
                16, 0, 0);
        }
#pragma unroll
        for (int i = 0; i < 4; i++) {
            int t = i * 256 + tid;
            int row = t >> 3;
            int kc = (t & 7) << 3;
            __builtin_amdgcn_global_load_lds(
                (const __attribute__((address_space(1))) void*)(BT + (size_t)(bn + row) * ldb + k0 + kc),
                (__attribute__((address_space(3))) void*)(Bs + (i * 4 + wave) * 512),
                16, 0, 0);
        }
        __syncthreads();
#pragma unroll
        for (int kk = 0; kk < 2; kk++) {
            bf16x8 a[4], b[4];
#pragma unroll
            for (int m = 0; m < 4; m++)
                a[m] = *(const bf16x8*)(As + (wr + m * 16 + lr) * 64 + kk * 32 + lg * 8);
#pragma unroll
            for (int n = 0; n < 4; n++)
                b[n] = *(const bf16x8*)(Bs + (wc + n * 16 + lr) * 64 + kk * 32 + lg * 8);
#pragma unroll
            for (int m = 0; m < 4; m++)
#pragma unroll
                for (int n = 0; n < 4; n++)
                    acc[m][n] = __builtin_amdgcn_mfma_f32_16x16x32_bf16(a[m], b[n], acc[m][n], 0, 0, 0);
        }
    }
#pragma unroll
    for (int m = 0; m < 4; m++) {
#pragma unroll
        for (int n = 0; n < 4; n++) {
#pragma unroll
            for (int r = 0; r < 4; r++) {
                int grow = bm + wr + m * 16 + lg * 4 + r;
                int gcol = bn + wc + n * 16 + lr;
                if (!CAUSAL || gcol <= grow)
                    Out[(size_t)grow * ldo + gcol] = acc[m][n][r] * scale;
            }
        }
    }
}

// ---------------- PV GEMM: split-K over causal-active chunks, atomic f32 accumulate ----------------
__global__ __launch_bounds__(256) void gemm_pv(
    const unsigned short* __restrict__ P, const unsigned short* __restrict__ vT,
    float* __restrict__ ob) {
    const int bm = blockIdx.x * 128;
    const int kb = blockIdx.y * 512;
    if (kb > bm + 127) return;
    const unsigned short* Pb = P + (size_t)blockIdx.z * Tt * 4096;
    const unsigned short* Vb = vT + (size_t)blockIdx.z * Dd * Tt;
    float* Ob = ob + (size_t)blockIdx.z * Tt * Dd;
    __shared__ alignas(16) unsigned short As[128 * 64];
    __shared__ alignas(16) unsigned short Bs[128 * 64];
    const int tid = threadIdx.x;
    const int wave = tid >> 6, lane = tid & 63;
    const int lr = lane & 15, lg = lane >> 4;
    const int wr = (wave >> 1) * 64, wc = (wave & 1) * 64;
    f32x4 acc[4][4] = {};

    for (int k0 = kb; k0 < kb + 512; k0 += 64) {
        __syncthreads();
#pragma unroll
        for (int i = 0; i < 4; i++) {
            int t = i * 256 + tid;
            int row = t >> 3;
            int kc = (t & 7) << 3;
            __builtin_amdgcn_global_load_lds(
                (const __attribute__((address_space(1))) void*)(Pb + (size_t)(bm + row) * 4096 + k0 + kc),
                (__attribute__((address_space(3))) void*)(As + (i * 4 + wave) * 512),
                16, 0, 0);
        }
#pragma unroll
        for (int i = 0; i < 4; i++) {
            int t = i * 256 + tid;
            int row = t >> 3;
            int kc = (t & 7) << 3;
            __builtin_amdgcn_global_load_lds(
                (const __attribute__((address_space(1))) void*)(Vb + (size_t)row * Tt + k0 + kc),
                (__attribute__((address_space(3))) void*)(Bs + (i * 4 + wave) * 512),
                16, 0, 0);
        }
        __syncthreads();
#pragma unroll
        for (int kk = 0; kk < 2; kk++) {
            bf16x8 a[4], b[4];
#pragma unroll
            for (int m = 0; m < 4; m++)
                a[m] = *(const bf16x8*)(As + (wr + m * 16 + lr) * 64 + kk * 32 + lg * 8);
#pragma unroll
            for (int n = 0; n < 4; n++)
                b[n] = *(const bf16x8*)(Bs + (wc + n * 16 + lr) * 64 + kk * 32 + lg * 8);
#pragma unroll
            for (int m = 0; m < 4; m++)
#pragma unroll
                for (int n = 0; n < 4; n++)
                    acc[m][n] = __builtin_amdgcn_mfma_f32_16x16x32_bf16(a[m], b[n], acc[m][n], 0, 0, 0);
        }
    }
#pragma unroll
    for (int m = 0; m < 4; m++)
#pragma unroll
        for (int n = 0; n < 4; n++)
#pragma unroll
            for (int r = 0; r < 4; r++) {
                int grow = bm + wr + m * 16 + lg * 4 + r;
                int gcol = wc + n * 16 + lr;
                atomicAdd(&Ob[(size_t)grow * Dd + gcol], acc[m][n][r]);
            }
}

// ---------------- gathered QKV projection, split-K=4 into bf16 partials ----------------
__global__ __launch_bounds__(256) void gemm_qkv_gather(
    const unsigned short* __restrict__ X, const unsigned short* __restrict__ W,
    const int* __restrict__ idx, const int* __restrict__ cnt,
    unsigned short* __restrict__ P) {
    const int z = blockIdx.z;  // e*NSPLIT + kchunk
    const int e = z >> 2, kc4 = z & 3;
    const int cn = min(cnt[e], CAP);
    const int bm = blockIdx.x * 128;
    if (bm >= cn) return;
    const int bn = blockIdx.y * 128;
    unsigned short* Ph = P + (size_t)kc4 * PHALF;
    __shared__ alignas(16) unsigned short As[128 * 64];
    __shared__ alignas(16) unsigned short Bs[128 * 64];
    __shared__ int toks[128];
    const int tid = threadIdx.x;
    if (tid < 128) toks[tid] = idx[(size_t)e * CAP + min(bm + tid, cn - 1)];
    const unsigned short* Wb = W + ((size_t)e * 384 + bn) * Cch;
    const int wave = tid >> 6, lane = tid & 63;
    const int lr = lane & 15, lg = lane >> 4;
    const int wr = (wave >> 1) * 64, wc = (wave & 1) * 64;
    f32x4 acc[4][4] = {};

    for (int k0 = kc4 * 512; k0 < kc4 * 512 + 512; k0 += 64) {
        __syncthreads();
#pragma unroll
        for (int i = 0; i < 4; i++) {
            int t = i * 256 + tid;
            int row = t >> 3;
            int kc = (t & 7) << 3;
            __builtin_amdgcn_global_load_lds(
                (const __attribute__((address_space(1))) void*)(X + (size_t)toks[row] * Cch + k0 + kc),
                (__attribute__((address_space(3))) void*)(As + (i * 4 + wave) * 512),
                16, 0, 0);
        }
#pragma unroll
        for (int i = 0; i < 4; i++) {
            int t = i * 256 + tid;
            int row = t >> 3;
            int kc = (t & 7) << 3;
            __builtin_amdgcn_global_load_lds(
                (const __attribute__((address_space(1))) void*)(Wb + (size_t)row * Cch + k0 + kc),
                (__attribute__((address_space(3))) void*)(Bs + (i * 4 + wave) * 512),
                16, 0, 0);
        }
        __syncthreads();
#pragma unroll
        for (int kk = 0; kk < 2; kk++) {
            bf16x8 a[4], b[4];
#pragma unroll
            for (int m = 0; m < 4; m++)
                a[m] = *(const bf16x8*)(As + (wr + m * 16 + lr) * 64 + kk * 32 + lg * 8);
#pragma unroll
            for (int n = 0; n < 4; n++)
                b[n] = *(const bf16x8*)(Bs + (wc + n * 16 + lr) * 64 + kk * 32 + lg * 8);
#pragma unroll
            for (int m = 0; m < 4; m++)
#pragma unroll
                for (int n = 0; n < 4; n++)
                    acc[m][n] = __builtin_amdgcn_mfma_f32_16x16x32_bf16(a[m], b[n], acc[m][n], 0, 0, 0);
        }
    }
#pragma unroll
    for (int m = 0; m < 4; m++)
#pragma unroll
        for (int n = 0; n < 4; n++)
#pragma unroll
            for (int r = 0; r < 4; r++) {
                int slot = bm + wr + m * 16 + lg * 4 + r;
                int col = bn + wc + n * 16 + lr;
                if (slot < cn)
                    Ph[((size_t)e * CAP + slot) * 384 + col] = f2bf(acc[m][n][r]);
            }
}

// ---------------- combine q/k/v from NSPLIT split-K partials ----------------
__global__ __launch_bounds__(256) void combine_qkv(
    const unsigned short* __restrict__ P, const float* __restrict__ rw,
    const int* __restrict__ pos,
    unsigned short* __restrict__ qb, unsigned short* __restrict__ kb,
    unsigned short* __restrict__ vb) {
    int i = blockIdx.x * 256 + threadIdx.x;
    int n = i >> 5;
    int d4 = (i & 31) << 2;
    float aq[4] = {}, ak[4] = {}, av[4] = {};
#pragma unroll
    for (int e = 0; e < 16; e++) {
        int p = pos[(size_t)n * 16 + e];
        if (p >= 0) {
            float w = rw[(size_t)n * 16 + e];
            const unsigned short* r0 = P + ((size_t)e * CAP + p) * 384 + d4;
#pragma unroll
            for (int h = 0; h < NSPLIT; h++) {
                const unsigned short* rh = r0 + (size_t)h * PHALF;
                const u16x4 q4 = *(const u16x4*)(rh);
                const u16x4 k4 = *(const u16x4*)(rh + 128);
                const u16x4 v4 = *(const u16x4*)(rh + 256);
#pragma unroll
                for (int j = 0; j < 4; j++) {
                    aq[j] += w * bf2f(q4[j]);
                    ak[j] += w * bf2f(k4[j]);
                    av[j] += w * bf2f(v4[j]);
                }
            }
        }
    }
    u16x4 sq = {f2bf(aq[0]), f2bf(aq[1]), f2bf(aq[2]), f2bf(aq[3])};
    u16x4 sk = {f2bf(ak[0]), f2bf(ak[1]), f2bf(ak[2]), f2bf(ak[3])};
    u16x4 sv = {f2bf(av[0]), f2bf(av[1]), f2bf(av[2]), f2bf(av[3])};
    *(u16x4*)(qb + (size_t)n * Dd + d4) = sq;
    *(u16x4*)(kb + (size_t)n * Dd + d4) = sk;
    *(u16x4*)(vb + (size_t)n * Dd + d4) = sv;
}

// ---------------- causal row softmax, in-place f32 -> bf16 ----------------
__global__ __launch_bounds__(256) void softmax_kernel(float* __restrict__ scores) {
    int i = blockIdx.x, b = blockIdx.y;
    float* row = scores + ((size_t)b * Tt + i) * Tt;
    int nv = i + 1;
    float v[8];
    int cnt = 0;
    float mx = -1e30f;
    for (int j = threadIdx.x; j < nv; j += 256) {
        float t = row[j];
        v[cnt++] = t;
        mx = fmaxf(mx, t);
    }
    __shared__ float sred[4];
    int w = threadIdx.x >> 6;
#pragma unroll
    for (int off = 32; off; off >>= 1) mx = fmaxf(mx, __shfl_down(mx, off));
    if ((threadIdx.x & 63) == 0) sred[w] = mx;
    __syncthreads();
    float m = fmaxf(fmaxf(sred[0], sred[1]), fmaxf(sred[2], sred[3]));
    float s = 0.f;
    for (int t = 0; t < cnt; t++) {
        v[t] = __expf(v[t] - m);
        s += v[t];
    }
    __syncthreads();
#pragma unroll
    for (int off = 32; off; off >>= 1) s += __shfl_down(s, off);
    if ((threadIdx.x & 63) == 0) sred[w] = s;
    __syncthreads();
    float inv = 1.f / (sred[0] + sred[1] + sred[2] + sred[3]);
    unsigned short* prow = (unsigned short*)row;
    cnt = 0;
    for (int j = threadIdx.x; j < Tt; j += 256) {
        float pv = 0.f;
        if (j < nv) pv = v[cnt++] * inv;
        prow[j] = f2bf(pv);
    }
}

// ---------------- og2[n][256] = [rw_e0 * o | rw_e1 * o] (bf16) ----------------
__global__ __launch_bounds__(256) void og2_kernel(
    const float* __restrict__ ob, const float* __restrict__ rw,
    const int* __restrict__ onmaskv, unsigned short* __restrict__ og2) {
    int idx = blockIdx.x * 256 + threadIdx.x;  // (n, k4-group of 4)
    int n = idx >> 6;
    int k4 = (idx & 63) << 2;
    int m = onmaskv[n];
    if (!m) m = 1;
    int e0 = __ffs(m) - 1;
    int m2 = m & (m - 1);
    bool has2 = m2 != 0;
    int e1 = has2 ? (__ffs(m2) - 1) : e0;
    float wgt;
    int kb;
    if (k4 < 128) { wgt = rw[(size_t)n * 16 + e0]; kb = k4; }
    else { wgt = has2 ? rw[(size_t)n * 16 + e1] : 0.f; kb = k4 - 128; }
    const f32x4 o4 = *(const f32x4*)(ob + (size_t)n * Dd + kb);
    u16x4 st = {f2bf(wgt * o4[0]), f2bf(wgt * o4[1]), f2bf(wgt * o4[2]), f2bf(wgt * o4[3])};
    *(u16x4*)(og2 + (size_t)n * 256 + k4) = st;
}

// ---------------- pair-bucket output GEMM: out row written exactly once ----------------
__global__ __launch_bounds__(256) void gemm_pair(
    const unsigned short* __restrict__ og2,   // [Nn][256] bf16
    const unsigned short* __restrict__ woT,   // [2048 c][E*128] bf16
    const int* __restrict__ ptok, const int4* __restrict__ tiledesc,
    const int* __restrict__ ntile_dev,
    float* __restrict__ out) {
    if (blockIdx.x >= *ntile_dev) return;
    const int4 td = tiledesc[blockIdx.x];
    const int ei = td.x >> 4, ej = td.x & 15;
    const int mstart = td.y, mcnt = td.z;
    const int bn = blockIdx.y * 128;
    __shared__ alignas(16) unsigned short As[128 * 64];
    __shared__ alignas(16) unsigned short Bs[128 * 64];
    __shared__ int toks[128];
    const int tid = threadIdx.x;
    if (tid < 128) toks[tid] = ptok[mstart + min(tid, mcnt - 1)];
    const int wave = tid >> 6, lane = tid & 63;
    const int lr = lane & 15, lg = lane >> 4;
    const int wr = (wave >> 1) * 64, wc = (wave & 1) * 64;
    f32x4 acc[4][4] = {};

#pragma unroll
    for (int ck = 0; ck < 4; ck++) {
        const int ebase = (ck < 2 ? ei : ej) * 128 + (ck & 1) * 64;
        const int abase = ck * 64;
        __syncthreads();  // first iter: also guards toks
#pragma unroll
        for (int q = 0; q < 4; q++) {
            int t = q * 256 + tid;
            int row = t >> 3;
            int kc = (t & 7) << 3;
            __builtin_amdgcn_global_load_lds(
                (const __attribute__((address_space(1))) void*)(og2 + (size_t)toks[row] * 256 + abase + kc),
                (__attribute__((address_space(3))) void*)(As + (q * 4 + wave) * 512),
                16, 0, 0);
        }
#pragma unroll
        for (int q = 0; q < 4; q++) {
            int t = q * 256 + tid;
            int row = t >> 3;
            int kc = (t & 7) << 3;
            __builtin_amdgcn_global_load_lds(
                (const __attribute__((address_space(1))) void*)(woT + (size_t)(bn + row) * 2048 + ebase + kc),
                (__attribute__((address_space(3))) void*)(Bs + (q * 4 + wave) * 512),
                16, 0, 0);
        }
        __syncthreads();
#pragma unroll
        for (int kk = 0; kk < 2; kk++) {
            bf16x8 a[4], b[4];
#pragma unroll
            for (int m = 0; m < 4; m++)
                a[m] = *(const bf16x8*)(As + (wr + m * 16 + lr) * 64 + kk * 32 + lg * 8);
#pragma unroll
            for (int n = 0; n < 4; n++)
                b[n] = *(const bf16x8*)(Bs + (wc + n * 16 + lr) * 64 + kk * 32 + lg * 8);
#pragma unroll
            for (int m = 0; m < 4; m++)
#pragma unroll
                for (int n = 0; n < 4; n++)
                    acc[m][n] = __builtin_amdgcn_mfma_f32_16x16x32_bf16(a[m], b[n], acc[m][n], 0, 0, 0);
        }
    }
#pragma unroll
    for (int m = 0; m < 4; m++)
#pragma unroll
        for (int n = 0; n < 4; n++)
#pragma unroll
            for (int r = 0; r < 4; r++) {
                int rowt = wr + m * 16 + lg * 4 + r;
                if (rowt < mcnt) {
                    int tok = toks[rowt];
                    out[(size_t)tok * 2048 + bn + wc + n * 16 + lr] = acc[m][n][r];
                }
            }
}

// ---------------- rare overflow path: experts beyond the first two (empty here) ----------------
__global__ __launch_bounds__(256) void overflow_kernel(
    const int* __restrict__ ocnt, const int* __restrict__ olist,
    const float* __restrict__ ob, const unsigned short* __restrict__ woT,
    const float* __restrict__ rw, float* __restrict__ out) {
    const int ne = *ocnt;
    __shared__ float osh[128];
    for (int it = blockIdx.x; it < ne; it += gridDim.x) {
        int n = olist[2 * it], e = olist[2 * it + 1];
        float wgt = rw[(size_t)n * 16 + e];
        if (threadIdx.x < 128) osh[threadIdx.x] = ob[(size_t)n * Dd + threadIdx.x];
        __syncthreads();
#pragma unroll 1
        for (int cc = 0; cc < 8; cc++) {
            int c = threadIdx.x * 8 + cc;
            float a = 0.f;
            for (int k = 0; k < 128; k++)
                a += osh[k] * bf2f(woT[(size_t)c * 2048 + e * 128 + k]);
            atomicAdd(&out[(size_t)n * 2048 + c], wgt * a);
        }
        __syncthreads();
    }
}

extern "C" void kernel_launch(void* const* d_in, const int* in_sizes, int n_in,
                              void* d_out, int out_size, void* d_ws, size_t ws_size,
                              hipStream_t stream) {
    (void)in_sizes; (void)n_in; (void)out_size; (void)ws_size;
    const float* hidden = (const float*)d_in[0];
    const float* sim = (const float*)d_in[1];
    const float* gates = (const float*)d_in[2];
    const float* qp = (const float*)d_in[3];
    const float* kp = (const float*)d_in[4];
    const float* vp = (const float*)d_in[5];
    const float* op = (const float*)d_in[6];
    const int* minex = (const int*)d_in[7];
    float* out = (float*)d_out;

    char* w = (char*)d_ws;
    size_t off = 0;
    auto alloc = [&](size_t bytes) -> char* {
        char* p = w + off;
        off = (off + bytes + 255) & ~(size_t)255;
        return p;
    };
    unsigned short* xb = (unsigned short*)alloc((size_t)Nn * Cch * 2);
    unsigned short* wqkvT = (unsigned short*)alloc((size_t)Ee * 384 * Cch * 2);
    unsigned short* woT = (unsigned short*)alloc((size_t)Cch * Ee * Dd * 2);
    float* rw = (float*)alloc((size_t)Nn * Ee * 4);
    float* sninv = (float*)alloc(256);
    float* simT = (float*)alloc((size_t)Ee * Cch * 4);
    int* cnt = (int*)alloc(256);
    int* onmaskv = (int*)alloc((size_t)Nn * 4);
    int* idx = (int*)alloc((size_t)Ee * CAP * 4);
    int* pos = (int*)alloc((size_t)Nn * 16 * 4);
    int* ptok = (int*)alloc((size_t)Nn * 4);
    int4* tiledesc = (int4*)alloc((size_t)MAXTILES * 16);
    int* ntile_dev = (int*)alloc(256);
    int* ocnt = (int*)alloc(256);
    int* olist = (int*)alloc((size_t)Nn * 14 * 2 * 4);
    char* big = alloc((size_t)Bsz * Tt * Tt * 4);  // P partials (63MB) / scores (67MB)
    unsigned short* qb = (unsigned short*)alloc((size_t)Nn * Dd * 2);
    unsigned short* kb = (unsigned short*)alloc((size_t)Nn * Dd * 2);
    unsigned short* vb = (unsigned short*)alloc((size_t)Nn * Dd * 2);
    unsigned short* vT = (unsigned short*)alloc((size_t)Bsz * Dd * Tt * 2);
    float* ob = (float*)alloc((size_t)Nn * Dd * 4);
    unsigned short* og2 = (unsigned short*)alloc((size_t)Nn * 256 * 2);
    unsigned short* Pc = (unsigned short*)big;
    float* scores = (float*)big;

    const float scale = 0.08838834764831845f;  // 1/sqrt(128)

    colnorm_kernel<<<1, 256, 0, stream>>>(sim, sninv);
    simt_kernel<<<(Ee * Cch) / 256, 256, 0, stream>>>(sim, simT);
    gating3_kernel<<<Nn / 16, 256, 0, stream>>>(hidden, simT, gates, sninv, minex, rw, xb, onmaskv);
    scan_kernel<<<Ee, 256, 0, stream>>>(onmaskv, idx, pos, cnt);
    scan_pair<<<1, 256, 0, stream>>>(onmaskv, ptok, tiledesc, ntile_dev, ocnt, olist);
    hipMemsetAsync(ob, 0, (size_t)Nn * Dd * 4, stream);

    // weight transposes (f32 -> bf16) into fused [E][384][C]
    transpose_f32_bf16<<<dim3(Dd / 32, Cch / 32, Ee), 256, 0, stream>>>(
        qp, wqkvT + 0 * Dd * Cch, Cch, Dd, (long)Cch * Dd, (long)384 * Cch);
    transpose_f32_bf16<<<dim3(Dd / 32, Cch / 32, Ee), 256, 0, stream>>>(
        kp, wqkvT + 1 * Dd * Cch, Cch, Dd, (long)Cch * Dd, (long)384 * Cch);
    transpose_f32_bf16<<<dim3(Dd / 32, Cch / 32, Ee), 256, 0, stream>>>(
        vp, wqkvT + 2 * Dd * Cch, Cch, Dd, (long)Cch * Dd, (long)384 * Cch);
    transpose_f32_bf16<<<dim3((Ee * Dd) / 32, Cch / 32, 1), 256, 0, stream>>>(
        op, woT, Ee * Dd, Cch, 0L, 0L);

    // gathered per-expert QKV projection (split-K=4), then combine
    gemm_qkv_gather<<<dim3(CAP / 128, 3, Ee * NSPLIT), 256, 0, stream>>>(xb, wqkvT, idx, cnt, Pc);
    combine_qkv<<<(Nn * 32) / 256, 256, 0, stream>>>(Pc, rw, pos, qb, kb, vb);

    // V transpose per batch
    transpose_u16<<<dim3(Dd / 32, Tt / 32, Bsz), 256, 0, stream>>>(
        vb, vT, Tt, Dd, (long)Tt * Dd, (long)Dd * Tt);

    // scores = Q K^T * scale (causal)
    gemm_nt<1><<<dim3(Tt / 128, Tt / 128, Bsz), 256, 0, stream>>>(
        qb, (long)Tt * Dd, Dd, kb, (long)Tt * Dd, Dd, scores, (long)Tt * Tt, Tt, Dd, scale);
    softmax_kernel<<<dim3(Tt, Bsz), 256, 0, stream>>>(scores);
    // O = P V  — split-K over causal-active 512-chunks, atomic accumulate
    gemm_pv<<<dim3(Tt / 128, Tt / 512, Bsz), 256, 0, stream>>>(
        (const unsigned short*)scores, vT, ob);

    // output projection: pair-bucket grouped GEMM, each out row stored exactly once
    og2_kernel<<<(Nn * 64) / 256, 256, 0, stream>>>(ob, rw, onmaskv, og2);
    gemm_pair<<<dim3(MAXTILES, Cch / 128), 256, 0, stream>>>(
        og2, woT, ptok, tiledesc, ntile_dev, out);
    overflow_kernel<<<256, 256, 0, stream>>>(ocnt, olist, ob, woT, rw, out);
}

// Round 9
// 419.103 us; speedup vs baseline: 1.0369x; 1.0369x over previous
//
#include <hip/hip_runtime.h>
#include <hip/hip_bf16.h>

#define DEV __device__ __forceinline__

typedef short bf16x8 __attribute__((ext_vector_type(8)));
typedef float f32x4 __attribute__((ext_vector_type(4)));
typedef unsigned short u16x4 __attribute__((ext_vector_type(4)));

static constexpr int Bsz = 4, Tt = 2048, Cch = 2048, Dd = 128, Ee = 16;
static constexpr int Nn = Bsz * Tt;
static constexpr int CAP = 1280;  // per-expert capacity (mean ~1024, sigma ~30 -> 8.5 sigma)
static constexpr int NSPLIT = 4;  // split-K partials for QKV gather
static constexpr size_t PHALF = (size_t)Ee * CAP * 384;  // elems per split-K partial (15.7MB)
static constexpr int MAXTILES = 320;  // >= 256 buckets + Nn/128

DEV unsigned short f2bf(float v) {
    __hip_bfloat16 h = __float2bfloat16(v);
    return __builtin_bit_cast(unsigned short, h);
}
DEV float bf2f(unsigned short u) {
    unsigned int x = ((unsigned int)u) << 16;
    return __builtin_bit_cast(float, x);
}

// ---------------- sim_matrix column norms ----------------
__global__ __launch_bounds__(256) void colnorm_kernel(const float* __restrict__ sim,
                                                      float* __restrict__ sninv) {
    int e = threadIdx.x & 15, j = threadIdx.x >> 4;
    float ss = 0.f;
    for (int r = j; r < Cch; r += 16) {
        float v = sim[r * Ee + e];
        ss += v * v;
    }
    __shared__ float red[16][17];
    red[j][e] = ss;
    __syncthreads();
    if (threadIdx.x < 16) {
        float s = 0.f;
        for (int t = 0; t < 16; t++) s += red[t][threadIdx.x];
        sninv[threadIdx.x] = 1.f / fmaxf(sqrtf(s), 1e-12f);
    }
}

// ---------------- sim transpose: simT[e][c] = sim[c][e] ----------------
__global__ __launch_bounds__(256) void simt_kernel(const float* __restrict__ sim,
                                                   float* __restrict__ simT) {
    int i = blockIdx.x * 256 + threadIdx.x;  // 16*2048
    int e = i >> 11, c = i & 2047;
    simT[i] = sim[c * 16 + e];
}

// ---------------- gating: simT staged in 128 KiB LDS; 2 tokens per wave register tile ----------------
__global__ __launch_bounds__(256) void gating4_kernel(
    const float* __restrict__ x, const float* __restrict__ simT,
    const float* __restrict__ gates, const float* __restrict__ sninv,
    const int* __restrict__ minex,
    float* __restrict__ rw, unsigned short* __restrict__ xb,
    int* __restrict__ onmaskv) {
    __shared__ f32x4 ssim[8192];  // 128 KiB = full simT in f32
    const int tid = threadIdx.x;
    const f32x4* stg = (const f32x4*)simT;
    for (int i = tid; i < 8192; i += 256) ssim[i] = stg[i];
    __syncthreads();
    const int wave = tid >> 6, lane = tid & 63;

#pragma unroll 1
    for (int g = 0; g < 4; g++) {
        const int n0 = blockIdx.x * 32 + wave * 8 + g * 2;
        float ss[2] = {0.f, 0.f};
        float d[2][16];
#pragma unroll
        for (int t = 0; t < 2; t++)
#pragma unroll
            for (int e = 0; e < 16; e++) d[t][e] = 0.f;

#pragma unroll
        for (int it = 0; it < 8; it++) {
            const int i = it * 64 + lane;
            f32x4 xv[2];
#pragma unroll
            for (int t = 0; t < 2; t++) {
                xv[t] = ((const f32x4*)(x + (size_t)(n0 + t) * Cch))[i];
                ss[t] += xv[t][0] * xv[t][0] + xv[t][1] * xv[t][1] +
                         xv[t][2] * xv[t][2] + xv[t][3] * xv[t][3];
                u16x4 xc = {f2bf(xv[t][0]), f2bf(xv[t][1]), f2bf(xv[t][2]), f2bf(xv[t][3])};
                ((u16x4*)(xb + (size_t)(n0 + t) * Cch))[i] = xc;
            }
#pragma unroll
            for (int e = 0; e < 16; e++) {
                const f32x4 sv = ssim[e * 512 + i];
                d[0][e] += xv[0][0] * sv[0] + xv[0][1] * sv[1] +
                           xv[0][2] * sv[2] + xv[0][3] * sv[3];
                d[1][e] += xv[1][0] * sv[0] + xv[1][1] * sv[1] +
                           xv[1][2] * sv[2] + xv[1][3] * sv[3];
            }
        }
#pragma unroll
        for (int off = 32; off; off >>= 1) {
#pragma unroll
            for (int t = 0; t < 2; t++) {
                ss[t] += __shfl_down(ss[t], off);
#pragma unroll
                for (int e = 0; e < 16; e++) d[t][e] += __shfl_down(d[t][e], off);
            }
        }
        if (lane == 0) {
#pragma unroll
            for (int t = 0; t < 2; t++) {
                const int n = n0 + t;
                float inv = 1.f / fmaxf(sqrtf(ss[t]), 1e-12f);
                float logit[16];
                int onmask = 0;
#pragma unroll
                for (int e = 0; e < 16; e++) {
                    float sg = 1.f / (1.f + __expf(-gates[e]));
                    float l = d[t][e] * inv * sninv[e] - sg;
                    logit[e] = l;
                    if (l > 0.f) onmask |= (1 << e);
                }
                if (onmask == 0) {
                    int k = *minex;
                    int ch = 0;
                    for (int kk = 0; kk < k; kk++) {
                        float bv = -1e30f;
                        int be = 0;
#pragma unroll
                        for (int e = 0; e < 16; e++)
                            if (!((ch >> e) & 1) && logit[e] > bv) { bv = logit[e]; be = e; }
                        ch |= (1 << be);
                    }
                    onmask = ch;
                }
                float mx = -1e30f;
#pragma unroll
                for (int e = 0; e < 16; e++)
                    if ((onmask >> e) & 1) mx = fmaxf(mx, fmaxf(logit[e], 0.f));
                float pe[16];
                float sum = 0.f;
#pragma unroll
                for (int e = 0; e < 16; e++) {
                    pe[e] = ((onmask >> e) & 1) ? __expf(fmaxf(logit[e], 0.f) - mx) : 0.f;
                    sum += pe[e];
                }
                float isum = 1.f / sum;
#pragma unroll
                for (int e = 0; e < 16; e++) rw[(size_t)n * 16 + e] = pe[e] * isum;
                onmaskv[n] = onmask;
            }
        }
    }
}

// ---------------- deterministic expert-list scan (for QKV gather) ----------------
__global__ __launch_bounds__(256) void scan_kernel(
    const int* __restrict__ onmaskv,
    int* __restrict__ idx, int* __restrict__ pos, int* __restrict__ cnt) {
    const int e = blockIdx.x;
    const int tid = threadIdx.x;
    const int base = tid * 32;
    int om[32];
    int c = 0;
#pragma unroll
    for (int i = 0; i < 32; i++) {
        om[i] = (onmaskv[base + i] >> e) & 1;
        c += om[i];
    }
    const int lane = tid & 63, w = tid >> 6;
    int sc = c;
#pragma unroll
    for (int off = 1; off < 64; off <<= 1) {
        int t = __shfl_up(sc, off);
        if (lane >= off) sc += t;
    }
    __shared__ int wsum[4];
    if (lane == 63) wsum[w] = sc;
    __syncthreads();
    int wbase = 0;
    for (int i = 0; i < w; i++) wbase += wsum[i];
    int slot = wbase + sc - c;
#pragma unroll
    for (int i = 0; i < 32; i++) {
        int n = base + i;
        int p = -1;
        if (om[i]) {
            if (slot < CAP) {
                idx[(size_t)e * CAP + slot] = n;
                p = slot;
            }
            slot++;
        }
        pos[(size_t)n * 16 + e] = p;
    }
    if (tid == 255) cnt[e] = slot;
}

// ---------------- pair-bucket scan for output projection ----------------
__global__ __launch_bounds__(256) void scan_pair(
    const int* __restrict__ onmaskv,
    int* __restrict__ ptok, int4* __restrict__ tiledesc, int* __restrict__ ntile_dev,
    int* __restrict__ ocnt, int* __restrict__ olist) {
    __shared__ int hist[256], cursor[256];
    __shared__ int wsum[4], wsum2[4];
    const int tid = threadIdx.x;
    if (tid == 0) *ocnt = 0;
    hist[tid] = 0;
    __syncthreads();
    for (int i = 0; i < 32; i++) {
        int n = tid * 32 + i;
        int m = onmaskv[n];
        if (!m) m = 1;
        int e0 = __ffs(m) - 1;
        int m2 = m & (m - 1);
        int e1 = m2 ? (__ffs(m2) - 1) : e0;
        atomicAdd(&hist[e0 * 16 + e1], 1);
        int mrest = m2 & (m2 - 1);
        while (mrest) {
            int e = __ffs(mrest) - 1;
            int s = atomicAdd(ocnt, 1);
            olist[2 * s] = n;
            olist[2 * s + 1] = e;
            mrest &= (mrest - 1);
        }
    }
    __syncthreads();
    const int lane = tid & 63, w = tid >> 6;
    int v = hist[tid];
    int s = v;
#pragma unroll
    for (int off = 1; off < 64; off <<= 1) {
        int t = __shfl_up(s, off);
        if (lane >= off) s += t;
    }
    if (lane == 63) wsum[w] = s;
    __syncthreads();
    int add = 0;
    for (int i = 0; i < w; i++) add += wsum[i];
    int excl = s + add - v;
    cursor[tid] = excl;
    int nt = (v + 127) >> 7;
    int s2 = nt;
#pragma unroll
    for (int off = 1; off < 64; off <<= 1) {
        int t = __shfl_up(s2, off);
        if (lane >= off) s2 += t;
    }
    if (lane == 63) wsum2[w] = s2;
    __syncthreads();
    int add2 = 0;
    for (int i = 0; i < w; i++) add2 += wsum2[i];
    int texcl = s2 + add2 - nt;
    for (int m = 0; m < nt; m++)
        tiledesc[texcl + m] = make_int4(tid, excl + m * 128, min(128, v - m * 128), 0);
    if (tid == 255) *ntile_dev = texcl + nt;
    __syncthreads();
    for (int i = 0; i < 32; i++) {
        int n = tid * 32 + i;
        int m = onmaskv[n];
        if (!m) m = 1;
        int e0 = __ffs(m) - 1;
        int m2 = m & (m - 1);
        int e1 = m2 ? (__ffs(m2) - 1) : e0;
        int slot = atomicAdd(&cursor[e0 * 16 + e1], 1);
        ptok[slot] = n;
    }
}

// ---------------- transposes ----------------
__global__ __launch_bounds__(256) void transpose_f32_bf16(
    const float* __restrict__ src, unsigned short* __restrict__ dst,
    int R, int Ccol, long ss, long ds) {
    __shared__ float tile[32][33];
    src += (size_t)blockIdx.z * ss;
    dst += (size_t)blockIdx.z * ds;
    int bx = blockIdx.x * 32, by = blockIdx.y * 32;
    int tx = threadIdx.x & 31, ty = threadIdx.x >> 5;
#pragma unroll
    for (int i = 0; i < 4; i++)
        tile[ty + i * 8][tx] = src[(size_t)(by + ty + i * 8) * Ccol + bx + tx];
    __syncthreads();
#pragma unroll
    for (int i = 0; i < 4; i++)
        dst[(size_t)(bx + ty + i * 8) * R + by + tx] = f2bf(tile[tx][ty + i * 8]);
}

__global__ __launch_bounds__(256) void transpose_u16(
    const unsigned short* __restrict__ src, unsigned short* __restrict__ dst,
    int R, int Ccol, long ss, long ds) {
    __shared__ unsigned short tile[32][33];
    src += (size_t)blockIdx.z * ss;
    dst += (size_t)blockIdx.z * ds;
    int bx = blockIdx.x * 32, by = blockIdx.y * 32;
    int tx = threadIdx.x & 31, ty = threadIdx.x >> 5;
#pragma unroll
    for (int i = 0; i < 4; i++)
        tile[ty + i * 8][tx] = src[(size_t)(by + ty + i * 8) * Ccol + bx + tx];
    __syncthreads();
#pragma unroll
    for (int i = 0; i < 4; i++)
        dst[(size_t)(bx + ty + i * 8) * R + by + tx] = tile[tx][ty + i * 8];
}

// ---------------- NT GEMM: Out[M,N] = A[M,K] * BT[N,K]^T (bf16 in, f32 out) ----------------
template <int CAUSAL>
__global__ __launch_bounds__(256) void gemm_nt(
    const unsigned short* __restrict__ A, long strideA, int lda,
    const unsigned short* __restrict__ BT, long strideB, int ldb,
    float* __restrict__ Out, long strideO, int ldo,
    int K, float scale) {
    __shared__ alignas(16) unsigned short As[128 * 64];
    __shared__ alignas(16) unsigned short Bs[128 * 64];
    const int bm = blockIdx.x * 128;
    const int bn = blockIdx.y * 128;
    if (CAUSAL && bn > bm + 127) return;
    A += (size_t)blockIdx.z * strideA;
    BT += (size_t)blockIdx.z * strideB;
    Out += (size_t)blockIdx.z * strideO;
    const int tid = threadIdx.x;
    const int wave = tid >> 6, lane = tid & 63;
    const int lr = lane & 15, lg = lane >> 4;
    const int wr = (wave >> 1) * 64, wc = (wave & 1) * 64;
    f32x4 acc[4][4] = {};

    for (int k0 = 0; k0 < K; k0 += 64) {
        __syncthreads();
#pragma unroll
        for (int i = 0; i < 4; i++) {
            int t = i * 256 + tid;
            int row = t >> 3;
            int kc = (t & 7) << 3;
            __builtin_amdgcn_global_load_lds(
                (const __attribute__((address_space(1))) void*)(A + (size_t)(bm + row) * lda + k0 + kc),
                (__attribute__((address_space(3))) void*)(As + (i * 4 + wave) * 512),
                16, 0, 0);
        }
#pragma unroll
        for (int i = 0; i < 4; i++) {
            int t = i * 256 + tid;
            int row = t >> 3;
            int kc = (t & 7) << 3;
            __builtin_amdgcn_global_load_lds(
                (const __attribute__((address_space(1))) void*)(BT + (size_t)(bn + row) * ldb + k0 + kc),
                (__attribute__((address_space(3))) void*)(Bs + (i * 4 + wave) * 512),
                16, 0, 0);
        }
        __syncthreads();
#pragma unroll
        for (int kk = 0; kk < 2; kk++) {
            bf16x8 a[4], b[4];
#pragma unroll
            for (int m = 0; m < 4; m++)
                a[m] = *(const bf16x8*)(As + (wr + m * 16 + lr) * 64 + kk * 32 + lg * 8);
#pragma unroll
            for (int n = 0; n < 4; n++)
                b[n] = *(const bf16x8*)(Bs + (wc + n * 16 + lr) * 64 + kk * 32 + lg * 8);
#pragma unroll
            for (int m = 0; m < 4; m++)
#pragma unroll
                for (int n = 0; n < 4; n++)
                    acc[m][n] = __builtin_amdgcn_mfma_f32_16x16x32_bf16(a[m], b[n], acc[m][n], 0, 0, 0);
        }
    }
#pragma unroll
    for (int m = 0; m < 4; m++) {
#pragma unroll
        for (int n = 0; n < 4; n++) {
#pragma unroll
            for (int r = 0; r < 4; r++) {
                int grow = bm + wr + m * 16 + lg * 4 + r;
                int gcol = bn + wc + n * 16 + lr;
                if (!CAUSAL || gcol <= grow)
                    Out[(size_t)grow * ldo + gcol] = acc[m][n][r] * scale;
            }
        }
    }
}

// ---------------- PV GEMM: split-K over causal-active chunks, atomic f32 accumulate ----------------
__global__ __launch_bounds__(256) void gemm_pv(
    const unsigned short* __restrict__ P, const unsigned short* __restrict__ vT,
    float* __restrict__ ob) {
    const int bm = blockIdx.x * 128;
    const int kb = blockIdx.y * 512;
    if (kb > bm + 127) return;
    const unsigned short* Pb = P + (size_t)blockIdx.z * Tt * 4096;
    const unsigned short* Vb = vT + (size_t)blockIdx.z * Dd * Tt;
    float* Ob = ob + (size_t)blockIdx.z * Tt * Dd;
    __shared__ alignas(16) unsigned short As[128 * 64];
    __shared__ alignas(16) unsigned short Bs[128 * 64];
    const int tid = threadIdx.x;
    const int wave = tid >> 6, lane = tid & 63;
    const int lr = lane & 15, lg = lane >> 4;
    const int wr = (wave >> 1) * 64, wc = (wave & 1) * 64;
    f32x4 acc[4][4] = {};

    for (int k0 = kb; k0 < kb + 512; k0 += 64) {
        __syncthreads();
#pragma unroll
        for (int i = 0; i < 4; i++) {
            int t = i * 256 + tid;
            int row = t >> 3;
            int kc = (t & 7) << 3;
            __builtin_amdgcn_global_load_lds(
                (const __attribute__((address_space(1))) void*)(Pb + (size_t)(bm + row) * 4096 + k0 + kc),
                (__attribute__((address_space(3))) void*)(As + (i * 4 + wave) * 512),
                16, 0, 0);
        }
#pragma unroll
        for (int i = 0; i < 4; i++) {
            int t = i * 256 + tid;
            int row = t >> 3;
            int kc = (t & 7) << 3;
            __builtin_amdgcn_global_load_lds(
                (const __attribute__((address_space(1))) void*)(Vb + (size_t)row * Tt + k0 + kc),
                (__attribute__((address_space(3))) void*)(Bs + (i * 4 + wave) * 512),
                16, 0, 0);
        }
        __syncthreads();
#pragma unroll
        for (int kk = 0; kk < 2; kk++) {
            bf16x8 a[4], b[4];
#pragma unroll
            for (int m = 0; m < 4; m++)
                a[m] = *(const bf16x8*)(As + (wr + m * 16 + lr) * 64 + kk * 32 + lg * 8);
#pragma unroll
            for (int n = 0; n < 4; n++)
                b[n] = *(const bf16x8*)(Bs + (wc + n * 16 + lr) * 64 + kk * 32 + lg * 8);
#pragma unroll
            for (int m = 0; m < 4; m++)
#pragma unroll
                for (int n = 0; n < 4; n++)
                    acc[m][n] = __builtin_amdgcn_mfma_f32_16x16x32_bf16(a[m], b[n], acc[m][n], 0, 0, 0);
        }
    }
#pragma unroll
    for (int m = 0; m < 4; m++)
#pragma unroll
        for (int n = 0; n < 4; n++)
#pragma unroll
            for (int r = 0; r < 4; r++) {
                int grow = bm + wr + m * 16 + lg * 4 + r;
                int gcol = wc + n * 16 + lr;
                atomicAdd(&Ob[(size_t)grow * Dd + gcol], acc[m][n][r]);
            }
}

// ---------------- gathered QKV projection, split-K=4 into bf16 partials ----------------
__global__ __launch_bounds__(256) void gemm_qkv_gather(
    const unsigned short* __restrict__ X, const unsigned short* __restrict__ W,
    const int* __restrict__ idx, const int* __restrict__ cnt,
    unsigned short* __restrict__ P) {
    const int z = blockIdx.z;  // e*NSPLIT + kchunk
    const int e = z >> 2, kc4 = z & 3;
    const int cn = min(cnt[e], CAP);
    const int bm = blockIdx.x * 128;
    if (bm >= cn) return;
    const int bn = blockIdx.y * 128;
    unsigned short* Ph = P + (size_t)kc4 * PHALF;
    __shared__ alignas(16) unsigned short As[128 * 64];
    __shared__ alignas(16) unsigned short Bs[128 * 64];
    __shared__ int toks[128];
    const int tid = threadIdx.x;
    if (tid < 128) toks[tid] = idx[(size_t)e * CAP + min(bm + tid, cn - 1)];
    const unsigned short* Wb = W + ((size_t)e * 384 + bn) * Cch;
    const int wave = tid >> 6, lane = tid & 63;
    const int lr = lane & 15, lg = lane >> 4;
    const int wr = (wave >> 1) * 64, wc = (wave & 1) * 64;
    f32x4 acc[4][4] = {};

    for (int k0 = kc4 * 512; k0 < kc4 * 512 + 512; k0 += 64) {
        __syncthreads();
#pragma unroll
        for (int i = 0; i < 4; i++) {
            int t = i * 256 + tid;
            int row = t >> 3;
            int kc = (t & 7) << 3;
            __builtin_amdgcn_global_load_lds(
                (const __attribute__((address_space(1))) void*)(X + (size_t)toks[row] * Cch + k0 + kc),
                (__attribute__((address_space(3))) void*)(As + (i * 4 + wave) * 512),
                16, 0, 0);
        }
#pragma unroll
        for (int i = 0; i < 4; i++) {
            int t = i * 256 + tid;
            int row = t >> 3;
            int kc = (t & 7) << 3;
            __builtin_amdgcn_global_load_lds(
                (const __attribute__((address_space(1))) void*)(Wb + (size_t)row * Cch + k0 + kc),
                (__attribute__((address_space(3))) void*)(Bs + (i * 4 + wave) * 512),
                16, 0, 0);
        }
        __syncthreads();
#pragma unroll
        for (int kk = 0; kk < 2; kk++) {
            bf16x8 a[4], b[4];
#pragma unroll
            for (int m = 0; m < 4; m++)
                a[m] = *(const bf16x8*)(As + (wr + m * 16 + lr) * 64 + kk * 32 + lg * 8);
#pragma unroll
            for (int n = 0; n < 4; n++)
                b[n] = *(const bf16x8*)(Bs + (wc + n * 16 + lr) * 64 + kk * 32 + lg * 8);
#pragma unroll
            for (int m = 0; m < 4; m++)
#pragma unroll
                for (int n = 0; n < 4; n++)
                    acc[m][n] = __builtin_amdgcn_mfma_f32_16x16x32_bf16(a[m], b[n], acc[m][n], 0, 0, 0);
        }
    }
#pragma unroll
    for (int m = 0; m < 4; m++)
#pragma unroll
        for (int n = 0; n < 4; n++)
#pragma unroll
            for (int r = 0; r < 4; r++) {
                int slot = bm + wr + m * 16 + lg * 4 + r;
                int col = bn + wc + n * 16 + lr;
                if (slot < cn)
                    Ph[((size_t)e * CAP + slot) * 384 + col] = f2bf(acc[m][n][r]);
            }
}

// ---------------- combine q/k/v from NSPLIT split-K partials ----------------
__global__ __launch_bounds__(256) void combine_qkv(
    const unsigned short* __restrict__ P, const float* __restrict__ rw,
    const int* __restrict__ pos,
    unsigned short* __restrict__ qb, unsigned short* __restrict__ kb,
    unsigned short* __restrict__ vb) {
    int i = blockIdx.x * 256 + threadIdx.x;
    int n = i >> 5;
    int d4 = (i & 31) << 2;
    float aq[4] = {}, ak[4] = {}, av[4] = {};
#pragma unroll
    for (int e = 0; e < 16; e++) {
        int p = pos[(size_t)n * 16 + e];
        if (p >= 0) {
            float w = rw[(size_t)n * 16 + e];
            const unsigned short* r0 = P + ((size_t)e * CAP + p) * 384 + d4;
#pragma unroll
            for (int h = 0; h < NSPLIT; h++) {
                const unsigned short* rh = r0 + (size_t)h * PHALF;
                const u16x4 q4 = *(const u16x4*)(rh);
                const u16x4 k4 = *(const u16x4*)(rh + 128);
                const u16x4 v4 = *(const u16x4*)(rh + 256);
#pragma unroll
                for (int j = 0; j < 4; j++) {
                    aq[j] += w * bf2f(q4[j]);
                    ak[j] += w * bf2f(k4[j]);
                    av[j] += w * bf2f(v4[j]);
                }
            }
        }
    }
    u16x4 sq = {f2bf(aq[0]), f2bf(aq[1]), f2bf(aq[2]), f2bf(aq[3])};
    u16x4 sk = {f2bf(ak[0]), f2bf(ak[1]), f2bf(ak[2]), f2bf(ak[3])};
    u16x4 sv = {f2bf(av[0]), f2bf(av[1]), f2bf(av[2]), f2bf(av[3])};
    *(u16x4*)(qb + (size_t)n * Dd + d4) = sq;
    *(u16x4*)(kb + (size_t)n * Dd + d4) = sk;
    *(u16x4*)(vb + (size_t)n * Dd + d4) = sv;
}

// ---------------- causal row softmax, in-place f32 -> bf16 ----------------
__global__ __launch_bounds__(256) void softmax_kernel(float* __restrict__ scores) {
    int i = blockIdx.x, b = blockIdx.y;
    float* row = scores + ((size_t)b * Tt + i) * Tt;
    int nv = i + 1;
    float v[8];
    int cnt = 0;
    float mx = -1e30f;
    for (int j = threadIdx.x; j < nv; j += 256) {
        float t = row[j];
        v[cnt++] = t;
        mx = fmaxf(mx, t);
    }
    __shared__ float sred[4];
    int w = threadIdx.x >> 6;
#pragma unroll
    for (int off = 32; off; off >>= 1) mx = fmaxf(mx, __shfl_down(mx, off));
    if ((threadIdx.x & 63) == 0) sred[w] = mx;
    __syncthreads();
    float m = fmaxf(fmaxf(sred[0], sred[1]), fmaxf(sred[2], sred[3]));
    float s = 0.f;
    for (int t = 0; t < cnt; t++) {
        v[t] = __expf(v[t] - m);
        s += v[t];
    }
    __syncthreads();
#pragma unroll
    for (int off = 32; off; off >>= 1) s += __shfl_down(s, off);
    if ((threadIdx.x & 63) == 0) sred[w] = s;
    __syncthreads();
    float inv = 1.f / (sred[0] + sred[1] + sred[2] + sred[3]);
    unsigned short* prow = (unsigned short*)row;
    cnt = 0;
    for (int j = threadIdx.x; j < Tt; j += 256) {
        float pv = 0.f;
        if (j < nv) pv = v[cnt++] * inv;
        prow[j] = f2bf(pv);
    }
}

// ---------------- og2[n][256] = [rw_e0 * o | rw_e1 * o] (bf16) ----------------
__global__ __launch_bounds__(256) void og2_kernel(
    const float* __restrict__ ob, const float* __restrict__ rw,
    const int* __restrict__ onmaskv, unsigned short* __restrict__ og2) {
    int idx = blockIdx.x * 256 + threadIdx.x;  // (n, k4-group of 4)
    int n = idx >> 6;
    int k4 = (idx & 63) << 2;
    int m = onmaskv[n];
    if (!m) m = 1;
    int e0 = __ffs(m) - 1;
    int m2 = m & (m - 1);
    bool has2 = m2 != 0;
    int e1 = has2 ? (__ffs(m2) - 1) : e0;
    float wgt;
    int kb;
    if (k4 < 128) { wgt = rw[(size_t)n * 16 + e0]; kb = k4; }
    else { wgt = has2 ? rw[(size_t)n * 16 + e1] : 0.f; kb = k4 - 128; }
    const f32x4 o4 = *(const f32x4*)(ob + (size_t)n * Dd + kb);
    u16x4 st = {f2bf(wgt * o4[0]), f2bf(wgt * o4[1]), f2bf(wgt * o4[2]), f2bf(wgt * o4[3])};
    *(u16x4*)(og2 + (size_t)n * 256 + k4) = st;
}

// ---------------- pair-bucket output GEMM: out row written exactly once ----------------
__global__ __launch_bounds__(256) void gemm_pair(
    const unsigned short* __restrict__ og2,   // [Nn][256] bf16
    const unsigned short* __restrict__ woT,   // [2048 c][E*128] bf16
    const int* __restrict__ ptok, const int4* __restrict__ tiledesc,
    const int* __restrict__ ntile_dev,
    float* __restrict__ out) {
    if (blockIdx.x >= *ntile_dev) return;
    const int4 td = tiledesc[blockIdx.x];
    const int ei = td.x >> 4, ej = td.x & 15;
    const int mstart = td.y, mcnt = td.z;
    const int bn = blockIdx.y * 128;
    __shared__ alignas(16) unsigned short As[128 * 64];
    __shared__ alignas(16) unsigned short Bs[128 * 64];
    __shared__ int toks[128];
    const int tid = threadIdx.x;
    if (tid < 128) toks[tid] = ptok[mstart + min(tid, mcnt - 1)];
    const int wave = tid >> 6, lane = tid & 63;
    const int lr = lane & 15, lg = lane >> 4;
    const int wr = (wave >> 1) * 64, wc = (wave & 1) * 64;
    f32x4 acc[4][4] = {};

#pragma unroll
    for (int ck = 0; ck < 4; ck++) {
        const int ebase = (ck < 2 ? ei : ej) * 128 + (ck & 1) * 64;
        const int abase = ck * 64;
        __syncthreads();  // first iter: also guards toks
#pragma unroll
        for (int q = 0; q < 4; q++) {
            int t = q * 256 + tid;
            int row = t >> 3;
            int kc = (t & 7) << 3;
            __builtin_amdgcn_global_load_lds(
                (const __attribute__((address_space(1))) void*)(og2 + (size_t)toks[row] * 256 + abase + kc),
                (__attribute__((address_space(3))) void*)(As + (q * 4 + wave) * 512),
                16, 0, 0);
        }
#pragma unroll
        for (int q = 0; q < 4; q++) {
            int t = q * 256 + tid;
            int row = t >> 3;
            int kc = (t & 7) << 3;
            __builtin_amdgcn_global_load_lds(
                (const __attribute__((address_space(1))) void*)(woT + (size_t)(bn + row) * 2048 + ebase + kc),
                (__attribute__((address_space(3))) void*)(Bs + (q * 4 + wave) * 512),
                16, 0, 0);
        }
        __syncthreads();
#pragma unroll
        for (int kk = 0; kk < 2; kk++) {
            bf16x8 a[4], b[4];
#pragma unroll
            for (int m = 0; m < 4; m++)
                a[m] = *(const bf16x8*)(As + (wr + m * 16 + lr) * 64 + kk * 32 + lg * 8);
#pragma unroll
            for (int n = 0; n < 4; n++)
                b[n] = *(const bf16x8*)(Bs + (wc + n * 16 + lr) * 64 + kk * 32 + lg * 8);
#pragma unroll
            for (int m = 0; m < 4; m++)
#pragma unroll
                for (int n = 0; n < 4; n++)
                    acc[m][n] = __builtin_amdgcn_mfma_f32_16x16x32_bf16(a[m], b[n], acc[m][n], 0, 0, 0);
        }
    }
#pragma unroll
    for (int m = 0; m < 4; m++)
#pragma unroll
        for (int n = 0; n < 4; n++)
#pragma unroll
            for (int r = 0; r < 4; r++) {
                int rowt = wr + m * 16 + lg * 4 + r;
                if (rowt < mcnt) {
                    int tok = toks[rowt];
                    out[(size_t)tok * 2048 + bn + wc + n * 16 + lr] = acc[m][n][r];
                }
            }
}

// ---------------- rare overflow path: experts beyond the first two (empty here) ----------------
__global__ __launch_bounds__(256) void overflow_kernel(
    const int* __restrict__ ocnt, const int* __restrict__ olist,
    const float* __restrict__ ob, const unsigned short* __restrict__ woT,
    const float* __restrict__ rw, float* __restrict__ out) {
    const int ne = *ocnt;
    __shared__ float osh[128];
    for (int it = blockIdx.x; it < ne; it += gridDim.x) {
        int n = olist[2 * it], e = olist[2 * it + 1];
        float wgt = rw[(size_t)n * 16 + e];
        if (threadIdx.x < 128) osh[threadIdx.x] = ob[(size_t)n * Dd + threadIdx.x];
        __syncthreads();
#pragma unroll 1
        for (int cc = 0; cc < 8; cc++) {
            int c = threadIdx.x * 8 + cc;
            float a = 0.f;
            for (int k = 0; k < 128; k++)
                a += osh[k] * bf2f(woT[(size_t)c * 2048 + e * 128 + k]);
            atomicAdd(&out[(size_t)n * 2048 + c], wgt * a);
        }
        __syncthreads();
    }
}

extern "C" void kernel_launch(void* const* d_in, const int* in_sizes, int n_in,
                              void* d_out, int out_size, void* d_ws, size_t ws_size,
                              hipStream_t stream) {
    (void)in_sizes; (void)n_in; (void)out_size; (void)ws_size;
    const float* hidden = (const float*)d_in[0];
    const float* sim = (const float*)d_in[1];
    const float* gates = (const float*)d_in[2];
    const float* qp = (const float*)d_in[3];
    const float* kp = (const float*)d_in[4];
    const float* vp = (const float*)d_in[5];
    const float* op = (const float*)d_in[6];
    const int* minex = (const int*)d_in[7];
    float* out = (float*)d_out;

    char* w = (char*)d_ws;
    size_t off = 0;
    auto alloc = [&](size_t bytes) -> char* {
        char* p = w + off;
        off = (off + bytes + 255) & ~(size_t)255;
        return p;
    };
    unsigned short* xb = (unsigned short*)alloc((size_t)Nn * Cch * 2);
    unsigned short* wqkvT = (unsigned short*)alloc((size_t)Ee * 384 * Cch * 2);
    unsigned short* woT = (unsigned short*)alloc((size_t)Cch * Ee * Dd * 2);
    float* rw = (float*)alloc((size_t)Nn * Ee * 4);
    float* sninv = (float*)alloc(256);
    float* simT = (float*)alloc((size_t)Ee * Cch * 4);
    int* cnt = (int*)alloc(256);
    int* onmaskv = (int*)alloc((size_t)Nn * 4);
    int* idx = (int*)alloc((size_t)Ee * CAP * 4);
    int* pos = (int*)alloc((size_t)Nn * 16 * 4);
    int* ptok = (int*)alloc((size_t)Nn * 4);
    int4* tiledesc = (int4*)alloc((size_t)MAXTILES * 16);
    int* ntile_dev = (int*)alloc(256);
    int* ocnt = (int*)alloc(256);
    int* olist = (int*)alloc((size_t)Nn * 14 * 2 * 4);
    char* big = alloc((size_t)Bsz * Tt * Tt * 4);  // P partials (63MB) / scores (67MB)
    unsigned short* qb = (unsigned short*)alloc((size_t)Nn * Dd * 2);
    unsigned short* kb = (unsigned short*)alloc((size_t)Nn * Dd * 2);
    unsigned short* vb = (unsigned short*)alloc((size_t)Nn * Dd * 2);
    unsigned short* vT = (unsigned short*)alloc((size_t)Bsz * Dd * Tt * 2);
    float* ob = (float*)alloc((size_t)Nn * Dd * 4);
    unsigned short* og2 = (unsigned short*)alloc((size_t)Nn * 256 * 2);
    unsigned short* Pc = (unsigned short*)big;
    float* scores = (float*)big;

    const float scale = 0.08838834764831845f;  // 1/sqrt(128)

    colnorm_kernel<<<1, 256, 0, stream>>>(sim, sninv);
    simt_kernel<<<(Ee * Cch) / 256, 256, 0, stream>>>(sim, simT);
    gating4_kernel<<<Nn / 32, 256, 0, stream>>>(hidden, simT, gates, sninv, minex, rw, xb, onmaskv);
    scan_kernel<<<Ee, 256, 0, stream>>>(onmaskv, idx, pos, cnt);
    scan_pair<<<1, 256, 0, stream>>>(onmaskv, ptok, tiledesc, ntile_dev, ocnt, olist);
    hipMemsetAsync(ob, 0, (size_t)Nn * Dd * 4, stream);

    // weight transposes (f32 -> bf16) into fused [E][384][C]
    transpose_f32_bf16<<<dim3(Dd / 32, Cch / 32, Ee), 256, 0, stream>>>(
        qp, wqkvT + 0 * Dd * Cch, Cch, Dd, (long)Cch * Dd, (long)384 * Cch);
    transpose_f32_bf16<<<dim3(Dd / 32, Cch / 32, Ee), 256, 0, stream>>>(
        kp, wqkvT + 1 * Dd * Cch, Cch, Dd, (long)Cch * Dd, (long)384 * Cch);
    transpose_f32_bf16<<<dim3(Dd / 32, Cch / 32, Ee), 256, 0, stream>>>(
        vp, wqkvT + 2 * Dd * Cch, Cch, Dd, (long)Cch * Dd, (long)384 * Cch);
    transpose_f32_bf16<<<dim3((Ee * Dd) / 32, Cch / 32, 1), 256, 0, stream>>>(
        op, woT, Ee * Dd, Cch, 0L, 0L);

    // gathered per-expert QKV projection (split-K=4), then combine
    gemm_qkv_gather<<<dim3(CAP / 128, 3, Ee * NSPLIT), 256, 0, stream>>>(xb, wqkvT, idx, cnt, Pc);
    combine_qkv<<<(Nn * 32) / 256, 256, 0, stream>>>(Pc, rw, pos, qb, kb, vb);

    // V transpose per batch
    transpose_u16<<<dim3(Dd / 32, Tt / 32, Bsz), 256, 0, stream>>>(
        vb, vT, Tt, Dd, (long)Tt * Dd, (long)Dd * Tt);

    // scores = Q K^T * scale (causal)
    gemm_nt<1><<<dim3(Tt / 128, Tt / 128, Bsz), 256, 0, stream>>>(
        qb, (long)Tt * Dd, Dd, kb, (long)Tt * Dd, Dd, scores, (long)Tt * Tt, Tt, Dd, scale);
    softmax_kernel<<<dim3(Tt, Bsz), 256, 0, stream>>>(scores);
    // O = P V  — split-K over causal-active 512-chunks, atomic accumulate
    gemm_pv<<<dim3(Tt / 128, Tt / 512, Bsz), 256, 0, stream>>>(
        (const unsigned short*)scores, vT, ob);

    // output projection: pair-bucket grouped GEMM, each out row stored exactly once
    og2_kernel<<<(Nn * 64) / 256, 256, 0, stream>>>(ob, rw, onmaskv, og2);
    gemm_pair<<<dim3(MAXTILES, Cch / 128), 256, 0, stream>>>(
        og2, woT, ptok, tiledesc, ntile_dev, out);
    overflow_kernel<<<256, 256, 0, stream>>>(ocnt, olist, ob, woT, rw, out);
}

// Round 10
// 344.968 us; speedup vs baseline: 1.2597x; 1.2149x over previous
//
#include <hip/hip_runtime.h>
#include <hip/hip_bf16.h>

#define DEV __device__ __forceinline__

typedef short bf16x8 __attribute__((ext_vector_type(8)));
typedef float f32x4 __attribute__((ext_vector_type(4)));
typedef unsigned short u16x4 __attribute__((ext_vector_type(4)));

static constexpr int Bsz = 4, Tt = 2048, Cch = 2048, Dd = 128, Ee = 16;
static constexpr int Nn = Bsz * Tt;
static constexpr int CAP = 1280;  // per-expert capacity (mean ~1024, sigma ~30 -> 8.5 sigma)
static constexpr int NSPLIT = 4;  // split-K partials for QKV gather
static constexpr size_t PHALF = (size_t)Ee * CAP * 384;  // elems per split-K partial (15.7MB)
static constexpr int MAXTILES = 320;  // >= 256 buckets + Nn/128

DEV unsigned short f2bf(float v) {
    __hip_bfloat16 h = __float2bfloat16(v);
    return __builtin_bit_cast(unsigned short, h);
}
DEV float bf2f(unsigned short u) {
    unsigned int x = ((unsigned int)u) << 16;
    return __builtin_bit_cast(float, x);
}

// ---------------- sim_matrix column norms ----------------
__global__ __launch_bounds__(256) void colnorm_kernel(const float* __restrict__ sim,
                                                      float* __restrict__ sninv) {
    int e = threadIdx.x & 15, j = threadIdx.x >> 4;
    float ss = 0.f;
    for (int r = j; r < Cch; r += 16) {
        float v = sim[r * Ee + e];
        ss += v * v;
    }
    __shared__ float red[16][17];
    red[j][e] = ss;
    __syncthreads();
    if (threadIdx.x < 16) {
        float s = 0.f;
        for (int t = 0; t < 16; t++) s += red[t][threadIdx.x];
        sninv[threadIdx.x] = 1.f / fmaxf(sqrtf(s), 1e-12f);
    }
}

// ---------------- sim transpose: simT[e][c] = sim[c][e] ----------------
__global__ __launch_bounds__(256) void simt_kernel(const float* __restrict__ sim,
                                                   float* __restrict__ simT) {
    int i = blockIdx.x * 256 + threadIdx.x;  // 16*2048
    int e = i >> 11, c = i & 2047;
    simT[i] = sim[c * 16 + e];
}

// ---------------- gating: full simT in 128 KiB LDS; 1024 threads (16 waves/CU);
// one token per wave-pass (d[16] only -> no spill) ----------------
__global__ __launch_bounds__(1024) void gating5_kernel(
    const float* __restrict__ x, const float* __restrict__ simT,
    const float* __restrict__ gates, const float* __restrict__ sninv,
    const int* __restrict__ minex,
    float* __restrict__ rw, unsigned short* __restrict__ xb,
    int* __restrict__ onmaskv) {
    __shared__ f32x4 ssim[8192];  // 128 KiB = full simT in f32
    const int tid = threadIdx.x;
    const f32x4* stg = (const f32x4*)simT;
#pragma unroll
    for (int i = 0; i < 8; i++) ssim[i * 1024 + tid] = stg[i * 1024 + tid];
    __syncthreads();
    const int wave = tid >> 6, lane = tid & 63;

#pragma unroll 1
    for (int g = 0; g < 2; g++) {
        const int n = blockIdx.x * 32 + g * 16 + wave;
        const f32x4* xr = (const f32x4*)(x + (size_t)n * Cch);
        u16x4* xbr = (u16x4*)(xb + (size_t)n * Cch);
        float ss = 0.f;
        float d[16];
#pragma unroll
        for (int e = 0; e < 16; e++) d[e] = 0.f;

#pragma unroll 2
        for (int it = 0; it < 8; it++) {
            const int i = it * 64 + lane;
            const f32x4 xv = xr[i];
            ss += xv[0] * xv[0] + xv[1] * xv[1] + xv[2] * xv[2] + xv[3] * xv[3];
            u16x4 xc = {f2bf(xv[0]), f2bf(xv[1]), f2bf(xv[2]), f2bf(xv[3])};
            xbr[i] = xc;
#pragma unroll
            for (int e = 0; e < 16; e++) {
                const f32x4 sv = ssim[e * 512 + i];
                d[e] += xv[0] * sv[0] + xv[1] * sv[1] + xv[2] * sv[2] + xv[3] * sv[3];
            }
        }
#pragma unroll
        for (int off = 32; off; off >>= 1) {
            ss += __shfl_down(ss, off);
#pragma unroll
            for (int e = 0; e < 16; e++) d[e] += __shfl_down(d[e], off);
        }
        if (lane == 0) {
            float inv = 1.f / fmaxf(sqrtf(ss), 1e-12f);
            float logit[16];
            int onmask = 0;
#pragma unroll
            for (int e = 0; e < 16; e++) {
                float sg = 1.f / (1.f + __expf(-gates[e]));
                float l = d[e] * inv * sninv[e] - sg;
                logit[e] = l;
                if (l > 0.f) onmask |= (1 << e);
            }
            if (onmask == 0) {
                int k = *minex;
                int ch = 0;
                for (int kk = 0; kk < k; kk++) {
                    float bv = -1e30f;
                    int be = 0;
#pragma unroll
                    for (int e = 0; e < 16; e++)
                        if (!((ch >> e) & 1) && logit[e] > bv) { bv = logit[e]; be = e; }
                    ch |= (1 << be);
                }
                onmask = ch;
            }
            float mx = -1e30f;
#pragma unroll
            for (int e = 0; e < 16; e++)
                if ((onmask >> e) & 1) mx = fmaxf(mx, fmaxf(logit[e], 0.f));
            float pe[16];
            float sum = 0.f;
#pragma unroll
            for (int e = 0; e < 16; e++) {
                pe[e] = ((onmask >> e) & 1) ? __expf(fmaxf(logit[e], 0.f) - mx) : 0.f;
                sum += pe[e];
            }
            float isum = 1.f / sum;
#pragma unroll
            for (int e = 0; e < 16; e++) rw[(size_t)n * 16 + e] = pe[e] * isum;
            onmaskv[n] = onmask;
        }
    }
}

// ---------------- deterministic expert-list scan (for QKV gather) ----------------
__global__ __launch_bounds__(256) void scan_kernel(
    const int* __restrict__ onmaskv,
    int* __restrict__ idx, int* __restrict__ pos, int* __restrict__ cnt) {
    const int e = blockIdx.x;
    const int tid = threadIdx.x;
    const int base = tid * 32;
    int om[32];
    int c = 0;
#pragma unroll
    for (int i = 0; i < 32; i++) {
        om[i] = (onmaskv[base + i] >> e) & 1;
        c += om[i];
    }
    const int lane = tid & 63, w = tid >> 6;
    int sc = c;
#pragma unroll
    for (int off = 1; off < 64; off <<= 1) {
        int t = __shfl_up(sc, off);
        if (lane >= off) sc += t;
    }
    __shared__ int wsum[4];
    if (lane == 63) wsum[w] = sc;
    __syncthreads();
    int wbase = 0;
    for (int i = 0; i < w; i++) wbase += wsum[i];
    int slot = wbase + sc - c;
#pragma unroll
    for (int i = 0; i < 32; i++) {
        int n = base + i;
        int p = -1;
        if (om[i]) {
            if (slot < CAP) {
                idx[(size_t)e * CAP + slot] = n;
                p = slot;
            }
            slot++;
        }
        pos[(size_t)n * 16 + e] = p;
    }
    if (tid == 255) cnt[e] = slot;
}

// ---------------- pair-bucket scan for output projection ----------------
__global__ __launch_bounds__(256) void scan_pair(
    const int* __restrict__ onmaskv,
    int* __restrict__ ptok, int4* __restrict__ tiledesc, int* __restrict__ ntile_dev,
    int* __restrict__ ocnt, int* __restrict__ olist) {
    __shared__ int hist[256], cursor[256];
    __shared__ int wsum[4], wsum2[4];
    const int tid = threadIdx.x;
    if (tid == 0) *ocnt = 0;
    hist[tid] = 0;
    __syncthreads();
    for (int i = 0; i < 32; i++) {
        int n = tid * 32 + i;
        int m = onmaskv[n];
        if (!m) m = 1;
        int e0 = __ffs(m) - 1;
        int m2 = m & (m - 1);
        int e1 = m2 ? (__ffs(m2) - 1) : e0;
        atomicAdd(&hist[e0 * 16 + e1], 1);
        int mrest = m2 & (m2 - 1);
        while (mrest) {
            int e = __ffs(mrest) - 1;
            int s = atomicAdd(ocnt, 1);
            olist[2 * s] = n;
            olist[2 * s + 1] = e;
            mrest &= (mrest - 1);
        }
    }
    __syncthreads();
    const int lane = tid & 63, w = tid >> 6;
    int v = hist[tid];
    int s = v;
#pragma unroll
    for (int off = 1; off < 64; off <<= 1) {
        int t = __shfl_up(s, off);
        if (lane >= off) s += t;
    }
    if (lane == 63) wsum[w] = s;
    __syncthreads();
    int add = 0;
    for (int i = 0; i < w; i++) add += wsum[i];
    int excl = s + add - v;
    cursor[tid] = excl;
    int nt = (v + 127) >> 7;
    int s2 = nt;
#pragma unroll
    for (int off = 1; off < 64; off <<= 1) {
        int t = __shfl_up(s2, off);
        if (lane >= off) s2 += t;
    }
    if (lane == 63) wsum2[w] = s2;
    __syncthreads();
    int add2 = 0;
    for (int i = 0; i < w; i++) add2 += wsum2[i];
    int texcl = s2 + add2 - nt;
    for (int m = 0; m < nt; m++)
        tiledesc[texcl + m] = make_int4(tid, excl + m * 128, min(128, v - m * 128), 0);
    if (tid == 255) *ntile_dev = texcl + nt;
    __syncthreads();
    for (int i = 0; i < 32; i++) {
        int n = tid * 32 + i;
        int m = onmaskv[n];
        if (!m) m = 1;
        int e0 = __ffs(m) - 1;
        int m2 = m & (m - 1);
        int e1 = m2 ? (__ffs(m2) - 1) : e0;
        int slot = atomicAdd(&cursor[e0 * 16 + e1], 1);
        ptok[slot] = n;
    }
}

// ---------------- transposes ----------------
__global__ __launch_bounds__(256) void transpose_f32_bf16(
    const float* __restrict__ src, unsigned short* __restrict__ dst,
    int R, int Ccol, long ss, long ds) {
    __shared__ float tile[32][33];
    src += (size_t)blockIdx.z * ss;
    dst += (size_t)blockIdx.z * ds;
    int bx = blockIdx.x * 32, by = blockIdx.y * 32;
    int tx = threadIdx.x & 31, ty = threadIdx.x >> 5;
#pragma unroll
    for (int i = 0; i < 4; i++)
        tile[ty + i * 8][tx] = src[(size_t)(by + ty + i * 8) * Ccol + bx + tx];
    __syncthreads();
#pragma unroll
    for (int i = 0; i < 4; i++)
        dst[(size_t)(bx + ty + i * 8) * R + by + tx] = f2bf(tile[tx][ty + i * 8]);
}

__global__ __launch_bounds__(256) void transpose_u16(
    const unsigned short* __restrict__ src, unsigned short* __restrict__ dst,
    int R, int Ccol, long ss, long ds) {
    __shared__ unsigned short tile[32][33];
    src += (size_t)blockIdx.z * ss;
    dst += (size_t)blockIdx.z * ds;
    int bx = blockIdx.x * 32, by = blockIdx.y * 32;
    int tx = threadIdx.x & 31, ty = threadIdx.x >> 5;
#pragma unroll
    for (int i = 0; i < 4; i++)
        tile[ty + i * 8][tx] = src[(size_t)(by + ty + i * 8) * Ccol + bx + tx];
    __syncthreads();
#pragma unroll
    for (int i = 0; i < 4; i++)
        dst[(size_t)(bx + ty + i * 8) * R + by + tx] = tile[tx][ty + i * 8];
}

// ---------------- NT GEMM: Out[M,N] = A[M,K] * BT[N,K]^T (bf16 in, f32 out) ----------------
template <int CAUSAL>
__global__ __launch_bounds__(256) void gemm_nt(
    const unsigned short* __restrict__ A, long strideA, int lda,
    const unsigned short* __restrict__ BT, long strideB, int ldb,
    float* __restrict__ Out, long strideO, int ldo,
    int K, float scale) {
    __shared__ alignas(16) unsigned short As[128 * 64];
    __shared__ alignas(16) unsigned short Bs[128 * 64];
    const int bm = blockIdx.x * 128;
    const int bn = blockIdx.y * 128;
    if (CAUSAL && bn > bm + 127) return;
    A += (size_t)blockIdx.z * strideA;
    BT += (size_t)blockIdx.z * strideB;
    Out += (size_t)blockIdx.z * strideO;
    const int tid = threadIdx.x;
    const int wave = tid >> 6, lane = tid & 63;
    const int lr = lane & 15, lg = lane >> 4;
    const int wr = (wave >> 1) * 64, wc = (wave & 1) * 64;
    f32x4 acc[4][4] = {};

    for (int k0 = 0; k0 < K; k0 += 64) {
        __syncthreads();
#pragma unroll
        for (int i = 0; i < 4; i++) {
            int t = i * 256 + tid;
            int row = t >> 3;
            int kc = (t & 7) << 3;
            __builtin_amdgcn_global_load_lds(
                (const __attribute__((address_space(1))) void*)(A + (size_t)(bm + row) * lda + k0 + kc),
                (__attribute__((address_space(3))) void*)(As + (i * 4 + wave) * 512),
                16, 0, 0);
        }
#pragma unroll
        for (int i = 0; i < 4; i++) {
            int t = i * 256 + tid;
            int row = t >> 3;
            int kc = (t & 7) << 3;
            __builtin_amdgcn_global_load_lds(
                (const __attribute__((address_space(1))) void*)(BT + (size_t)(bn + row) * ldb + k0 + kc),
                (__attribute__((address_space(3))) void*)(Bs + (i * 4 + wave) * 512),
                16, 0, 0);
        }
        __syncthreads();
#pragma unroll
        for (int kk = 0; kk < 2; kk++) {
            bf16x8 a[4], b[4];
#pragma unroll
            for (int m = 0; m < 4; m++)
                a[m] = *(const bf16x8*)(As + (wr + m * 16 + lr) * 64 + kk * 32 + lg * 8);
#pragma unroll
            for (int n = 0; n < 4; n++)
                b[n] = *(const bf16x8*)(Bs + (wc + n * 16 + lr) * 64 + kk * 32 + lg * 8);
#pragma unroll
            for (int m = 0; m < 4; m++)
#pragma unroll
                for (int n = 0; n < 4; n++)
                    acc[m][n] = __builtin_amdgcn_mfma_f32_16x16x32_bf16(a[m], b[n], acc[m][n], 0, 0, 0);
        }
    }
#pragma unroll
    for (int m = 0; m < 4; m++) {
#pragma unroll
        for (int n = 0; n < 4; n++) {
#pragma unroll
            for (int r = 0; r < 4; r++) {
                int grow = bm + wr + m * 16 + lg * 4 + r;
                int gcol = bn + wc + n * 16 + lr;
                if (!CAUSAL || gcol <= grow)
                    Out[(size_t)grow * ldo + gcol] = acc[m][n][r] * scale;
            }
        }
    }
}

// ---------------- PV GEMM: split-K over causal-active chunks, atomic f32 accumulate ----------------
__global__ __launch_bounds__(256) void gemm_pv(
    const unsigned short* __restrict__ P, const unsigned short* __restrict__ vT,
    float* __restrict__ ob) {
    const int bm = blockIdx.x * 128;
    const int kb = blockIdx.y * 512;
    if (kb > bm + 127) return;
    const unsigned short* Pb = P + (size_t)blockIdx.z * Tt * 4096;
    const unsigned short* Vb = vT + (size_t)blockIdx.z * Dd * Tt;
    float* Ob = ob + (size_t)blockIdx.z * Tt * Dd;
    __shared__ alignas(16) unsigned short As[128 * 64];
    __shared__ alignas(16) unsigned short Bs[128 * 64];
    const int tid = threadIdx.x;
    const int wave = tid >> 6, lane = tid & 63;
    const int lr = lane & 15, lg = lane >> 4;
    const int wr = (wave >> 1) * 64, wc = (wave & 1) * 64;
    f32x4 acc[4][4] = {};

    for (int k0 = kb; k0 < kb + 512; k0 += 64) {
        __syncthreads();
#pragma unroll
        for (int i = 0; i < 4; i++) {
            int t = i * 256 + tid;
            int row = t >> 3;
            int kc = (t & 7) << 3;
            __builtin_amdgcn_global_load_lds(
                (const __attribute__((address_space(1))) void*)(Pb + (size_t)(bm + row) * 4096 + k0 + kc),
                (__attribute__((address_space(3))) void*)(As + (i * 4 + wave) * 512),
                16, 0, 0);
        }
#pragma unroll
        for (int i = 0; i < 4; i++) {
            int t = i * 256 + tid;
            int row = t >> 3;
            int kc = (t & 7) << 3;
            __builtin_amdgcn_global_load_lds(
                (const __attribute__((address_space(1))) void*)(Vb + (size_t)row * Tt + k0 + kc),
                (__attribute__((address_space(3))) void*)(Bs + (i * 4 + wave) * 512),
                16, 0, 0);
        }
        __syncthreads();
#pragma unroll
        for (int kk = 0; kk < 2; kk++) {
            bf16x8 a[4], b[4];
#pragma unroll
            for (int m = 0; m < 4; m++)
                a[m] = *(const bf16x8*)(As + (wr + m * 16 + lr) * 64 + kk * 32 + lg * 8);
#pragma unroll
            for (int n = 0; n < 4; n++)
                b[n] = *(const bf16x8*)(Bs + (wc + n * 16 + lr) * 64 + kk * 32 + lg * 8);
#pragma unroll
            for (int m = 0; m < 4; m++)
#pragma unroll
                for (int n = 0; n < 4; n++)
                    acc[m][n] = __builtin_amdgcn_mfma_f32_16x16x32_bf16(a[m], b[n], acc[m][n], 0, 0, 0);
        }
    }
#pragma unroll
    for (int m = 0; m < 4; m++)
#pragma unroll
        for (int n = 0; n < 4; n++)
#pragma unroll
            for (int r = 0; r < 4; r++) {
                int grow = bm + wr + m * 16 + lg * 4 + r;
                int gcol = wc + n * 16 + lr;
                atomicAdd(&Ob[(size_t)grow * Dd + gcol], acc[m][n][r]);
            }
}

// ---------------- gathered QKV projection, split-K=4 into bf16 partials ----------------
__global__ __launch_bounds__(256) void gemm_qkv_gather(
    const unsigned short* __restrict__ X, const unsigned short* __restrict__ W,
    const int* __restrict__ idx, const int* __restrict__ cnt,
    unsigned short* __restrict__ P) {
    const int z = blockIdx.z;  // e*NSPLIT + kchunk
    const int e = z >> 2, kc4 = z & 3;
    const int cn = min(cnt[e], CAP);
    const int bm = blockIdx.x * 128;
    if (bm >= cn) return;
    const int bn = blockIdx.y * 128;
    unsigned short* Ph = P + (size_t)kc4 * PHALF;
    __shared__ alignas(16) unsigned short As[128 * 64];
    __shared__ alignas(16) unsigned short Bs[128 * 64];
    __shared__ int toks[128];
    const int tid = threadIdx.x;
    if (tid < 128) toks[tid] = idx[(size_t)e * CAP + min(bm + tid, cn - 1)];
    const unsigned short* Wb = W + ((size_t)e * 384 + bn) * Cch;
    const int wave = tid >> 6, lane = tid & 63;
    const int lr = lane & 15, lg = lane >> 4;
    const int wr = (wave >> 1) * 64, wc = (wave & 1) * 64;
    f32x4 acc[4][4] = {};

    for (int k0 = kc4 * 512; k0 < kc4 * 512 + 512; k0 += 64) {
        __syncthreads();
#pragma unroll
        for (int i = 0; i < 4; i++) {
            int t = i * 256 + tid;
            int row = t >> 3;
            int kc = (t & 7) << 3;
            __builtin_amdgcn_global_load_lds(
                (const __attribute__((address_space(1))) void*)(X + (size_t)toks[row] * Cch + k0 + kc),
                (__attribute__((address_space(3))) void*)(As + (i * 4 + wave) * 512),
                16, 0, 0);
        }
#pragma unroll
        for (int i = 0; i < 4; i++) {
            int t = i * 256 + tid;
            int row = t >> 3;
            int kc = (t & 7) << 3;
            __builtin_amdgcn_global_load_lds(
                (const __attribute__((address_space(1))) void*)(Wb + (size_t)row * Cch + k0 + kc),
                (__attribute__((address_space(3))) void*)(Bs + (i * 4 + wave) * 512),
                16, 0, 0);
        }
        __syncthreads();
#pragma unroll
        for (int kk = 0; kk < 2; kk++) {
            bf16x8 a[4], b[4];
#pragma unroll
            for (int m = 0; m < 4; m++)
                a[m] = *(const bf16x8*)(As + (wr + m * 16 + lr) * 64 + kk * 32 + lg * 8);
#pragma unroll
            for (int n = 0; n < 4; n++)
                b[n] = *(const bf16x8*)(Bs + (wc + n * 16 + lr) * 64 + kk * 32 + lg * 8);
#pragma unroll
            for (int m = 0; m < 4; m++)
#pragma unroll
                for (int n = 0; n < 4; n++)
                    acc[m][n] = __builtin_amdgcn_mfma_f32_16x16x32_bf16(a[m], b[n], acc[m][n], 0, 0, 0);
        }
    }
#pragma unroll
    for (int m = 0; m < 4; m++)
#pragma unroll
        for (int n = 0; n < 4; n++)
#pragma unroll
            for (int r = 0; r < 4; r++) {
                int slot = bm + wr + m * 16 + lg * 4 + r;
                int col = bn + wc + n * 16 + lr;
                if (slot < cn)
                    Ph[((size_t)e * CAP + slot) * 384 + col] = f2bf(acc[m][n][r]);
            }
}

// ---------------- combine q/k/v from NSPLIT split-K partials ----------------
__global__ __launch_bounds__(256) void combine_qkv(
    const unsigned short* __restrict__ P, const float* __restrict__ rw,
    const int* __restrict__ pos,
    unsigned short* __restrict__ qb, unsigned short* __restrict__ kb,
    unsigned short* __restrict__ vb) {
    int i = blockIdx.x * 256 + threadIdx.x;
    int n = i >> 5;
    int d4 = (i & 31) << 2;
    float aq[4] = {}, ak[4] = {}, av[4] = {};
#pragma unroll
    for (int e = 0; e < 16; e++) {
        int p = pos[(size_t)n * 16 + e];
        if (p >= 0) {
            float w = rw[(size_t)n * 16 + e];
            const unsigned short* r0 = P + ((size_t)e * CAP + p) * 384 + d4;
#pragma unroll
            for (int h = 0; h < NSPLIT; h++) {
                const unsigned short* rh = r0 + (size_t)h * PHALF;
                const u16x4 q4 = *(const u16x4*)(rh);
                const u16x4 k4 = *(const u16x4*)(rh + 128);
                const u16x4 v4 = *(const u16x4*)(rh + 256);
#pragma unroll
                for (int j = 0; j < 4; j++) {
                    aq[j] += w * bf2f(q4[j]);
                    ak[j] += w * bf2f(k4[j]);
                    av[j] += w * bf2f(v4[j]);
                }
            }
        }
    }
    u16x4 sq = {f2bf(aq[0]), f2bf(aq[1]), f2bf(aq[2]), f2bf(aq[3])};
    u16x4 sk = {f2bf(ak[0]), f2bf(ak[1]), f2bf(ak[2]), f2bf(ak[3])};
    u16x4 sv = {f2bf(av[0]), f2bf(av[1]), f2bf(av[2]), f2bf(av[3])};
    *(u16x4*)(qb + (size_t)n * Dd + d4) = sq;
    *(u16x4*)(kb + (size_t)n * Dd + d4) = sk;
    *(u16x4*)(vb + (size_t)n * Dd + d4) = sv;
}

// ---------------- causal row softmax, in-place f32 -> bf16 ----------------
__global__ __launch_bounds__(256) void softmax_kernel(float* __restrict__ scores) {
    int i = blockIdx.x, b = blockIdx.y;
    float* row = scores + ((size_t)b * Tt + i) * Tt;
    int nv = i + 1;
    float v[8];
    int cnt = 0;
    float mx = -1e30f;
    for (int j = threadIdx.x; j < nv; j += 256) {
        float t = row[j];
        v[cnt++] = t;
        mx = fmaxf(mx, t);
    }
    __shared__ float sred[4];
    int w = threadIdx.x >> 6;
#pragma unroll
    for (int off = 32; off; off >>= 1) mx = fmaxf(mx, __shfl_down(mx, off));
    if ((threadIdx.x & 63) == 0) sred[w] = mx;
    __syncthreads();
    float m = fmaxf(fmaxf(sred[0], sred[1]), fmaxf(sred[2], sred[3]));
    float s = 0.f;
    for (int t = 0; t < cnt; t++) {
        v[t] = __expf(v[t] - m);
        s += v[t];
    }
    __syncthreads();
#pragma unroll
    for (int off = 32; off; off >>= 1) s += __shfl_down(s, off);
    if ((threadIdx.x & 63) == 0) sred[w] = s;
    __syncthreads();
    float inv = 1.f / (sred[0] + sred[1] + sred[2] + sred[3]);
    unsigned short* prow = (unsigned short*)row;
    cnt = 0;
    for (int j = threadIdx.x; j < Tt; j += 256) {
        float pv = 0.f;
        if (j < nv) pv = v[cnt++] * inv;
        prow[j] = f2bf(pv);
    }
}

// ---------------- og2[n][256] = [rw_e0 * o | rw_e1 * o] (bf16) ----------------
__global__ __launch_bounds__(256) void og2_kernel(
    const float* __restrict__ ob, const float* __restrict__ rw,
    const int* __restrict__ onmaskv, unsigned short* __restrict__ og2) {
    int idx = blockIdx.x * 256 + threadIdx.x;  // (n, k4-group of 4)
    int n = idx >> 6;
    int k4 = (idx & 63) << 2;
    int m = onmaskv[n];
    if (!m) m = 1;
    int e0 = __ffs(m) - 1;
    int m2 = m & (m - 1);
    bool has2 = m2 != 0;
    int e1 = has2 ? (__ffs(m2) - 1) : e0;
    float wgt;
    int kb;
    if (k4 < 128) { wgt = rw[(size_t)n * 16 + e0]; kb = k4; }
    else { wgt = has2 ? rw[(size_t)n * 16 + e1] : 0.f; kb = k4 - 128; }
    const f32x4 o4 = *(const f32x4*)(ob + (size_t)n * Dd + kb);
    u16x4 st = {f2bf(wgt * o4[0]), f2bf(wgt * o4[1]), f2bf(wgt * o4[2]), f2bf(wgt * o4[3])};
    *(u16x4*)(og2 + (size_t)n * 256 + k4) = st;
}

// ---------------- pair-bucket output GEMM: out row written exactly once ----------------
__global__ __launch_bounds__(256) void gemm_pair(
    const unsigned short* __restrict__ og2,   // [Nn][256] bf16
    const unsigned short* __restrict__ woT,   // [2048 c][E*128] bf16
    const int* __restrict__ ptok, const int4* __restrict__ tiledesc,
    const int* __restrict__ ntile_dev,
    float* __restrict__ out) {
    if (blockIdx.x >= *ntile_dev) return;
    const int4 td = tiledesc[blockIdx.x];
    const int ei = td.x >> 4, ej = td.x & 15;
    const int mstart = td.y, mcnt = td.z;
    const int bn = blockIdx.y * 128;
    __shared__ alignas(16) unsigned short As[128 * 64];
    __shared__ alignas(16) unsigned short Bs[128 * 64];
    __shared__ int toks[128];
    const int tid = threadIdx.x;
    if (tid < 128) toks[tid] = ptok[mstart + min(tid, mcnt - 1)];
    const int wave = tid >> 6, lane = tid & 63;
    const int lr = lane & 15, lg = lane >> 4;
    const int wr = (wave >> 1) * 64, wc = (wave & 1) * 64;
    f32x4 acc[4][4] = {};

#pragma unroll
    for (int ck = 0; ck < 4; ck++) {
        const int ebase = (ck < 2 ? ei : ej) * 128 + (ck & 1) * 64;
        const int abase = ck * 64;
        __syncthreads();  // first iter: also guards toks
#pragma unroll
        for (int q = 0; q < 4; q++) {
            int t = q * 256 + tid;
            int row = t >> 3;
            int kc = (t & 7) << 3;
            __builtin_amdgcn_global_load_lds(
                (const __attribute__((address_space(1))) void*)(og2 + (size_t)toks[row] * 256 + abase + kc),
                (__attribute__((address_space(3))) void*)(As + (q * 4 + wave) * 512),
                16, 0, 0);
        }
#pragma unroll
        for (int q = 0; q < 4; q++) {
            int t = q * 256 + tid;
            int row = t >> 3;
            int kc = (t & 7) << 3;
            __builtin_amdgcn_global_load_lds(
                (const __attribute__((address_space(1))) void*)(woT + (size_t)(bn + row) * 2048 + ebase + kc),
                (__attribute__((address_space(3))) void*)(Bs + (q * 4 + wave) * 512),
                16, 0, 0);
        }
        __syncthreads();
#pragma unroll
        for (int kk = 0; kk < 2; kk++) {
            bf16x8 a[4], b[4];
#pragma unroll
            for (int m = 0; m < 4; m++)
                a[m] = *(const bf16x8*)(As + (wr + m * 16 + lr) * 64 + kk * 32 + lg * 8);
#pragma unroll
            for (int n = 0; n < 4; n++)
                b[n] = *(const bf16x8*)(Bs + (wc + n * 16 + lr) * 64 + kk * 32 + lg * 8);
#pragma unroll
            for (int m = 0; m < 4; m++)
#pragma unroll
                for (int n = 0; n < 4; n++)
                    acc[m][n] = __builtin_amdgcn_mfma_f32_16x16x32_bf16(a[m], b[n], acc[m][n], 0, 0, 0);
        }
    }
#pragma unroll
    for (int m = 0; m < 4; m++)
#pragma unroll
        for (int n = 0; n < 4; n++)
#pragma unroll
            for (int r = 0; r < 4; r++) {
                int rowt = wr + m * 16 + lg * 4 + r;
                if (rowt < mcnt) {
                    int tok = toks[rowt];
                    out[(size_t)tok * 2048 + bn + wc + n * 16 + lr] = acc[m][n][r];
                }
            }
}

// ---------------- rare overflow path: experts beyond the first two (empty here) ----------------
__global__ __launch_bounds__(256) void overflow_kernel(
    const int* __restrict__ ocnt, const int* __restrict__ olist,
    const float* __restrict__ ob, const unsigned short* __restrict__ woT,
    const float* __restrict__ rw, float* __restrict__ out) {
    const int ne = *ocnt;
    __shared__ float osh[128];
    for (int it = blockIdx.x; it < ne; it += gridDim.x) {
        int n = olist[2 * it], e = olist[2 * it + 1];
        float wgt = rw[(size_t)n * 16 + e];
        if (threadIdx.x < 128) osh[threadIdx.x] = ob[(size_t)n * Dd + threadIdx.x];
        __syncthreads();
#pragma unroll 1
        for (int cc = 0; cc < 8; cc++) {
            int c = threadIdx.x * 8 + cc;
            float a = 0.f;
            for (int k = 0; k < 128; k++)
                a += osh[k] * bf2f(woT[(size_t)c * 2048 + e * 128 + k]);
            atomicAdd(&out[(size_t)n * 2048 + c], wgt * a);
        }
        __syncthreads();
    }
}

extern "C" void kernel_launch(void* const* d_in, const int* in_sizes, int n_in,
                              void* d_out, int out_size, void* d_ws, size_t ws_size,
                              hipStream_t stream) {
    (void)in_sizes; (void)n_in; (void)out_size; (void)ws_size;
    const float* hidden = (const float*)d_in[0];
    const float* sim = (const float*)d_in[1];
    const float* gates = (const float*)d_in[2];
    const float* qp = (const float*)d_in[3];
    const float* kp = (const float*)d_in[4];
    const float* vp = (const float*)d_in[5];
    const float* op = (const float*)d_in[6];
    const int* minex = (const int*)d_in[7];
    float* out = (float*)d_out;

    char* w = (char*)d_ws;
    size_t off = 0;
    auto alloc = [&](size_t bytes) -> char* {
        char* p = w + off;
        off = (off + bytes + 255) & ~(size_t)255;
        return p;
    };
    unsigned short* xb = (unsigned short*)alloc((size_t)Nn * Cch * 2);
    unsigned short* wqkvT = (unsigned short*)alloc((size_t)Ee * 384 * Cch * 2);
    unsigned short* woT = (unsigned short*)alloc((size_t)Cch * Ee * Dd * 2);
    float* rw = (float*)alloc((size_t)Nn * Ee * 4);
    float* sninv = (float*)alloc(256);
    float* simT = (float*)alloc((size_t)Ee * Cch * 4);
    int* cnt = (int*)alloc(256);
    int* onmaskv = (int*)alloc((size_t)Nn * 4);
    int* idx = (int*)alloc((size_t)Ee * CAP * 4);
    int* pos = (int*)alloc((size_t)Nn * 16 * 4);
    int* ptok = (int*)alloc((size_t)Nn * 4);
    int4* tiledesc = (int4*)alloc((size_t)MAXTILES * 16);
    int* ntile_dev = (int*)alloc(256);
    int* ocnt = (int*)alloc(256);
    int* olist = (int*)alloc((size_t)Nn * 14 * 2 * 4);
    char* big = alloc((size_t)Bsz * Tt * Tt * 4);  // P partials (63MB) / scores (67MB)
    unsigned short* qb = (unsigned short*)alloc((size_t)Nn * Dd * 2);
    unsigned short* kb = (unsigned short*)alloc((size_t)Nn * Dd * 2);
    unsigned short* vb = (unsigned short*)alloc((size_t)Nn * Dd * 2);
    unsigned short* vT = (unsigned short*)alloc((size_t)Bsz * Dd * Tt * 2);
    float* ob = (float*)alloc((size_t)Nn * Dd * 4);
    unsigned short* og2 = (unsigned short*)alloc((size_t)Nn * 256 * 2);
    unsigned short* Pc = (unsigned short*)big;
    float* scores = (float*)big;

    const float scale = 0.08838834764831845f;  // 1/sqrt(128)

    colnorm_kernel<<<1, 256, 0, stream>>>(sim, sninv);
    simt_kernel<<<(Ee * Cch) / 256, 256, 0, stream>>>(sim, simT);
    gating5_kernel<<<Nn / 32, 1024, 0, stream>>>(hidden, simT, gates, sninv, minex, rw, xb, onmaskv);
    scan_kernel<<<Ee, 256, 0, stream>>>(onmaskv, idx, pos, cnt);
    scan_pair<<<1, 256, 0, stream>>>(onmaskv, ptok, tiledesc, ntile_dev, ocnt, olist);
    hipMemsetAsync(ob, 0, (size_t)Nn * Dd * 4, stream);

    // weight transposes (f32 -> bf16) into fused [E][384][C]
    transpose_f32_bf16<<<dim3(Dd / 32, Cch / 32, Ee), 256, 0, stream>>>(
        qp, wqkvT + 0 * Dd * Cch, Cch, Dd, (long)Cch * Dd, (long)384 * Cch);
    transpose_f32_bf16<<<dim3(Dd / 32, Cch / 32, Ee), 256, 0, stream>>>(
        kp, wqkvT + 1 * Dd * Cch, Cch, Dd, (long)Cch * Dd, (long)384 * Cch);
    transpose_f32_bf16<<<dim3(Dd / 32, Cch / 32, Ee), 256, 0, stream>>>(
        vp, wqkvT + 2 * Dd * Cch, Cch, Dd, (long)Cch * Dd, (long)384 * Cch);
    transpose_f32_bf16<<<dim3((Ee * Dd) / 32, Cch / 32, 1), 256, 0, stream>>>(
        op, woT, Ee * Dd, Cch, 0L, 0L);

    // gathered per-expert QKV projection (split-K=4), then combine
    gemm_qkv_gather<<<dim3(CAP / 128, 3, Ee * NSPLIT), 256, 0, stream>>>(xb, wqkvT, idx, cnt, Pc);
    combine_qkv<<<(Nn * 32) / 256, 256, 0, stream>>>(Pc, rw, pos, qb, kb, vb);

    // V transpose per batch
    transpose_u16<<<dim3(Dd / 32, Tt / 32, Bsz), 256, 0, stream>>>(
        vb, vT, Tt, Dd, (long)Tt * Dd, (long)Dd * Tt);

    // scores = Q K^T * scale (causal)
    gemm_nt<1><<<dim3(Tt / 128, Tt / 128, Bsz), 256, 0, stream>>>(
        qb, (long)Tt * Dd, Dd, kb, (long)Tt * Dd, Dd, scores, (long)Tt * Tt, Tt, Dd, scale);
    softmax_kernel<<<dim3(Tt, Bsz), 256, 0, stream>>>(scores);
    // O = P V  — split-K over causal-active 512-chunks, atomic accumulate
    gemm_pv<<<dim3(Tt / 128, Tt / 512, Bsz), 256, 0, stream>>>(
        (const unsigned short*)scores, vT, ob);

    // output projection: pair-bucket grouped GEMM, each out row stored exactly once
    og2_kernel<<<(Nn * 64) / 256, 256, 0, stream>>>(ob, rw, onmaskv, og2);
    gemm_pair<<<dim3(MAXTILES, Cch / 128), 256, 0, stream>>>(
        og2, woT, ptok, tiledesc, ntile_dev, out);
    overflow_kernel<<<256, 256, 0, stream>>>(ocnt, olist, ob, woT, rw, out);
}

// Round 11
// 329.441 us; speedup vs baseline: 1.3191x; 1.0471x over previous
//
#include <hip/hip_runtime.h>
#include <hip/hip_bf16.h>

#define DEV __device__ __forceinline__

typedef short bf16x8 __attribute__((ext_vector_type(8)));
typedef float f32x4 __attribute__((ext_vector_type(4)));
typedef unsigned short u16x4 __attribute__((ext_vector_type(4)));

static constexpr int Bsz = 4, Tt = 2048, Cch = 2048, Dd = 128, Ee = 16;
static constexpr int Nn = Bsz * Tt;
static constexpr int CAP = 1280;  // per-expert capacity (mean ~1024, sigma ~30 -> 8.5 sigma)
static constexpr int NSPLIT = 4;  // split-K partials for QKV gather
static constexpr size_t PHALF = (size_t)Ee * CAP * 384;  // elems per split-K partial (15.7MB)
static constexpr int MAXTILES = 320;  // >= 256 buckets + Nn/128
static constexpr int MT = CAP / 128;          // m-tiles per expert (10)
static constexpr int NGRP = MT * Ee * NSPLIT; // groups = 640; each group = 3 column tiles

DEV unsigned short f2bf(float v) {
    __hip_bfloat16 h = __float2bfloat16(v);
    return __builtin_bit_cast(unsigned short, h);
}
DEV float bf2f(unsigned short u) {
    unsigned int x = ((unsigned int)u) << 16;
    return __builtin_bit_cast(float, x);
}

// ---------------- sim_matrix column norms ----------------
__global__ __launch_bounds__(256) void colnorm_kernel(const float* __restrict__ sim,
                                                      float* __restrict__ sninv) {
    int e = threadIdx.x & 15, j = threadIdx.x >> 4;
    float ss = 0.f;
    for (int r = j; r < Cch; r += 16) {
        float v = sim[r * Ee + e];
        ss += v * v;
    }
    __shared__ float red[16][17];
    red[j][e] = ss;
    __syncthreads();
    if (threadIdx.x < 16) {
        float s = 0.f;
        for (int t = 0; t < 16; t++) s += red[t][threadIdx.x];
        sninv[threadIdx.x] = 1.f / fmaxf(sqrtf(s), 1e-12f);
    }
}

// ---------------- sim transpose: simT[e][c] = sim[c][e] ----------------
__global__ __launch_bounds__(256) void simt_kernel(const float* __restrict__ sim,
                                                   float* __restrict__ simT) {
    int i = blockIdx.x * 256 + threadIdx.x;  // 16*2048
    int e = i >> 11, c = i & 2047;
    simT[i] = sim[c * 16 + e];
}

// ---------------- gating: full simT in 128 KiB LDS; 1024 threads (16 waves/CU) ----------------
__global__ __launch_bounds__(1024) void gating5_kernel(
    const float* __restrict__ x, const float* __restrict__ simT,
    const float* __restrict__ gates, const float* __restrict__ sninv,
    const int* __restrict__ minex,
    float* __restrict__ rw, unsigned short* __restrict__ xb,
    int* __restrict__ onmaskv) {
    __shared__ f32x4 ssim[8192];  // 128 KiB = full simT in f32
    const int tid = threadIdx.x;
    const f32x4* stg = (const f32x4*)simT;
#pragma unroll
    for (int i = 0; i < 8; i++) ssim[i * 1024 + tid] = stg[i * 1024 + tid];
    __syncthreads();
    const int wave = tid >> 6, lane = tid & 63;

#pragma unroll 1
    for (int g = 0; g < 2; g++) {
        const int n = blockIdx.x * 32 + g * 16 + wave;
        const f32x4* xr = (const f32x4*)(x + (size_t)n * Cch);
        u16x4* xbr = (u16x4*)(xb + (size_t)n * Cch);
        float ss = 0.f;
        float d[16];
#pragma unroll
        for (int e = 0; e < 16; e++) d[e] = 0.f;

#pragma unroll 2
        for (int it = 0; it < 8; it++) {
            const int i = it * 64 + lane;
            const f32x4 xv = xr[i];
            ss += xv[0] * xv[0] + xv[1] * xv[1] + xv[2] * xv[2] + xv[3] * xv[3];
            u16x4 xc = {f2bf(xv[0]), f2bf(xv[1]), f2bf(xv[2]), f2bf(xv[3])};
            xbr[i] = xc;
#pragma unroll
            for (int e = 0; e < 16; e++) {
                const f32x4 sv = ssim[e * 512 + i];
                d[e] += xv[0] * sv[0] + xv[1] * sv[1] + xv[2] * sv[2] + xv[3] * sv[3];
            }
        }
#pragma unroll
        for (int off = 32; off; off >>= 1) {
            ss += __shfl_down(ss, off);
#pragma unroll
            for (int e = 0; e < 16; e++) d[e] += __shfl_down(d[e], off);
        }
        if (lane == 0) {
            float inv = 1.f / fmaxf(sqrtf(ss), 1e-12f);
            float logit[16];
            int onmask = 0;
#pragma unroll
            for (int e = 0; e < 16; e++) {
                float sg = 1.f / (1.f + __expf(-gates[e]));
                float l = d[e] * inv * sninv[e] - sg;
                logit[e] = l;
                if (l > 0.f) onmask |= (1 << e);
            }
            if (onmask == 0) {
                int k = *minex;
                int ch = 0;
                for (int kk = 0; kk < k; kk++) {
                    float bv = -1e30f;
                    int be = 0;
#pragma unroll
                    for (int e = 0; e < 16; e++)
                        if (!((ch >> e) & 1) && logit[e] > bv) { bv = logit[e]; be = e; }
                    ch |= (1 << be);
                }
                onmask = ch;
            }
            float mx = -1e30f;
#pragma unroll
            for (int e = 0; e < 16; e++)
                if ((onmask >> e) & 1) mx = fmaxf(mx, fmaxf(logit[e], 0.f));
            float pe[16];
            float sum = 0.f;
#pragma unroll
            for (int e = 0; e < 16; e++) {
                pe[e] = ((onmask >> e) & 1) ? __expf(fmaxf(logit[e], 0.f) - mx) : 0.f;
                sum += pe[e];
            }
            float isum = 1.f / sum;
#pragma unroll
            for (int e = 0; e < 16; e++) rw[(size_t)n * 16 + e] = pe[e] * isum;
            onmaskv[n] = onmask;
        }
    }
}

// ---------------- deterministic expert-list scan (for QKV gather) ----------------
__global__ __launch_bounds__(256) void scan_kernel(
    const int* __restrict__ onmaskv,
    int* __restrict__ idx, int* __restrict__ pos, int* __restrict__ cnt) {
    const int e = blockIdx.x;
    const int tid = threadIdx.x;
    const int base = tid * 32;
    int om[32];
    int c = 0;
#pragma unroll
    for (int i = 0; i < 32; i++) {
        om[i] = (onmaskv[base + i] >> e) & 1;
        c += om[i];
    }
    const int lane = tid & 63, w = tid >> 6;
    int sc = c;
#pragma unroll
    for (int off = 1; off < 64; off <<= 1) {
        int t = __shfl_up(sc, off);
        if (lane >= off) sc += t;
    }
    __shared__ int wsum[4];
    if (lane == 63) wsum[w] = sc;
    __syncthreads();
    int wbase = 0;
    for (int i = 0; i < w; i++) wbase += wsum[i];
    int slot = wbase + sc - c;
#pragma unroll
    for (int i = 0; i < 32; i++) {
        int n = base + i;
        int p = -1;
        if (om[i]) {
            if (slot < CAP) {
                idx[(size_t)e * CAP + slot] = n;
                p = slot;
            }
            slot++;
        }
        pos[(size_t)n * 16 + e] = p;
    }
    if (tid == 255) cnt[e] = slot;
}

// ---------------- pair-bucket scan for output projection ----------------
__global__ __launch_bounds__(256) void scan_pair(
    const int* __restrict__ onmaskv,
    int* __restrict__ ptok, int4* __restrict__ tiledesc, int* __restrict__ ntile_dev,
    int* __restrict__ ocnt, int* __restrict__ olist) {
    __shared__ int hist[256], cursor[256];
    __shared__ int wsum[4], wsum2[4];
    const int tid = threadIdx.x;
    if (tid == 0) *ocnt = 0;
    hist[tid] = 0;
    __syncthreads();
    for (int i = 0; i < 32; i++) {
        int n = tid * 32 + i;
        int m = onmaskv[n];
        if (!m) m = 1;
        int e0 = __ffs(m) - 1;
        int m2 = m & (m - 1);
        int e1 = m2 ? (__ffs(m2) - 1) : e0;
        atomicAdd(&hist[e0 * 16 + e1], 1);
        int mrest = m2 & (m2 - 1);
        while (mrest) {
            int e = __ffs(mrest) - 1;
            int s = atomicAdd(ocnt, 1);
            olist[2 * s] = n;
            olist[2 * s + 1] = e;
            mrest &= (mrest - 1);
        }
    }
    __syncthreads();
    const int lane = tid & 63, w = tid >> 6;
    int v = hist[tid];
    int s = v;
#pragma unroll
    for (int off = 1; off < 64; off <<= 1) {
        int t = __shfl_up(s, off);
        if (lane >= off) s += t;
    }
    if (lane == 63) wsum[w] = s;
    __syncthreads();
    int add = 0;
    for (int i = 0; i < w; i++) add += wsum[i];
    int excl = s + add - v;
    cursor[tid] = excl;
    int nt = (v + 127) >> 7;
    int s2 = nt;
#pragma unroll
    for (int off = 1; off < 64; off <<= 1) {
        int t = __shfl_up(s2, off);
        if (lane >= off) s2 += t;
    }
    if (lane == 63) wsum2[w] = s2;
    __syncthreads();
    int add2 = 0;
    for (int i = 0; i < w; i++) add2 += wsum2[i];
    int texcl = s2 + add2 - nt;
    for (int m = 0; m < nt; m++)
        tiledesc[texcl + m] = make_int4(tid, excl + m * 128, min(128, v - m * 128), 0);
    if (tid == 255) *ntile_dev = texcl + nt;
    __syncthreads();
    for (int i = 0; i < 32; i++) {
        int n = tid * 32 + i;
        int m = onmaskv[n];
        if (!m) m = 1;
        int e0 = __ffs(m) - 1;
        int m2 = m & (m - 1);
        int e1 = m2 ? (__ffs(m2) - 1) : e0;
        int slot = atomicAdd(&cursor[e0 * 16 + e1], 1);
        ptok[slot] = n;
    }
}

// ---------------- transposes ----------------
__global__ __launch_bounds__(256) void transpose_f32_bf16(
    const float* __restrict__ src, unsigned short* __restrict__ dst,
    int R, int Ccol, long ss, long ds) {
    __shared__ float tile[32][33];
    src += (size_t)blockIdx.z * ss;
    dst += (size_t)blockIdx.z * ds;
    int bx = blockIdx.x * 32, by = blockIdx.y * 32;
    int tx = threadIdx.x & 31, ty = threadIdx.x >> 5;
#pragma unroll
    for (int i = 0; i < 4; i++)
        tile[ty + i * 8][tx] = src[(size_t)(by + ty + i * 8) * Ccol + bx + tx];
    __syncthreads();
#pragma unroll
    for (int i = 0; i < 4; i++)
        dst[(size_t)(bx + ty + i * 8) * R + by + tx] = f2bf(tile[tx][ty + i * 8]);
}

__global__ __launch_bounds__(256) void transpose_u16(
    const unsigned short* __restrict__ src, unsigned short* __restrict__ dst,
    int R, int Ccol, long ss, long ds) {
    __shared__ unsigned short tile[32][33];
    src += (size_t)blockIdx.z * ss;
    dst += (size_t)blockIdx.z * ds;
    int bx = blockIdx.x * 32, by = blockIdx.y * 32;
    int tx = threadIdx.x & 31, ty = threadIdx.x >> 5;
#pragma unroll
    for (int i = 0; i < 4; i++)
        tile[ty + i * 8][tx] = src[(size_t)(by + ty + i * 8) * Ccol + bx + tx];
    __syncthreads();
#pragma unroll
    for (int i = 0; i < 4; i++)
        dst[(size_t)(bx + ty + i * 8) * R + by + tx] = tile[tx][ty + i * 8];
}

// ---------------- NT GEMM: Out[M,N] = A[M,K] * BT[N,K]^T (bf16 in, f32 out) ----------------
template <int CAUSAL>
__global__ __launch_bounds__(256) void gemm_nt(
    const unsigned short* __restrict__ A, long strideA, int lda,
    const unsigned short* __restrict__ BT, long strideB, int ldb,
    float* __restrict__ Out, long strideO, int ldo,
    int K, float scale) {
    __shared__ alignas(16) unsigned short As[128 * 64];
    __shared__ alignas(16) unsigned short Bs[128 * 64];
    const int bm = blockIdx.x * 128;
    const int bn = blockIdx.y * 128;
    if (CAUSAL && bn > bm + 127) return;
    A += (size_t)blockIdx.z * strideA;
    BT += (size_t)blockIdx.z * strideB;
    Out += (size_t)blockIdx.z * strideO;
    const int tid = threadIdx.x;
    const int wave = tid >> 6, lane = tid & 63;
    const int lr = lane & 15, lg = lane >> 4;
    const int wr = (wave >> 1) * 64, wc = (wave & 1) * 64;
    f32x4 acc[4][4] = {};

    for (int k0 = 0; k0 < K; k0 += 64) {
        __syncthreads();
#pragma unroll
        for (int i = 0; i < 4; i++) {
            int t = i * 256 + tid;
            int row = t >> 3;
            int kc = (t & 7) << 3;
            __builtin_amdgcn_global_load_lds(
                (const __attribute__((address_space(1))) void*)(A + (size_t)(bm + row) * lda + k0 + kc),
                (__attribute__((address_space(3))) void*)(As + (i * 4 + wave) * 512),
                16, 0, 0);
        }
#pragma unroll
        for (int i = 0; i < 4; i++) {
            int t = i * 256 + tid;
            int row = t >> 3;
            int kc = (t & 7) << 3;
            __builtin_amdgcn_global_load_lds(
                (const __attribute__((address_space(1))) void*)(BT + (size_t)(bn + row) * ldb + k0 + kc),
                (__attribute__((address_space(3))) void*)(Bs + (i * 4 + wave) * 512),
                16, 0, 0);
        }
        __syncthreads();
#pragma unroll
        for (int kk = 0; kk < 2; kk++) {
            bf16x8 a[4], b[4];
#pragma unroll
            for (int m = 0; m < 4; m++)
                a[m] = *(const bf16x8*)(As + (wr + m * 16 + lr) * 64 + kk * 32 + lg * 8);
#pragma unroll
            for (int n = 0; n < 4; n++)
                b[n] = *(const bf16x8*)(Bs + (wc + n * 16 + lr) * 64 + kk * 32 + lg * 8);
#pragma unroll
            for (int m = 0; m < 4; m++)
#pragma unroll
                for (int n = 0; n < 4; n++)
                    acc[m][n] = __builtin_amdgcn_mfma_f32_16x16x32_bf16(a[m], b[n], acc[m][n], 0, 0, 0);
        }
    }
#pragma unroll
    for (int m = 0; m < 4; m++) {
#pragma unroll
        for (int n = 0; n < 4; n++) {
#pragma unroll
            for (int r = 0; r < 4; r++) {
                int grow = bm + wr + m * 16 + lg * 4 + r;
                int gcol = bn + wc + n * 16 + lr;
                if (!CAUSAL || gcol <= grow)
                    Out[(size_t)grow * ldo + gcol] = acc[m][n][r] * scale;
            }
        }
    }
}

// ---------------- PV GEMM: split-K over causal-active chunks, atomic f32 accumulate ----------------
__global__ __launch_bounds__(256) void gemm_pv(
    const unsigned short* __restrict__ P, const unsigned short* __restrict__ vT,
    float* __restrict__ ob) {
    const int bm = blockIdx.x * 128;
    const int kb = blockIdx.y * 512;
    if (kb > bm + 127) return;
    const unsigned short* Pb = P + (size_t)blockIdx.z * Tt * 4096;
    const unsigned short* Vb = vT + (size_t)blockIdx.z * Dd * Tt;
    float* Ob = ob + (size_t)blockIdx.z * Tt * Dd;
    __shared__ alignas(16) unsigned short As[128 * 64];
    __shared__ alignas(16) unsigned short Bs[128 * 64];
    const int tid = threadIdx.x;
    const int wave = tid >> 6, lane = tid & 63;
    const int lr = lane & 15, lg = lane >> 4;
    const int wr = (wave >> 1) * 64, wc = (wave & 1) * 64;
    f32x4 acc[4][4] = {};

    for (int k0 = kb; k0 < kb + 512; k0 += 64) {
        __syncthreads();
#pragma unroll
        for (int i = 0; i < 4; i++) {
            int t = i * 256 + tid;
            int row = t >> 3;
            int kc = (t & 7) << 3;
            __builtin_amdgcn_global_load_lds(
                (const __attribute__((address_space(1))) void*)(Pb + (size_t)(bm + row) * 4096 + k0 + kc),
                (__attribute__((address_space(3))) void*)(As + (i * 4 + wave) * 512),
                16, 0, 0);
        }
#pragma unroll
        for (int i = 0; i < 4; i++) {
            int t = i * 256 + tid;
            int row = t >> 3;
            int kc = (t & 7) << 3;
            __builtin_amdgcn_global_load_lds(
                (const __attribute__((address_space(1))) void*)(Vb + (size_t)row * Tt + k0 + kc),
                (__attribute__((address_space(3))) void*)(Bs + (i * 4 + wave) * 512),
                16, 0, 0);
        }
        __syncthreads();
#pragma unroll
        for (int kk = 0; kk < 2; kk++) {
            bf16x8 a[4], b[4];
#pragma unroll
            for (int m = 0; m < 4; m++)
                a[m] = *(const bf16x8*)(As + (wr + m * 16 + lr) * 64 + kk * 32 + lg * 8);
#pragma unroll
            for (int n = 0; n < 4; n++)
                b[n] = *(const bf16x8*)(Bs + (wc + n * 16 + lr) * 64 + kk * 32 + lg * 8);
#pragma unroll
            for (int m = 0; m < 4; m++)
#pragma unroll
                for (int n = 0; n < 4; n++)
                    acc[m][n] = __builtin_amdgcn_mfma_f32_16x16x32_bf16(a[m], b[n], acc[m][n], 0, 0, 0);
        }
    }
#pragma unroll
    for (int m = 0; m < 4; m++)
#pragma unroll
        for (int n = 0; n < 4; n++)
#pragma unroll
            for (int r = 0; r < 4; r++) {
                int grow = bm + wr + m * 16 + lg * 4 + r;
                int gcol = wc + n * 16 + lr;
                atomicAdd(&Ob[(size_t)grow * Dd + gcol], acc[m][n][r]);
            }
}

// ---------------- gathered QKV projection, split-K=4, XCD-group swizzle ----------------
// 1D grid (1920). Groups of 3 column-tiles share the same A rows; members are
// placed at L = r + 8*(3*gq + j) so all 3 share L%8 (same XCD) -> A fetched
// from HBM once, L2-hit twice.
__global__ __launch_bounds__(256) void gemm_qkv_gather(
    const unsigned short* __restrict__ X, const unsigned short* __restrict__ W,
    const int* __restrict__ idx, const int* __restrict__ cnt,
    unsigned short* __restrict__ P) {
    const int L = blockIdx.x;
    const int r = L & 7, s = L >> 3;
    const int gq = s / 3, j = s - gq * 3;   // j = column tile (0..2)
    const int g = gq * 8 + r;               // group in [0, NGRP)
    const int m = g % MT;                   // m-tile
    const int zc = g / MT;                  // (e, kchunk)
    const int e = zc >> 2, kc4 = zc & 3;
    const int cn = min(cnt[e], CAP);
    const int bm = m * 128;
    if (bm >= cn) return;
    const int bn = j * 128;
    unsigned short* Ph = P + (size_t)kc4 * PHALF;
    __shared__ alignas(16) unsigned short As[128 * 64];
    __shared__ alignas(16) unsigned short Bs[128 * 64];
    __shared__ int toks[128];
    const int tid = threadIdx.x;
    if (tid < 128) toks[tid] = idx[(size_t)e * CAP + min(bm + tid, cn - 1)];
    const unsigned short* Wb = W + ((size_t)e * 384 + bn) * Cch;
    const int wave = tid >> 6, lane = tid & 63;
    const int lr = lane & 15, lg = lane >> 4;
    const int wr = (wave >> 1) * 64, wc = (wave & 1) * 64;
    f32x4 acc[4][4] = {};

    for (int k0 = kc4 * 512; k0 < kc4 * 512 + 512; k0 += 64) {
        __syncthreads();
#pragma unroll
        for (int i = 0; i < 4; i++) {
            int t = i * 256 + tid;
            int row = t >> 3;
            int kc = (t & 7) << 3;
            __builtin_amdgcn_global_load_lds(
                (const __attribute__((address_space(1))) void*)(X + (size_t)toks[row] * Cch + k0 + kc),
                (__attribute__((address_space(3))) void*)(As + (i * 4 + wave) * 512),
                16, 0, 0);
        }
#pragma unroll
        for (int i = 0; i < 4; i++) {
            int t = i * 256 + tid;
            int row = t >> 3;
            int kc = (t & 7) << 3;
            __builtin_amdgcn_global_load_lds(
                (const __attribute__((address_space(1))) void*)(Wb + (size_t)row * Cch + k0 + kc),
                (__attribute__((address_space(3))) void*)(Bs + (i * 4 + wave) * 512),
                16, 0, 0);
        }
        __syncthreads();
#pragma unroll
        for (int kk = 0; kk < 2; kk++) {
            bf16x8 a[4], b[4];
#pragma unroll
            for (int m2 = 0; m2 < 4; m2++)
                a[m2] = *(const bf16x8*)(As + (wr + m2 * 16 + lr) * 64 + kk * 32 + lg * 8);
#pragma unroll
            for (int n = 0; n < 4; n++)
                b[n] = *(const bf16x8*)(Bs + (wc + n * 16 + lr) * 64 + kk * 32 + lg * 8);
#pragma unroll
            for (int m2 = 0; m2 < 4; m2++)
#pragma unroll
                for (int n = 0; n < 4; n++)
                    acc[m2][n] = __builtin_amdgcn_mfma_f32_16x16x32_bf16(a[m2], b[n], acc[m2][n], 0, 0, 0);
        }
    }
#pragma unroll
    for (int m2 = 0; m2 < 4; m2++)
#pragma unroll
        for (int n = 0; n < 4; n++)
#pragma unroll
            for (int rr = 0; rr < 4; rr++) {
                int slot = bm + wr + m2 * 16 + lg * 4 + rr;
                int col = bn + wc + n * 16 + lr;
                if (slot < cn)
                    Ph[((size_t)e * CAP + slot) * 384 + col] = f2bf(acc[m2][n][rr]);
            }
}

// ---------------- combine q/k/v from NSPLIT split-K partials ----------------
__global__ __launch_bounds__(256) void combine_qkv(
    const unsigned short* __restrict__ P, const float* __restrict__ rw,
    const int* __restrict__ pos,
    unsigned short* __restrict__ qb, unsigned short* __restrict__ kb,
    unsigned short* __restrict__ vb) {
    int i = blockIdx.x * 256 + threadIdx.x;
    int n = i >> 5;
    int d4 = (i & 31) << 2;
    float aq[4] = {}, ak[4] = {}, av[4] = {};
#pragma unroll
    for (int e = 0; e < 16; e++) {
        int p = pos[(size_t)n * 16 + e];
        if (p >= 0) {
            float w = rw[(size_t)n * 16 + e];
            const unsigned short* r0 = P + ((size_t)e * CAP + p) * 384 + d4;
#pragma unroll
            for (int h = 0; h < NSPLIT; h++) {
                const unsigned short* rh = r0 + (size_t)h * PHALF;
                const u16x4 q4 = *(const u16x4*)(rh);
                const u16x4 k4 = *(const u16x4*)(rh + 128);
                const u16x4 v4 = *(const u16x4*)(rh + 256);
#pragma unroll
                for (int jj = 0; jj < 4; jj++) {
                    aq[jj] += w * bf2f(q4[jj]);
                    ak[jj] += w * bf2f(k4[jj]);
                    av[jj] += w * bf2f(v4[jj]);
                }
            }
        }
    }
    u16x4 sq = {f2bf(aq[0]), f2bf(aq[1]), f2bf(aq[2]), f2bf(aq[3])};
    u16x4 sk = {f2bf(ak[0]), f2bf(ak[1]), f2bf(ak[2]), f2bf(ak[3])};
    u16x4 sv = {f2bf(av[0]), f2bf(av[1]), f2bf(av[2]), f2bf(av[3])};
    *(u16x4*)(qb + (size_t)n * Dd + d4) = sq;
    *(u16x4*)(kb + (size_t)n * Dd + d4) = sk;
    *(u16x4*)(vb + (size_t)n * Dd + d4) = sv;
}

// ---------------- causal row softmax, in-place f32 -> bf16 ----------------
__global__ __launch_bounds__(256) void softmax_kernel(float* __restrict__ scores) {
    int i = blockIdx.x, b = blockIdx.y;
    float* row = scores + ((size_t)b * Tt + i) * Tt;
    int nv = i + 1;
    float v[8];
    int cnt = 0;
    float mx = -1e30f;
    for (int j = threadIdx.x; j < nv; j += 256) {
        float t = row[j];
        v[cnt++] = t;
        mx = fmaxf(mx, t);
    }
    __shared__ float sred[4];
    int w = threadIdx.x >> 6;
#pragma unroll
    for (int off = 32; off; off >>= 1) mx = fmaxf(mx, __shfl_down(mx, off));
    if ((threadIdx.x & 63) == 0) sred[w] = mx;
    __syncthreads();
    float m = fmaxf(fmaxf(sred[0], sred[1]), fmaxf(sred[2], sred[3]));
    float s = 0.f;
    for (int t = 0; t < cnt; t++) {
        v[t] = __expf(v[t] - m);
        s += v[t];
    }
    __syncthreads();
#pragma unroll
    for (int off = 32; off; off >>= 1) s += __shfl_down(s, off);
    if ((threadIdx.x & 63) == 0) sred[w] = s;
    __syncthreads();
    float inv = 1.f / (sred[0] + sred[1] + sred[2] + sred[3]);
    unsigned short* prow = (unsigned short*)row;
    cnt = 0;
    for (int j = threadIdx.x; j < Tt; j += 256) {
        float pv = 0.f;
        if (j < nv) pv = v[cnt++] * inv;
        prow[j] = f2bf(pv);
    }
}

// ---------------- og2[n][256] = [rw_e0 * o | rw_e1 * o] (bf16) ----------------
__global__ __launch_bounds__(256) void og2_kernel(
    const float* __restrict__ ob, const float* __restrict__ rw,
    const int* __restrict__ onmaskv, unsigned short* __restrict__ og2) {
    int idx = blockIdx.x * 256 + threadIdx.x;  // (n, k4-group of 4)
    int n = idx >> 6;
    int k4 = (idx & 63) << 2;
    int m = onmaskv[n];
    if (!m) m = 1;
    int e0 = __ffs(m) - 1;
    int m2 = m & (m - 1);
    bool has2 = m2 != 0;
    int e1 = has2 ? (__ffs(m2) - 1) : e0;
    float wgt;
    int kb;
    if (k4 < 128) { wgt = rw[(size_t)n * 16 + e0]; kb = k4; }
    else { wgt = has2 ? rw[(size_t)n * 16 + e1] : 0.f; kb = k4 - 128; }
    const f32x4 o4 = *(const f32x4*)(ob + (size_t)n * Dd + kb);
    u16x4 st = {f2bf(wgt * o4[0]), f2bf(wgt * o4[1]), f2bf(wgt * o4[2]), f2bf(wgt * o4[3])};
    *(u16x4*)(og2 + (size_t)n * 256 + k4) = st;
}

// ---------------- pair-bucket output GEMM: out row written exactly once ----------------
__global__ __launch_bounds__(256) void gemm_pair(
    const unsigned short* __restrict__ og2,   // [Nn][256] bf16
    const unsigned short* __restrict__ woT,   // [2048 c][E*128] bf16
    const int* __restrict__ ptok, const int4* __restrict__ tiledesc,
    const int* __restrict__ ntile_dev,
    float* __restrict__ out) {
    if (blockIdx.x >= *ntile_dev) return;
    const int4 td = tiledesc[blockIdx.x];
    const int ei = td.x >> 4, ej = td.x & 15;
    const int mstart = td.y, mcnt = td.z;
    const int bn = blockIdx.y * 128;
    __shared__ alignas(16) unsigned short As[128 * 64];
    __shared__ alignas(16) unsigned short Bs[128 * 64];
    __shared__ int toks[128];
    const int tid = threadIdx.x;
    if (tid < 128) toks[tid] = ptok[mstart + min(tid, mcnt - 1)];
    const int wave = tid >> 6, lane = tid & 63;
    const int lr = lane & 15, lg = lane >> 4;
    const int wr = (wave >> 1) * 64, wc = (wave & 1) * 64;
    f32x4 acc[4][4] = {};

#pragma unroll
    for (int ck = 0; ck < 4; ck++) {
        const int ebase = (ck < 2 ? ei : ej) * 128 + (ck & 1) * 64;
        const int abase = ck * 64;
        __syncthreads();  // first iter: also guards toks
#pragma unroll
        for (int q = 0; q < 4; q++) {
            int t = q * 256 + tid;
            int row = t >> 3;
            int kc = (t & 7) << 3;
            __builtin_amdgcn_global_load_lds(
                (const __attribute__((address_space(1))) void*)(og2 + (size_t)toks[row] * 256 + abase + kc),
                (__attribute__((address_space(3))) void*)(As + (q * 4 + wave) * 512),
                16, 0, 0);
        }
#pragma unroll
        for (int q = 0; q < 4; q++) {
            int t = q * 256 + tid;
            int row = t >> 3;
            int kc = (t & 7) << 3;
            __builtin_amdgcn_global_load_lds(
                (const __attribute__((address_space(1))) void*)(woT + (size_t)(bn + row) * 2048 + ebase + kc),
                (__attribute__((address_space(3))) void*)(Bs + (q * 4 + wave) * 512),
                16, 0, 0);
        }
        __syncthreads();
#pragma unroll
        for (int kk = 0; kk < 2; kk++) {
            bf16x8 a[4], b[4];
#pragma unroll
            for (int m = 0; m < 4; m++)
                a[m] = *(const bf16x8*)(As + (wr + m * 16 + lr) * 64 + kk * 32 + lg * 8);
#pragma unroll
            for (int n = 0; n < 4; n++)
                b[n] = *(const bf16x8*)(Bs + (wc + n * 16 + lr) * 64 + kk * 32 + lg * 8);
#pragma unroll
            for (int m = 0; m < 4; m++)
#pragma unroll
                for (int n = 0; n < 4; n++)
                    acc[m][n] = __builtin_amdgcn_mfma_f32_16x16x32_bf16(a[m], b[n], acc[m][n], 0, 0, 0);
        }
    }
#pragma unroll
    for (int m = 0; m < 4; m++)
#pragma unroll
        for (int n = 0; n < 4; n++)
#pragma unroll
            for (int r = 0; r < 4; r++) {
                int rowt = wr + m * 16 + lg * 4 + r;
                if (rowt < mcnt) {
                    int tok = toks[rowt];
                    out[(size_t)tok * 2048 + bn + wc + n * 16 + lr] = acc[m][n][r];
                }
            }
}

// ---------------- rare overflow path: experts beyond the first two (empty here) ----------------
__global__ __launch_bounds__(256) void overflow_kernel(
    const int* __restrict__ ocnt, const int* __restrict__ olist,
    const float* __restrict__ ob, const unsigned short* __restrict__ woT,
    const float* __restrict__ rw, float* __restrict__ out) {
    const int ne = *ocnt;
    __shared__ float osh[128];
    for (int it = blockIdx.x; it < ne; it += gridDim.x) {
        int n = olist[2 * it], e = olist[2 * it + 1];
        float wgt = rw[(size_t)n * 16 + e];
        if (threadIdx.x < 128) osh[threadIdx.x] = ob[(size_t)n * Dd + threadIdx.x];
        __syncthreads();
#pragma unroll 1
        for (int cc = 0; cc < 8; cc++) {
            int c = threadIdx.x * 8 + cc;
            float a = 0.f;
            for (int k = 0; k < 128; k++)
                a += osh[k] * bf2f(woT[(size_t)c * 2048 + e * 128 + k]);
            atomicAdd(&out[(size_t)n * 2048 + c], wgt * a);
        }
        __syncthreads();
    }
}

extern "C" void kernel_launch(void* const* d_in, const int* in_sizes, int n_in,
                              void* d_out, int out_size, void* d_ws, size_t ws_size,
                              hipStream_t stream) {
    (void)in_sizes; (void)n_in; (void)out_size; (void)ws_size;
    const float* hidden = (const float*)d_in[0];
    const float* sim = (const float*)d_in[1];
    const float* gates = (const float*)d_in[2];
    const float* qp = (const float*)d_in[3];
    const float* kp = (const float*)d_in[4];
    const float* vp = (const float*)d_in[5];
    const float* op = (const float*)d_in[6];
    const int* minex = (const int*)d_in[7];
    float* out = (float*)d_out;

    char* w = (char*)d_ws;
    size_t off = 0;
    auto alloc = [&](size_t bytes) -> char* {
        char* p = w + off;
        off = (off + bytes + 255) & ~(size_t)255;
        return p;
    };
    unsigned short* xb = (unsigned short*)alloc((size_t)Nn * Cch * 2);
    unsigned short* wqkvT = (unsigned short*)alloc((size_t)Ee * 384 * Cch * 2);
    unsigned short* woT = (unsigned short*)alloc((size_t)Cch * Ee * Dd * 2);
    float* rw = (float*)alloc((size_t)Nn * Ee * 4);
    float* sninv = (float*)alloc(256);
    float* simT = (float*)alloc((size_t)Ee * Cch * 4);
    int* cnt = (int*)alloc(256);
    int* onmaskv = (int*)alloc((size_t)Nn * 4);
    int* idx = (int*)alloc((size_t)Ee * CAP * 4);
    int* pos = (int*)alloc((size_t)Nn * 16 * 4);
    int* ptok = (int*)alloc((size_t)Nn * 4);
    int4* tiledesc = (int4*)alloc((size_t)MAXTILES * 16);
    int* ntile_dev = (int*)alloc(256);
    int* ocnt = (int*)alloc(256);
    int* olist = (int*)alloc((size_t)Nn * 14 * 2 * 4);
    char* big = alloc((size_t)Bsz * Tt * Tt * 4);  // P partials (63MB) / scores (67MB)
    unsigned short* qb = (unsigned short*)alloc((size_t)Nn * Dd * 2);
    unsigned short* kb = (unsigned short*)alloc((size_t)Nn * Dd * 2);
    unsigned short* vb = (unsigned short*)alloc((size_t)Nn * Dd * 2);
    unsigned short* vT = (unsigned short*)alloc((size_t)Bsz * Dd * Tt * 2);
    float* ob = (float*)alloc((size_t)Nn * Dd * 4);
    unsigned short* og2 = (unsigned short*)alloc((size_t)Nn * 256 * 2);
    unsigned short* Pc = (unsigned short*)big;
    float* scores = (float*)big;

    const float scale = 0.08838834764831845f;  // 1/sqrt(128)

    colnorm_kernel<<<1, 256, 0, stream>>>(sim, sninv);
    simt_kernel<<<(Ee * Cch) / 256, 256, 0, stream>>>(sim, simT);
    gating5_kernel<<<Nn / 32, 1024, 0, stream>>>(hidden, simT, gates, sninv, minex, rw, xb, onmaskv);
    scan_kernel<<<Ee, 256, 0, stream>>>(onmaskv, idx, pos, cnt);
    scan_pair<<<1, 256, 0, stream>>>(onmaskv, ptok, tiledesc, ntile_dev, ocnt, olist);
    hipMemsetAsync(ob, 0, (size_t)Nn * Dd * 4, stream);

    // weight transposes (f32 -> bf16) into fused [E][384][C]
    transpose_f32_bf16<<<dim3(Dd / 32, Cch / 32, Ee), 256, 0, stream>>>(
        qp, wqkvT + 0 * Dd * Cch, Cch, Dd, (long)Cch * Dd, (long)384 * Cch);
    transpose_f32_bf16<<<dim3(Dd / 32, Cch / 32, Ee), 256, 0, stream>>>(
        kp, wqkvT + 1 * Dd * Cch, Cch, Dd, (long)Cch * Dd, (long)384 * Cch);
    transpose_f32_bf16<<<dim3(Dd / 32, Cch / 32, Ee), 256, 0, stream>>>(
        vp, wqkvT + 2 * Dd * Cch, Cch, Dd, (long)Cch * Dd, (long)384 * Cch);
    transpose_f32_bf16<<<dim3((Ee * Dd) / 32, Cch / 32, 1), 256, 0, stream>>>(
        op, woT, Ee * Dd, Cch, 0L, 0L);

    // gathered per-expert QKV projection (split-K=4, XCD-group swizzle), then combine
    gemm_qkv_gather<<<NGRP * 3, 256, 0, stream>>>(xb, wqkvT, idx, cnt, Pc);
    combine_qkv<<<(Nn * 32) / 256, 256, 0, stream>>>(Pc, rw, pos, qb, kb, vb);

    // V transpose per batch
    transpose_u16<<<dim3(Dd / 32, Tt / 32, Bsz), 256, 0, stream>>>(
        vb, vT, Tt, Dd, (long)Tt * Dd, (long)Dd * Tt);

    // scores = Q K^T * scale (causal)
    gemm_nt<1><<<dim3(Tt / 128, Tt / 128, Bsz), 256, 0, stream>>>(
        qb, (long)Tt * Dd, Dd, kb, (long)Tt * Dd, Dd, scores, (long)Tt * Tt, Tt, Dd, scale);
    softmax_kernel<<<dim3(Tt, Bsz), 256, 0, stream>>>(scores);
    // O = P V  — split-K over causal-active 512-chunks, atomic accumulate
    gemm_pv<<<dim3(Tt / 128, Tt / 512, Bsz), 256, 0, stream>>>(
        (const unsigned short*)scores, vT, ob);

    // output projection: pair-bucket grouped GEMM, each out row stored exactly once
    og2_kernel<<<(Nn * 64) / 256, 256, 0, stream>>>(ob, rw, onmaskv, og2);
    gemm_pair<<<dim3(MAXTILES, Cch / 128), 256, 0, stream>>>(
        og2, woT, ptok, tiledesc, ntile_dev, out);
    overflow_kernel<<<256, 256, 0, stream>>>(ocnt, olist, ob, woT, rw, out);
}

// Round 12
// 299.299 us; speedup vs baseline: 1.4519x; 1.1007x over previous
//
#include <hip/hip_runtime.h>
#include <hip/hip_bf16.h>

#define DEV __device__ __forceinline__

typedef short bf16x8 __attribute__((ext_vector_type(8)));
typedef float f32x4 __attribute__((ext_vector_type(4)));
typedef unsigned short u16x4 __attribute__((ext_vector_type(4)));

static constexpr int Bsz = 4, Tt = 2048, Cch = 2048, Dd = 128, Ee = 16;
static constexpr int Nn = Bsz * Tt;
static constexpr int CAP = 1280;
static constexpr int NSPLIT = 4;
static constexpr size_t PHALF = (size_t)Ee * CAP * 384;
static constexpr int MAXTILES = 320;
static constexpr int MT = CAP / 128;
static constexpr int NGRP = MT * Ee * NSPLIT;

DEV unsigned short f2bf(float v) {
    __hip_bfloat16 h = __float2bfloat16(v);
    return __builtin_bit_cast(unsigned short, h);
}
DEV float bf2f(unsigned short u) {
    unsigned int x = ((unsigned int)u) << 16;
    return __builtin_bit_cast(float, x);
}

// ---------------- sim_matrix column norms ----------------
__global__ __launch_bounds__(256) void colnorm_kernel(const float* __restrict__ sim,
                                                      float* __restrict__ sninv) {
    int e = threadIdx.x & 15, j = threadIdx.x >> 4;
    float ss = 0.f;
    for (int r = j; r < Cch; r += 16) {
        float v = sim[r * Ee + e];
        ss += v * v;
    }
    __shared__ float red[16][17];
    red[j][e] = ss;
    __syncthreads();
    if (threadIdx.x < 16) {
        float s = 0.f;
        for (int t = 0; t < 16; t++) s += red[t][threadIdx.x];
        sninv[threadIdx.x] = 1.f / fmaxf(sqrtf(s), 1e-12f);
    }
}

// ---------------- sim transpose ----------------
__global__ __launch_bounds__(256) void simt_kernel(const float* __restrict__ sim,
                                                   float* __restrict__ simT) {
    int i = blockIdx.x * 256 + threadIdx.x;
    int e = i >> 11, c = i & 2047;
    simT[i] = sim[c * 16 + e];
}

// ---------------- gating: full simT in 128 KiB LDS; 1024 threads ----------------
__global__ __launch_bounds__(1024) void gating5_kernel(
    const float* __restrict__ x, const float* __restrict__ simT,
    const float* __restrict__ gates, const float* __restrict__ sninv,
    const int* __restrict__ minex,
    float* __restrict__ rw, unsigned short* __restrict__ xb,
    int* __restrict__ onmaskv) {
    __shared__ f32x4 ssim[8192];
    const int tid = threadIdx.x;
    const f32x4* stg = (const f32x4*)simT;
#pragma unroll
    for (int i = 0; i < 8; i++) ssim[i * 1024 + tid] = stg[i * 1024 + tid];
    __syncthreads();
    const int wave = tid >> 6, lane = tid & 63;

#pragma unroll 1
    for (int g = 0; g < 2; g++) {
        const int n = blockIdx.x * 32 + g * 16 + wave;
        const f32x4* xr = (const f32x4*)(x + (size_t)n * Cch);
        u16x4* xbr = (u16x4*)(xb + (size_t)n * Cch);
        float ss = 0.f;
        float d[16];
#pragma unroll
        for (int e = 0; e < 16; e++) d[e] = 0.f;

#pragma unroll 2
        for (int it = 0; it < 8; it++) {
            const int i = it * 64 + lane;
            const f32x4 xv = xr[i];
            ss += xv[0] * xv[0] + xv[1] * xv[1] + xv[2] * xv[2] + xv[3] * xv[3];
            u16x4 xc = {f2bf(xv[0]), f2bf(xv[1]), f2bf(xv[2]), f2bf(xv[3])};
            xbr[i] = xc;
#pragma unroll
            for (int e = 0; e < 16; e++) {
                const f32x4 sv = ssim[e * 512 + i];
                d[e] += xv[0] * sv[0] + xv[1] * sv[1] + xv[2] * sv[2] + xv[3] * sv[3];
            }
        }
#pragma unroll
        for (int off = 32; off; off >>= 1) {
            ss += __shfl_down(ss, off);
#pragma unroll
            for (int e = 0; e < 16; e++) d[e] += __shfl_down(d[e], off);
        }
        if (lane == 0) {
            float inv = 1.f / fmaxf(sqrtf(ss), 1e-12f);
            float logit[16];
            int onmask = 0;
#pragma unroll
            for (int e = 0; e < 16; e++) {
                float sg = 1.f / (1.f + __expf(-gates[e]));
                float l = d[e] * inv * sninv[e] - sg;
                logit[e] = l;
                if (l > 0.f) onmask |= (1 << e);
            }
            if (onmask == 0) {
                int k = *minex;
                int ch = 0;
                for (int kk = 0; kk < k; kk++) {
                    float bv = -1e30f;
                    int be = 0;
#pragma unroll
                    for (int e = 0; e < 16; e++)
                        if (!((ch >> e) & 1) && logit[e] > bv) { bv = logit[e]; be = e; }
                    ch |= (1 << be);
                }
                onmask = ch;
            }
            float mx = -1e30f;
#pragma unroll
            for (int e = 0; e < 16; e++)
                if ((onmask >> e) & 1) mx = fmaxf(mx, fmaxf(logit[e], 0.f));
            float pe[16];
            float sum = 0.f;
#pragma unroll
            for (int e = 0; e < 16; e++) {
                pe[e] = ((onmask >> e) & 1) ? __expf(fmaxf(logit[e], 0.f) - mx) : 0.f;
                sum += pe[e];
            }
            float isum = 1.f / sum;
#pragma unroll
            for (int e = 0; e < 16; e++) rw[(size_t)n * 16 + e] = pe[e] * isum;
            onmaskv[n] = onmask;
        }
    }
}

// ---------------- deterministic expert-list scan ----------------
__global__ __launch_bounds__(256) void scan_kernel(
    const int* __restrict__ onmaskv,
    int* __restrict__ idx, int* __restrict__ pos, int* __restrict__ cnt) {
    const int e = blockIdx.x;
    const int tid = threadIdx.x;
    const int base = tid * 32;
    int om[32];
    int c = 0;
#pragma unroll
    for (int i = 0; i < 32; i++) {
        om[i] = (onmaskv[base + i] >> e) & 1;
        c += om[i];
    }
    const int lane = tid & 63, w = tid >> 6;
    int sc = c;
#pragma unroll
    for (int off = 1; off < 64; off <<= 1) {
        int t = __shfl_up(sc, off);
        if (lane >= off) sc += t;
    }
    __shared__ int wsum[4];
    if (lane == 63) wsum[w] = sc;
    __syncthreads();
    int wbase = 0;
    for (int i = 0; i < w; i++) wbase += wsum[i];
    int slot = wbase + sc - c;
#pragma unroll
    for (int i = 0; i < 32; i++) {
        int n = base + i;
        int p = -1;
        if (om[i]) {
            if (slot < CAP) {
                idx[(size_t)e * CAP + slot] = n;
                p = slot;
            }
            slot++;
        }
        pos[(size_t)n * 16 + e] = p;
    }
    if (tid == 255) cnt[e] = slot;
}

// ---------------- pair-bucket scan ----------------
__global__ __launch_bounds__(256) void scan_pair(
    const int* __restrict__ onmaskv,
    int* __restrict__ ptok, int4* __restrict__ tiledesc, int* __restrict__ ntile_dev,
    int* __restrict__ ocnt, int* __restrict__ olist) {
    __shared__ int hist[256], cursor[256];
    __shared__ int wsum[4], wsum2[4];
    const int tid = threadIdx.x;
    if (tid == 0) *ocnt = 0;
    hist[tid] = 0;
    __syncthreads();
    for (int i = 0; i < 32; i++) {
        int n = tid * 32 + i;
        int m = onmaskv[n];
        if (!m) m = 1;
        int e0 = __ffs(m) - 1;
        int m2 = m & (m - 1);
        int e1 = m2 ? (__ffs(m2) - 1) : e0;
        atomicAdd(&hist[e0 * 16 + e1], 1);
        int mrest = m2 & (m2 - 1);
        while (mrest) {
            int e = __ffs(mrest) - 1;
            int s = atomicAdd(ocnt, 1);
            olist[2 * s] = n;
            olist[2 * s + 1] = e;
            mrest &= (mrest - 1);
        }
    }
    __syncthreads();
    const int lane = tid & 63, w = tid >> 6;
    int v = hist[tid];
    int s = v;
#pragma unroll
    for (int off = 1; off < 64; off <<= 1) {
        int t = __shfl_up(s, off);
        if (lane >= off) s += t;
    }
    if (lane == 63) wsum[w] = s;
    __syncthreads();
    int add = 0;
    for (int i = 0; i < w; i++) add += wsum[i];
    int excl = s + add - v;
    cursor[tid] = excl;
    int nt = (v + 127) >> 7;
    int s2 = nt;
#pragma unroll
    for (int off = 1; off < 64; off <<= 1) {
        int t = __shfl_up(s2, off);
        if (lane >= off) s2 += t;
    }
    if (lane == 63) wsum2[w] = s2;
    __syncthreads();
    int add2 = 0;
    for (int i = 0; i < w; i++) add2 += wsum2[i];
    int texcl = s2 + add2 - nt;
    for (int m = 0; m < nt; m++)
        tiledesc[texcl + m] = make_int4(tid, excl + m * 128, min(128, v - m * 128), 0);
    if (tid == 255) *ntile_dev = texcl + nt;
    __syncthreads();
    for (int i = 0; i < 32; i++) {
        int n = tid * 32 + i;
        int m = onmaskv[n];
        if (!m) m = 1;
        int e0 = __ffs(m) - 1;
        int m2 = m & (m - 1);
        int e1 = m2 ? (__ffs(m2) - 1) : e0;
        int slot = atomicAdd(&cursor[e0 * 16 + e1], 1);
        ptok[slot] = n;
    }
}

// ---------------- transposes ----------------
__global__ __launch_bounds__(256) void transpose_f32_bf16(
    const float* __restrict__ src, unsigned short* __restrict__ dst,
    int R, int Ccol, long ss, long ds) {
    __shared__ float tile[32][33];
    src += (size_t)blockIdx.z * ss;
    dst += (size_t)blockIdx.z * ds;
    int bx = blockIdx.x * 32, by = blockIdx.y * 32;
    int tx = threadIdx.x & 31, ty = threadIdx.x >> 5;
#pragma unroll
    for (int i = 0; i < 4; i++)
        tile[ty + i * 8][tx] = src[(size_t)(by + ty + i * 8) * Ccol + bx + tx];
    __syncthreads();
#pragma unroll
    for (int i = 0; i < 4; i++)
        dst[(size_t)(bx + ty + i * 8) * R + by + tx] = f2bf(tile[tx][ty + i * 8]);
}

__global__ __launch_bounds__(256) void transpose_u16(
    const unsigned short* __restrict__ src, unsigned short* __restrict__ dst,
    int R, int Ccol, long ss, long ds) {
    __shared__ unsigned short tile[32][33];
    src += (size_t)blockIdx.z * ss;
    dst += (size_t)blockIdx.z * ds;
    int bx = blockIdx.x * 32, by = blockIdx.y * 32;
    int tx = threadIdx.x & 31, ty = threadIdx.x >> 5;
#pragma unroll
    for (int i = 0; i < 4; i++)
        tile[ty + i * 8][tx] = src[(size_t)(by + ty + i * 8) * Ccol + bx + tx];
    __syncthreads();
#pragma unroll
    for (int i = 0; i < 4; i++)
        dst[(size_t)(bx + ty + i * 8) * R + by + tx] = tile[tx][ty + i * 8];
}

// ---------------- gathered QKV projection, split-K=4, XCD-group swizzle ----------------
__global__ __launch_bounds__(256) void gemm_qkv_gather(
    const unsigned short* __restrict__ X, const unsigned short* __restrict__ W,
    const int* __restrict__ idx, const int* __restrict__ cnt,
    unsigned short* __restrict__ P) {
    const int L = blockIdx.x;
    const int r = L & 7, s = L >> 3;
    const int gq = s / 3, j = s - gq * 3;
    const int g = gq * 8 + r;
    const int m = g % MT;
    const int zc = g / MT;
    const int e = zc >> 2, kc4 = zc & 3;
    const int cn = min(cnt[e], CAP);
    const int bm = m * 128;
    if (bm >= cn) return;
    const int bn = j * 128;
    unsigned short* Ph = P + (size_t)kc4 * PHALF;
    __shared__ alignas(16) unsigned short As[128 * 64];
    __shared__ alignas(16) unsigned short Bs[128 * 64];
    __shared__ int toks[128];
    const int tid = threadIdx.x;
    if (tid < 128) toks[tid] = idx[(size_t)e * CAP + min(bm + tid, cn - 1)];
    const unsigned short* Wb = W + ((size_t)e * 384 + bn) * Cch;
    const int wave = tid >> 6, lane = tid & 63;
    const int lr = lane & 15, lg = lane >> 4;
    const int wr = (wave >> 1) * 64, wc = (wave & 1) * 64;
    f32x4 acc[4][4] = {};

    for (int k0 = kc4 * 512; k0 < kc4 * 512 + 512; k0 += 64) {
        __syncthreads();
#pragma unroll
        for (int i = 0; i < 4; i++) {
            int t = i * 256 + tid;
            int row = t >> 3;
            int kc = (t & 7) << 3;
            __builtin_amdgcn_global_load_lds(
                (const __attribute__((address_space(1))) void*)(X + (size_t)toks[row] * Cch + k0 + kc),
                (__attribute__((address_space(3))) void*)(As + (i * 4 + wave) * 512),
                16, 0, 0);
        }
#pragma unroll
        for (int i = 0; i < 4; i++) {
            int t = i * 256 + tid;
            int row = t >> 3;
            int kc = (t & 7) << 3;
            __builtin_amdgcn_global_load_lds(
                (const __attribute__((address_space(1))) void*)(Wb + (size_t)row * Cch + k0 + kc),
                (__attribute__((address_space(3))) void*)(Bs + (i * 4 + wave) * 512),
                16, 0, 0);
        }
        __syncthreads();
#pragma unroll
        for (int kk = 0; kk < 2; kk++) {
            bf16x8 a[4], b[4];
#pragma unroll
            for (int m2 = 0; m2 < 4; m2++)
                a[m2] = *(const bf16x8*)(As + (wr + m2 * 16 + lr) * 64 + kk * 32 + lg * 8);
#pragma unroll
            for (int n = 0; n < 4; n++)
                b[n] = *(const bf16x8*)(Bs + (wc + n * 16 + lr) * 64 + kk * 32 + lg * 8);
#pragma unroll
            for (int m2 = 0; m2 < 4; m2++)
#pragma unroll
                for (int n = 0; n < 4; n++)
                    acc[m2][n] = __builtin_amdgcn_mfma_f32_16x16x32_bf16(a[m2], b[n], acc[m2][n], 0, 0, 0);
        }
    }
#pragma unroll
    for (int m2 = 0; m2 < 4; m2++)
#pragma unroll
        for (int n = 0; n < 4; n++)
#pragma unroll
            for (int rr = 0; rr < 4; rr++) {
                int slot = bm + wr + m2 * 16 + lg * 4 + rr;
                int col = bn + wc + n * 16 + lr;
                if (slot < cn)
                    Ph[((size_t)e * CAP + slot) * 384 + col] = f2bf(acc[m2][n][rr]);
            }
}

// ---------------- combine q/k/v from NSPLIT split-K partials ----------------
__global__ __launch_bounds__(256) void combine_qkv(
    const unsigned short* __restrict__ P, const float* __restrict__ rw,
    const int* __restrict__ pos,
    unsigned short* __restrict__ qb, unsigned short* __restrict__ kb,
    unsigned short* __restrict__ vb) {
    int i = blockIdx.x * 256 + threadIdx.x;
    int n = i >> 5;
    int d4 = (i & 31) << 2;
    float aq[4] = {}, ak[4] = {}, av[4] = {};
#pragma unroll
    for (int e = 0; e < 16; e++) {
        int p = pos[(size_t)n * 16 + e];
        if (p >= 0) {
            float w = rw[(size_t)n * 16 + e];
            const unsigned short* r0 = P + ((size_t)e * CAP + p) * 384 + d4;
#pragma unroll
            for (int h = 0; h < NSPLIT; h++) {
                const unsigned short* rh = r0 + (size_t)h * PHALF;
                const u16x4 q4 = *(const u16x4*)(rh);
                const u16x4 k4 = *(const u16x4*)(rh + 128);
                const u16x4 v4 = *(const u16x4*)(rh + 256);
#pragma unroll
                for (int jj = 0; jj < 4; jj++) {
                    aq[jj] += w * bf2f(q4[jj]);
                    ak[jj] += w * bf2f(k4[jj]);
                    av[jj] += w * bf2f(v4[jj]);
                }
            }
        }
    }
    u16x4 sq = {f2bf(aq[0]), f2bf(aq[1]), f2bf(aq[2]), f2bf(aq[3])};
    u16x4 sk = {f2bf(ak[0]), f2bf(ak[1]), f2bf(ak[2]), f2bf(ak[3])};
    u16x4 sv = {f2bf(av[0]), f2bf(av[1]), f2bf(av[2]), f2bf(av[3])};
    *(u16x4*)(qb + (size_t)n * Dd + d4) = sq;
    *(u16x4*)(kb + (size_t)n * Dd + d4) = sk;
    *(u16x4*)(vb + (size_t)n * Dd + d4) = sv;
}

// ---------------- flash attention, split-KV: partial O/m/l per (q-tile, kv-chunk) ----------------
// grid (16 q-tiles, 4 kv-chunks, B). 4 waves x 32 q-rows. Swizzled LDS (XOR 16B units).
__global__ __launch_bounds__(256) void flash_kernel(
    const unsigned short* __restrict__ qb, const unsigned short* __restrict__ kb,
    const unsigned short* __restrict__ vT,
    float* __restrict__ Op, float* __restrict__ ml) {
    const int qt = blockIdx.x, ch = blockIdx.y, b = blockIdx.z;
    const int q0 = qt * 128, kv0 = ch * 512;
    if (kv0 > q0 + 127) return;
    __shared__ alignas(16) unsigned short Qs[128 * 128];   // 32KB, rows 256B
    __shared__ alignas(16) unsigned short Ks[64 * 128];    // 16KB, rows 256B
    __shared__ alignas(16) unsigned short Vs[128 * 64];    // 16KB, rows 128B
    __shared__ alignas(16) unsigned short Ps[4][32 * 64];  // 16KB, per-wave
    const int tid = threadIdx.x;
    const int wave = tid >> 6, lane = tid & 63;
    const int lr = lane & 15, lg = lane >> 4;
    const float scale = 0.08838834764831845f;
    const unsigned short* Qg = qb + ((size_t)b * Tt + q0) * 128;
    const unsigned short* Kg = kb + (size_t)b * Tt * 128;
    const unsigned short* Vg = vT + (size_t)b * 128 * Tt;

    // stage Q once (swizzled source -> linear dest)
#pragma unroll
    for (int i = 0; i < 8; i++) {
        int dof = (i * 256 + tid) << 4;           // byte offset in Qs
        int row = dof >> 8;                        // 0..127
        int c16 = (dof >> 4) & 15;
        int s16 = c16 ^ (row & 7);
        __builtin_amdgcn_global_load_lds(
            (const __attribute__((address_space(1))) void*)(Qg + (size_t)row * 128 + s16 * 8),
            (__attribute__((address_space(3))) void*)(Qs + (size_t)(i * 4 + wave) * 512),
            16, 0, 0);
    }

    f32x4 acc_o[2][8] = {};
    float rm[2][4], rl[2][4];
#pragma unroll
    for (int mf = 0; mf < 2; mf++)
#pragma unroll
        for (int rg = 0; rg < 4; rg++) { rm[mf][rg] = -1e30f; rl[mf][rg] = 0.f; }

    const int ktend = min(kv0 + 512, q0 + 128);
    for (int kt = kv0; kt < ktend; kt += 64) {
        if (kt > kv0) __syncthreads();  // all waves done with prev Ks/Vs
        // stage K sub-tile (64 rows x 256B)
#pragma unroll
        for (int i = 0; i < 4; i++) {
            int dof = (i * 256 + tid) << 4;
            int row = dof >> 8;                    // 0..63
            int c16 = (dof >> 4) & 15;
            int s16 = c16 ^ (row & 7);
            __builtin_amdgcn_global_load_lds(
                (const __attribute__((address_space(1))) void*)(Kg + (size_t)(kt + row) * 128 + s16 * 8),
                (__attribute__((address_space(3))) void*)(Ks + (size_t)(i * 4 + wave) * 512),
                16, 0, 0);
        }
        // stage V^T sub-tile (128 d-rows x 128B)
#pragma unroll
        for (int i = 0; i < 4; i++) {
            int dof = (i * 256 + tid) << 4;
            int row = dof >> 7;                    // 0..127
            int c16 = (dof >> 4) & 7;
            int s16 = c16 ^ (row & 7);
            __builtin_amdgcn_global_load_lds(
                (const __attribute__((address_space(1))) void*)(Vg + (size_t)row * Tt + kt + s16 * 8),
                (__attribute__((address_space(3))) void*)(Vs + (size_t)(i * 4 + wave) * 512),
                16, 0, 0);
        }
        __syncthreads();  // Q (first iter) + K + V staged

        // S = Q K^T  (wave rows = wave*32 .. +32, cols = 64)
        f32x4 acc_s[2][4] = {};
#pragma unroll
        for (int kk = 0; kk < 4; kk++) {
            bf16x8 a[2], bfr[4];
#pragma unroll
            for (int mf = 0; mf < 2; mf++) {
                int row = wave * 32 + mf * 16 + lr;
                int c16 = (kk * 4 + lg) ^ (row & 7);
                a[mf] = *(const bf16x8*)(Qs + row * 128 + c16 * 8);
            }
#pragma unroll
            for (int nf = 0; nf < 4; nf++) {
                int row = nf * 16 + lr;
                int c16 = (kk * 4 + lg) ^ (row & 7);
                bfr[nf] = *(const bf16x8*)(Ks + row * 128 + c16 * 8);
            }
#pragma unroll
            for (int mf = 0; mf < 2; mf++)
#pragma unroll
                for (int nf = 0; nf < 4; nf++)
                    acc_s[mf][nf] = __builtin_amdgcn_mfma_f32_16x16x32_bf16(a[mf], bfr[nf], acc_s[mf][nf], 0, 0, 0);
        }

        // online softmax per row; rows owned per lane: (mf, reg) -> row lg*4+reg local
#pragma unroll
        for (int mf = 0; mf < 2; mf++) {
            float sv[4][4], pmax[4];
#pragma unroll
            for (int rg = 0; rg < 4; rg++) pmax[rg] = -1e30f;
#pragma unroll
            for (int nf = 0; nf < 4; nf++) {
                int colg = kt + nf * 16 + lr;
#pragma unroll
                for (int rg = 0; rg < 4; rg++) {
                    int rowg = q0 + wave * 32 + mf * 16 + lg * 4 + rg;
                    float s = acc_s[mf][nf][rg] * scale;
                    if (colg > rowg) s = -1e30f;
                    sv[nf][rg] = s;
                    pmax[rg] = fmaxf(pmax[rg], s);
                }
            }
#pragma unroll
            for (int rg = 0; rg < 4; rg++) {
#pragma unroll
                for (int off = 1; off < 16; off <<= 1)
                    pmax[rg] = fmaxf(pmax[rg], __shfl_xor(pmax[rg], off));
                float mnew = fmaxf(rm[mf][rg], pmax[rg]);
                float f = __expf(rm[mf][rg] - mnew);
                rm[mf][rg] = mnew;
#pragma unroll
                for (int nd = 0; nd < 8; nd++) acc_o[mf][nd][rg] *= f;
                float rsum = 0.f;
#pragma unroll
                for (int nf = 0; nf < 4; nf++) {
                    float p = __expf(sv[nf][rg] - mnew);
                    sv[nf][rg] = p;
                    rsum += p;
                }
#pragma unroll
                for (int off = 1; off < 16; off <<= 1) rsum += __shfl_xor(rsum, off);
                rl[mf][rg] = rl[mf][rg] * f + rsum;
                // write P row to wave-private swizzled LDS
                int rloc = mf * 16 + lg * 4 + rg;
#pragma unroll
                for (int nf = 0; nf < 4; nf++) {
                    int col = nf * 16 + lr;
                    int unit = (col >> 3) ^ (rloc & 7);
                    Ps[wave][rloc * 64 + unit * 8 + (col & 7)] = f2bf(sv[nf][rg]);
                }
            }
        }

        // O += P V   (P: 32x64 per wave, V: 64x128)
#pragma unroll
        for (int kk2 = 0; kk2 < 2; kk2++) {
            bf16x8 a[2], bfr[8];
#pragma unroll
            for (int mf = 0; mf < 2; mf++) {
                int row = mf * 16 + lr;
                int c16 = (kk2 * 4 + lg) ^ (row & 7);
                a[mf] = *(const bf16x8*)(&Ps[wave][row * 64 + c16 * 8]);
            }
#pragma unroll
            for (int nd = 0; nd < 8; nd++) {
                int row = nd * 16 + lr;
                int c16 = ((kk2 * 4 + lg) ^ (row & 7)) & 7;
                bfr[nd] = *(const bf16x8*)(Vs + row * 64 + c16 * 8);
            }
#pragma unroll
            for (int mf = 0; mf < 2; mf++)
#pragma unroll
                for (int nd = 0; nd < 8; nd++)
                    acc_o[mf][nd] = __builtin_amdgcn_mfma_f32_16x16x32_bf16(a[mf], bfr[nd], acc_o[mf][nd], 0, 0, 0);
        }
    }

    // write partials
    float* Opb = Op + (((size_t)b * 4 + ch) * Tt) * 128;
    float* mlb = ml + (((size_t)b * 4 + ch) * Tt) * 2;
#pragma unroll
    for (int mf = 0; mf < 2; mf++)
#pragma unroll
        for (int rg = 0; rg < 4; rg++) {
            int rowl = q0 + wave * 32 + mf * 16 + lg * 4 + rg;
#pragma unroll
            for (int nd = 0; nd < 8; nd++)
                Opb[(size_t)rowl * 128 + nd * 16 + lr] = acc_o[mf][nd][rg];
            if (lr == 0) {
                mlb[rowl * 2] = rm[mf][rg];
                mlb[rowl * 2 + 1] = rl[mf][rg];
            }
        }
}

// ---------------- flash combine: merge chunk partials; write ob f32 + og2 bf16 ----------------
__global__ __launch_bounds__(256) void flash_combine(
    const float* __restrict__ Op, const float* __restrict__ ml,
    const float* __restrict__ rw, const int* __restrict__ onmaskv,
    float* __restrict__ ob, unsigned short* __restrict__ og2) {
    int i = blockIdx.x * 256 + threadIdx.x;  // (n, d)
    int n = i >> 7, d = i & 127;
    int rs = n & 2047, b = n >> 11;
    int nch = rs / 512 + 1;
    float ms = -1e30f;
    for (int c = 0; c < nch; c++)
        ms = fmaxf(ms, ml[(((size_t)b * 4 + c) * Tt + rs) * 2]);
    float num = 0.f, den = 0.f;
    for (int c = 0; c < nch; c++) {
        size_t rbase = ((size_t)b * 4 + c) * Tt + rs;
        float mi = ml[rbase * 2], li = ml[rbase * 2 + 1];
        float w = __expf(mi - ms);
        num += w * Op[rbase * 128 + d];
        den += w * li;
    }
    float o = num / den;
    ob[(size_t)n * 128 + d] = o;
    int m = onmaskv[n];
    if (!m) m = 1;
    int e0 = __ffs(m) - 1;
    int m2 = m & (m - 1);
    float w0 = rw[(size_t)n * 16 + e0];
    float w1 = m2 ? rw[(size_t)n * 16 + (__ffs(m2) - 1)] : 0.f;
    og2[(size_t)n * 256 + d] = f2bf(w0 * o);
    og2[(size_t)n * 256 + 128 + d] = f2bf(w1 * o);
}

// ---------------- pair-bucket output GEMM ----------------
__global__ __launch_bounds__(256) void gemm_pair(
    const unsigned short* __restrict__ og2,
    const unsigned short* __restrict__ woT,
    const int* __restrict__ ptok, const int4* __restrict__ tiledesc,
    const int* __restrict__ ntile_dev,
    float* __restrict__ out) {
    if (blockIdx.x >= *ntile_dev) return;
    const int4 td = tiledesc[blockIdx.x];
    const int ei = td.x >> 4, ej = td.x & 15;
    const int mstart = td.y, mcnt = td.z;
    const int bn = blockIdx.y * 128;
    __shared__ alignas(16) unsigned short As[128 * 64];
    __shared__ alignas(16) unsigned short Bs[128 * 64];
    __shared__ int toks[128];
    const int tid = threadIdx.x;
    if (tid < 128) toks[tid] = ptok[mstart + min(tid, mcnt - 1)];
    const int wave = tid >> 6, lane = tid & 63;
    const int lr = lane & 15, lg = lane >> 4;
    const int wr = (wave >> 1) * 64, wc = (wave & 1) * 64;
    f32x4 acc[4][4] = {};

#pragma unroll
    for (int ck = 0; ck < 4; ck++) {
        const int ebase = (ck < 2 ? ei : ej) * 128 + (ck & 1) * 64;
        const int abase = ck * 64;
        __syncthreads();
#pragma unroll
        for (int q = 0; q < 4; q++) {
            int t = q * 256 + tid;
            int row = t >> 3;
            int kc = (t & 7) << 3;
            __builtin_amdgcn_global_load_lds(
                (const __attribute__((address_space(1))) void*)(og2 + (size_t)toks[row] * 256 + abase + kc),
                (__attribute__((address_space(3))) void*)(As + (q * 4 + wave) * 512),
                16, 0, 0);
        }
#pragma unroll
        for (int q = 0; q < 4; q++) {
            int t = q * 256 + tid;
            int row = t >> 3;
            int kc = (t & 7) << 3;
            __builtin_amdgcn_global_load_lds(
                (const __attribute__((address_space(1))) void*)(woT + (size_t)(bn + row) * 2048 + ebase + kc),
                (__attribute__((address_space(3))) void*)(Bs + (q * 4 + wave) * 512),
                16, 0, 0);
        }
        __syncthreads();
#pragma unroll
        for (int kk = 0; kk < 2; kk++) {
            bf16x8 a[4], b[4];
#pragma unroll
            for (int m = 0; m < 4; m++)
                a[m] = *(const bf16x8*)(As + (wr + m * 16 + lr) * 64 + kk * 32 + lg * 8);
#pragma unroll
            for (int n = 0; n < 4; n++)
                b[n] = *(const bf16x8*)(Bs + (wc + n * 16 + lr) * 64 + kk * 32 + lg * 8);
#pragma unroll
            for (int m = 0; m < 4; m++)
#pragma unroll
                for (int n = 0; n < 4; n++)
                    acc[m][n] = __builtin_amdgcn_mfma_f32_16x16x32_bf16(a[m], b[n], acc[m][n], 0, 0, 0);
        }
    }
#pragma unroll
    for (int m = 0; m < 4; m++)
#pragma unroll
        for (int n = 0; n < 4; n++)
#pragma unroll
            for (int r = 0; r < 4; r++) {
                int rowt = wr + m * 16 + lg * 4 + r;
                if (rowt < mcnt) {
                    int tok = toks[rowt];
                    out[(size_t)tok * 2048 + bn + wc + n * 16 + lr] = acc[m][n][r];
                }
            }
}

// ---------------- rare overflow path ----------------
__global__ __launch_bounds__(256) void overflow_kernel(
    const int* __restrict__ ocnt, const int* __restrict__ olist,
    const float* __restrict__ ob, const unsigned short* __restrict__ woT,
    const float* __restrict__ rw, float* __restrict__ out) {
    const int ne = *ocnt;
    __shared__ float osh[128];
    for (int it = blockIdx.x; it < ne; it += gridDim.x) {
        int n = olist[2 * it], e = olist[2 * it + 1];
        float wgt = rw[(size_t)n * 16 + e];
        if (threadIdx.x < 128) osh[threadIdx.x] = ob[(size_t)n * Dd + threadIdx.x];
        __syncthreads();
#pragma unroll 1
        for (int cc = 0; cc < 8; cc++) {
            int c = threadIdx.x * 8 + cc;
            float a = 0.f;
            for (int k = 0; k < 128; k++)
                a += osh[k] * bf2f(woT[(size_t)c * 2048 + e * 128 + k]);
            atomicAdd(&out[(size_t)n * 2048 + c], wgt * a);
        }
        __syncthreads();
    }
}

extern "C" void kernel_launch(void* const* d_in, const int* in_sizes, int n_in,
                              void* d_out, int out_size, void* d_ws, size_t ws_size,
                              hipStream_t stream) {
    (void)in_sizes; (void)n_in; (void)out_size; (void)ws_size;
    const float* hidden = (const float*)d_in[0];
    const float* sim = (const float*)d_in[1];
    const float* gates = (const float*)d_in[2];
    const float* qp = (const float*)d_in[3];
    const float* kp = (const float*)d_in[4];
    const float* vp = (const float*)d_in[5];
    const float* op = (const float*)d_in[6];
    const int* minex = (const int*)d_in[7];
    float* out = (float*)d_out;

    char* w = (char*)d_ws;
    size_t off = 0;
    auto alloc = [&](size_t bytes) -> char* {
        char* p = w + off;
        off = (off + bytes + 255) & ~(size_t)255;
        return p;
    };
    unsigned short* xb = (unsigned short*)alloc((size_t)Nn * Cch * 2);
    unsigned short* wqkvT = (unsigned short*)alloc((size_t)Ee * 384 * Cch * 2);
    unsigned short* woT = (unsigned short*)alloc((size_t)Cch * Ee * Dd * 2);
    float* rw = (float*)alloc((size_t)Nn * Ee * 4);
    float* sninv = (float*)alloc(256);
    float* simT = (float*)alloc((size_t)Ee * Cch * 4);
    int* cnt = (int*)alloc(256);
    int* onmaskv = (int*)alloc((size_t)Nn * 4);
    int* idx = (int*)alloc((size_t)Ee * CAP * 4);
    int* pos = (int*)alloc((size_t)Nn * 16 * 4);
    int* ptok = (int*)alloc((size_t)Nn * 4);
    int4* tiledesc = (int4*)alloc((size_t)MAXTILES * 16);
    int* ntile_dev = (int*)alloc(256);
    int* ocnt = (int*)alloc(256);
    int* olist = (int*)alloc((size_t)Nn * 14 * 2 * 4);
    char* big = alloc((size_t)Bsz * Tt * Tt * 4);  // Pc (63MB), later Op partials (16.8MB)
    unsigned short* qb = (unsigned short*)alloc((size_t)Nn * Dd * 2);
    unsigned short* kb = (unsigned short*)alloc((size_t)Nn * Dd * 2);
    unsigned short* vb = (unsigned short*)alloc((size_t)Nn * Dd * 2);
    unsigned short* vT = (unsigned short*)alloc((size_t)Bsz * Dd * Tt * 2);
    float* ob = (float*)alloc((size_t)Nn * Dd * 4);
    unsigned short* og2 = (unsigned short*)alloc((size_t)Nn * 256 * 2);
    float* ml = (float*)alloc((size_t)Bsz * 4 * Tt * 2 * 4);
    unsigned short* Pc = (unsigned short*)big;
    float* Op = (float*)big;  // aliases Pc (dead after combine_qkv)

    colnorm_kernel<<<1, 256, 0, stream>>>(sim, sninv);
    simt_kernel<<<(Ee * Cch) / 256, 256, 0, stream>>>(sim, simT);
    gating5_kernel<<<Nn / 32, 1024, 0, stream>>>(hidden, simT, gates, sninv, minex, rw, xb, onmaskv);
    scan_kernel<<<Ee, 256, 0, stream>>>(onmaskv, idx, pos, cnt);
    scan_pair<<<1, 256, 0, stream>>>(onmaskv, ptok, tiledesc, ntile_dev, ocnt, olist);

    // weight transposes (f32 -> bf16) into fused [E][384][C]
    transpose_f32_bf16<<<dim3(Dd / 32, Cch / 32, Ee), 256, 0, stream>>>(
        qp, wqkvT + 0 * Dd * Cch, Cch, Dd, (long)Cch * Dd, (long)384 * Cch);
    transpose_f32_bf16<<<dim3(Dd / 32, Cch / 32, Ee), 256, 0, stream>>>(
        kp, wqkvT + 1 * Dd * Cch, Cch, Dd, (long)Cch * Dd, (long)384 * Cch);
    transpose_f32_bf16<<<dim3(Dd / 32, Cch / 32, Ee), 256, 0, stream>>>(
        vp, wqkvT + 2 * Dd * Cch, Cch, Dd, (long)Cch * Dd, (long)384 * Cch);
    transpose_f32_bf16<<<dim3((Ee * Dd) / 32, Cch / 32, 1), 256, 0, stream>>>(
        op, woT, Ee * Dd, Cch, 0L, 0L);

    // gathered per-expert QKV projection (split-K=4, XCD swizzle), then combine
    gemm_qkv_gather<<<NGRP * 3, 256, 0, stream>>>(xb, wqkvT, idx, cnt, Pc);
    combine_qkv<<<(Nn * 32) / 256, 256, 0, stream>>>(Pc, rw, pos, qb, kb, vb);

    // V transpose per batch
    transpose_u16<<<dim3(Dd / 32, Tt / 32, Bsz), 256, 0, stream>>>(
        vb, vT, Tt, Dd, (long)Tt * Dd, (long)Dd * Tt);

    // flash attention (split-KV) + combine (writes ob and og2)
    flash_kernel<<<dim3(Tt / 128, 4, Bsz), 256, 0, stream>>>(qb, kb, vT, Op, ml);
    flash_combine<<<(Nn * 128) / 256, 256, 0, stream>>>(Op, ml, rw, onmaskv, ob, og2);

    // output projection: pair-bucket grouped GEMM
    gemm_pair<<<dim3(MAXTILES, Cch / 128), 256, 0, stream>>>(
        og2, woT, ptok, tiledesc, ntile_dev, out);
    overflow_kernel<<<256, 256, 0, stream>>>(ocnt, olist, ob, woT, rw, out);
}

// Round 13
// 286.766 us; speedup vs baseline: 1.5154x; 1.0437x over previous
//
#include <hip/hip_runtime.h>
#include <hip/hip_bf16.h>

#define DEV __device__ __forceinline__

typedef short bf16x8 __attribute__((ext_vector_type(8)));
typedef float f32x4 __attribute__((ext_vector_type(4)));
typedef unsigned short u16x4 __attribute__((ext_vector_type(4)));

static constexpr int Bsz = 4, Tt = 2048, Cch = 2048, Dd = 128, Ee = 16;
static constexpr int Nn = Bsz * Tt;
static constexpr int CAP = 1280;
static constexpr int NSPLIT = 2;  // split-K partials for QKV gather (K=1024 each)
static constexpr size_t PHALF = (size_t)Ee * CAP * 384;
static constexpr int MAXTILES = 320;
static constexpr int MT = CAP / 128;            // 10 m-tiles per expert
static constexpr int NGRP = MT * Ee * NSPLIT;   // 320 groups; each = 3 column tiles

DEV unsigned short f2bf(float v) {
    __hip_bfloat16 h = __float2bfloat16(v);
    return __builtin_bit_cast(unsigned short, h);
}
DEV float bf2f(unsigned short u) {
    unsigned int x = ((unsigned int)u) << 16;
    return __builtin_bit_cast(float, x);
}

// ---------------- sim_matrix column norms ----------------
__global__ __launch_bounds__(256) void colnorm_kernel(const float* __restrict__ sim,
                                                      float* __restrict__ sninv) {
    int e = threadIdx.x & 15, j = threadIdx.x >> 4;
    float ss = 0.f;
    for (int r = j; r < Cch; r += 16) {
        float v = sim[r * Ee + e];
        ss += v * v;
    }
    __shared__ float red[16][17];
    red[j][e] = ss;
    __syncthreads();
    if (threadIdx.x < 16) {
        float s = 0.f;
        for (int t = 0; t < 16; t++) s += red[t][threadIdx.x];
        sninv[threadIdx.x] = 1.f / fmaxf(sqrtf(s), 1e-12f);
    }
}

// ---------------- sim transpose ----------------
__global__ __launch_bounds__(256) void simt_kernel(const float* __restrict__ sim,
                                                   float* __restrict__ simT) {
    int i = blockIdx.x * 256 + threadIdx.x;
    int e = i >> 11, c = i & 2047;
    simT[i] = sim[c * 16 + e];
}

// ---------------- gating: full simT in 128 KiB LDS; 1024 threads ----------------
__global__ __launch_bounds__(1024) void gating5_kernel(
    const float* __restrict__ x, const float* __restrict__ simT,
    const float* __restrict__ gates, const float* __restrict__ sninv,
    const int* __restrict__ minex,
    float* __restrict__ rw, unsigned short* __restrict__ xb,
    int* __restrict__ onmaskv) {
    __shared__ f32x4 ssim[8192];
    const int tid = threadIdx.x;
    const f32x4* stg = (const f32x4*)simT;
#pragma unroll
    for (int i = 0; i < 8; i++) ssim[i * 1024 + tid] = stg[i * 1024 + tid];
    __syncthreads();
    const int wave = tid >> 6, lane = tid & 63;

#pragma unroll 1
    for (int g = 0; g < 2; g++) {
        const int n = blockIdx.x * 32 + g * 16 + wave;
        const f32x4* xr = (const f32x4*)(x + (size_t)n * Cch);
        u16x4* xbr = (u16x4*)(xb + (size_t)n * Cch);
        float ss = 0.f;
        float d[16];
#pragma unroll
        for (int e = 0; e < 16; e++) d[e] = 0.f;

#pragma unroll 2
        for (int it = 0; it < 8; it++) {
            const int i = it * 64 + lane;
            const f32x4 xv = xr[i];
            ss += xv[0] * xv[0] + xv[1] * xv[1] + xv[2] * xv[2] + xv[3] * xv[3];
            u16x4 xc = {f2bf(xv[0]), f2bf(xv[1]), f2bf(xv[2]), f2bf(xv[3])};
            xbr[i] = xc;
#pragma unroll
            for (int e = 0; e < 16; e++) {
                const f32x4 sv = ssim[e * 512 + i];
                d[e] += xv[0] * sv[0] + xv[1] * sv[1] + xv[2] * sv[2] + xv[3] * sv[3];
            }
        }
#pragma unroll
        for (int off = 32; off; off >>= 1) {
            ss += __shfl_down(ss, off);
#pragma unroll
            for (int e = 0; e < 16; e++) d[e] += __shfl_down(d[e], off);
        }
        if (lane == 0) {
            float inv = 1.f / fmaxf(sqrtf(ss), 1e-12f);
            float logit[16];
            int onmask = 0;
#pragma unroll
            for (int e = 0; e < 16; e++) {
                float sg = 1.f / (1.f + __expf(-gates[e]));
                float l = d[e] * inv * sninv[e] - sg;
                logit[e] = l;
                if (l > 0.f) onmask |= (1 << e);
            }
            if (onmask == 0) {
                int k = *minex;
                int ch = 0;
                for (int kk = 0; kk < k; kk++) {
                    float bv = -1e30f;
                    int be = 0;
#pragma unroll
                    for (int e = 0; e < 16; e++)
                        if (!((ch >> e) & 1) && logit[e] > bv) { bv = logit[e]; be = e; }
                    ch |= (1 << be);
                }
                onmask = ch;
            }
            float mx = -1e30f;
#pragma unroll
            for (int e = 0; e < 16; e++)
                if ((onmask >> e) & 1) mx = fmaxf(mx, fmaxf(logit[e], 0.f));
            float pe[16];
            float sum = 0.f;
#pragma unroll
            for (int e = 0; e < 16; e++) {
                pe[e] = ((onmask >> e) & 1) ? __expf(fmaxf(logit[e], 0.f) - mx) : 0.f;
                sum += pe[e];
            }
            float isum = 1.f / sum;
#pragma unroll
            for (int e = 0; e < 16; e++) rw[(size_t)n * 16 + e] = pe[e] * isum;
            onmaskv[n] = onmask;
        }
    }
}

// ---------------- deterministic expert-list scan ----------------
__global__ __launch_bounds__(256) void scan_kernel(
    const int* __restrict__ onmaskv,
    int* __restrict__ idx, int* __restrict__ pos, int* __restrict__ cnt) {
    const int e = blockIdx.x;
    const int tid = threadIdx.x;
    const int base = tid * 32;
    int om[32];
    int c = 0;
#pragma unroll
    for (int i = 0; i < 32; i++) {
        om[i] = (onmaskv[base + i] >> e) & 1;
        c += om[i];
    }
    const int lane = tid & 63, w = tid >> 6;
    int sc = c;
#pragma unroll
    for (int off = 1; off < 64; off <<= 1) {
        int t = __shfl_up(sc, off);
        if (lane >= off) sc += t;
    }
    __shared__ int wsum[4];
    if (lane == 63) wsum[w] = sc;
    __syncthreads();
    int wbase = 0;
    for (int i = 0; i < w; i++) wbase += wsum[i];
    int slot = wbase + sc - c;
#pragma unroll
    for (int i = 0; i < 32; i++) {
        int n = base + i;
        int p = -1;
        if (om[i]) {
            if (slot < CAP) {
                idx[(size_t)e * CAP + slot] = n;
                p = slot;
            }
            slot++;
        }
        pos[(size_t)n * 16 + e] = p;
    }
    if (tid == 255) cnt[e] = slot;
}

// ---------------- pair-bucket scan ----------------
__global__ __launch_bounds__(256) void scan_pair(
    const int* __restrict__ onmaskv,
    int* __restrict__ ptok, int4* __restrict__ tiledesc, int* __restrict__ ntile_dev,
    int* __restrict__ ocnt, int* __restrict__ olist) {
    __shared__ int hist[256], cursor[256];
    __shared__ int wsum[4], wsum2[4];
    const int tid = threadIdx.x;
    if (tid == 0) *ocnt = 0;
    hist[tid] = 0;
    __syncthreads();
    for (int i = 0; i < 32; i++) {
        int n = tid * 32 + i;
        int m = onmaskv[n];
        if (!m) m = 1;
        int e0 = __ffs(m) - 1;
        int m2 = m & (m - 1);
        int e1 = m2 ? (__ffs(m2) - 1) : e0;
        atomicAdd(&hist[e0 * 16 + e1], 1);
        int mrest = m2 & (m2 - 1);
        while (mrest) {
            int e = __ffs(mrest) - 1;
            int s = atomicAdd(ocnt, 1);
            olist[2 * s] = n;
            olist[2 * s + 1] = e;
            mrest &= (mrest - 1);
        }
    }
    __syncthreads();
    const int lane = tid & 63, w = tid >> 6;
    int v = hist[tid];
    int s = v;
#pragma unroll
    for (int off = 1; off < 64; off <<= 1) {
        int t = __shfl_up(s, off);
        if (lane >= off) s += t;
    }
    if (lane == 63) wsum[w] = s;
    __syncthreads();
    int add = 0;
    for (int i = 0; i < w; i++) add += wsum[i];
    int excl = s + add - v;
    cursor[tid] = excl;
    int nt = (v + 127) >> 7;
    int s2 = nt;
#pragma unroll
    for (int off = 1; off < 64; off <<= 1) {
        int t = __shfl_up(s2, off);
        if (lane >= off) s2 += t;
    }
    if (lane == 63) wsum2[w] = s2;
    __syncthreads();
    int add2 = 0;
    for (int i = 0; i < w; i++) add2 += wsum2[i];
    int texcl = s2 + add2 - nt;
    for (int m = 0; m < nt; m++)
        tiledesc[texcl + m] = make_int4(tid, excl + m * 128, min(128, v - m * 128), 0);
    if (tid == 255) *ntile_dev = texcl + nt;
    __syncthreads();
    for (int i = 0; i < 32; i++) {
        int n = tid * 32 + i;
        int m = onmaskv[n];
        if (!m) m = 1;
        int e0 = __ffs(m) - 1;
        int m2 = m & (m - 1);
        int e1 = m2 ? (__ffs(m2) - 1) : e0;
        int slot = atomicAdd(&cursor[e0 * 16 + e1], 1);
        ptok[slot] = n;
    }
}

// ---------------- transposes ----------------
__global__ __launch_bounds__(256) void transpose_f32_bf16(
    const float* __restrict__ src, unsigned short* __restrict__ dst,
    int R, int Ccol, long ss, long ds) {
    __shared__ float tile[32][33];
    src += (size_t)blockIdx.z * ss;
    dst += (size_t)blockIdx.z * ds;
    int bx = blockIdx.x * 32, by = blockIdx.y * 32;
    int tx = threadIdx.x & 31, ty = threadIdx.x >> 5;
#pragma unroll
    for (int i = 0; i < 4; i++)
        tile[ty + i * 8][tx] = src[(size_t)(by + ty + i * 8) * Ccol + bx + tx];
    __syncthreads();
#pragma unroll
    for (int i = 0; i < 4; i++)
        dst[(size_t)(bx + ty + i * 8) * R + by + tx] = f2bf(tile[tx][ty + i * 8]);
}

__global__ __launch_bounds__(256) void transpose_u16(
    const unsigned short* __restrict__ src, unsigned short* __restrict__ dst,
    int R, int Ccol, long ss, long ds) {
    __shared__ unsigned short tile[32][33];
    src += (size_t)blockIdx.z * ss;
    dst += (size_t)blockIdx.z * ds;
    int bx = blockIdx.x * 32, by = blockIdx.y * 32;
    int tx = threadIdx.x & 31, ty = threadIdx.x >> 5;
#pragma unroll
    for (int i = 0; i < 4; i++)
        tile[ty + i * 8][tx] = src[(size_t)(by + ty + i * 8) * Ccol + bx + tx];
    __syncthreads();
#pragma unroll
    for (int i = 0; i < 4; i++)
        dst[(size_t)(bx + ty + i * 8) * R + by + tx] = tile[tx][ty + i * 8];
}

// ---------------- gathered QKV projection, split-K=2, XCD-group swizzle ----------------
__global__ __launch_bounds__(256) void gemm_qkv_gather(
    const unsigned short* __restrict__ X, const unsigned short* __restrict__ W,
    const int* __restrict__ idx, const int* __restrict__ cnt,
    unsigned short* __restrict__ P) {
    const int L = blockIdx.x;
    const int r = L & 7, s = L >> 3;
    const int gq = s / 3, j = s - gq * 3;
    const int g = gq * 8 + r;
    const int m = g % MT;
    const int zc = g / MT;
    const int e = zc >> 1, kc2 = zc & 1;
    const int cn = min(cnt[e], CAP);
    const int bm = m * 128;
    if (bm >= cn) return;
    const int bn = j * 128;
    unsigned short* Ph = P + (size_t)kc2 * PHALF;
    __shared__ alignas(16) unsigned short As[128 * 64];
    __shared__ alignas(16) unsigned short Bs[128 * 64];
    __shared__ int toks[128];
    const int tid = threadIdx.x;
    if (tid < 128) toks[tid] = idx[(size_t)e * CAP + min(bm + tid, cn - 1)];
    const unsigned short* Wb = W + ((size_t)e * 384 + bn) * Cch;
    const int wave = tid >> 6, lane = tid & 63;
    const int lr = lane & 15, lg = lane >> 4;
    const int wr = (wave >> 1) * 64, wc = (wave & 1) * 64;
    f32x4 acc[4][4] = {};

    for (int k0 = kc2 * 1024; k0 < kc2 * 1024 + 1024; k0 += 64) {
        __syncthreads();
#pragma unroll
        for (int i = 0; i < 4; i++) {
            int t = i * 256 + tid;
            int row = t >> 3;
            int kc = (t & 7) << 3;
            __builtin_amdgcn_global_load_lds(
                (const __attribute__((address_space(1))) void*)(X + (size_t)toks[row] * Cch + k0 + kc),
                (__attribute__((address_space(3))) void*)(As + (i * 4 + wave) * 512),
                16, 0, 0);
        }
#pragma unroll
        for (int i = 0; i < 4; i++) {
            int t = i * 256 + tid;
            int row = t >> 3;
            int kc = (t & 7) << 3;
            __builtin_amdgcn_global_load_lds(
                (const __attribute__((address_space(1))) void*)(Wb + (size_t)row * Cch + k0 + kc),
                (__attribute__((address_space(3))) void*)(Bs + (i * 4 + wave) * 512),
                16, 0, 0);
        }
        __syncthreads();
#pragma unroll
        for (int kk = 0; kk < 2; kk++) {
            bf16x8 a[4], b[4];
#pragma unroll
            for (int m2 = 0; m2 < 4; m2++)
                a[m2] = *(const bf16x8*)(As + (wr + m2 * 16 + lr) * 64 + kk * 32 + lg * 8);
#pragma unroll
            for (int n = 0; n < 4; n++)
                b[n] = *(const bf16x8*)(Bs + (wc + n * 16 + lr) * 64 + kk * 32 + lg * 8);
#pragma unroll
            for (int m2 = 0; m2 < 4; m2++)
#pragma unroll
                for (int n = 0; n < 4; n++)
                    acc[m2][n] = __builtin_amdgcn_mfma_f32_16x16x32_bf16(a[m2], b[n], acc[m2][n], 0, 0, 0);
        }
    }
#pragma unroll
    for (int m2 = 0; m2 < 4; m2++)
#pragma unroll
        for (int n = 0; n < 4; n++)
#pragma unroll
            for (int rr = 0; rr < 4; rr++) {
                int slot = bm + wr + m2 * 16 + lg * 4 + rr;
                int col = bn + wc + n * 16 + lr;
                if (slot < cn)
                    Ph[((size_t)e * CAP + slot) * 384 + col] = f2bf(acc[m2][n][rr]);
            }
}

// ---------------- combine q/k/v from NSPLIT split-K partials ----------------
__global__ __launch_bounds__(256) void combine_qkv(
    const unsigned short* __restrict__ P, const float* __restrict__ rw,
    const int* __restrict__ pos,
    unsigned short* __restrict__ qb, unsigned short* __restrict__ kb,
    unsigned short* __restrict__ vb) {
    int i = blockIdx.x * 256 + threadIdx.x;
    int n = i >> 5;
    int d4 = (i & 31) << 2;
    float aq[4] = {}, ak[4] = {}, av[4] = {};
#pragma unroll
    for (int e = 0; e < 16; e++) {
        int p = pos[(size_t)n * 16 + e];
        if (p >= 0) {
            float w = rw[(size_t)n * 16 + e];
            const unsigned short* r0 = P + ((size_t)e * CAP + p) * 384 + d4;
#pragma unroll
            for (int h = 0; h < NSPLIT; h++) {
                const unsigned short* rh = r0 + (size_t)h * PHALF;
                const u16x4 q4 = *(const u16x4*)(rh);
                const u16x4 k4 = *(const u16x4*)(rh + 128);
                const u16x4 v4 = *(const u16x4*)(rh + 256);
#pragma unroll
                for (int jj = 0; jj < 4; jj++) {
                    aq[jj] += w * bf2f(q4[jj]);
                    ak[jj] += w * bf2f(k4[jj]);
                    av[jj] += w * bf2f(v4[jj]);
                }
            }
        }
    }
    u16x4 sq = {f2bf(aq[0]), f2bf(aq[1]), f2bf(aq[2]), f2bf(aq[3])};
    u16x4 sk = {f2bf(ak[0]), f2bf(ak[1]), f2bf(ak[2]), f2bf(ak[3])};
    u16x4 sv = {f2bf(av[0]), f2bf(av[1]), f2bf(av[2]), f2bf(av[3])};
    *(u16x4*)(qb + (size_t)n * Dd + d4) = sq;
    *(u16x4*)(kb + (size_t)n * Dd + d4) = sk;
    *(u16x4*)(vb + (size_t)n * Dd + d4) = sv;
}

// ---------------- flash attention, split-KV ----------------
__global__ __launch_bounds__(256) void flash_kernel(
    const unsigned short* __restrict__ qb, const unsigned short* __restrict__ kb,
    const unsigned short* __restrict__ vT,
    float* __restrict__ Op, float* __restrict__ ml) {
    const int qt = blockIdx.x, ch = blockIdx.y, b = blockIdx.z;
    const int q0 = qt * 128, kv0 = ch * 512;
    if (kv0 > q0 + 127) return;
    __shared__ alignas(16) unsigned short Qs[128 * 128];
    __shared__ alignas(16) unsigned short Ks[64 * 128];
    __shared__ alignas(16) unsigned short Vs[128 * 64];
    __shared__ alignas(16) unsigned short Ps[4][32 * 64];
    const int tid = threadIdx.x;
    const int wave = tid >> 6, lane = tid & 63;
    const int lr = lane & 15, lg = lane >> 4;
    const float scale = 0.08838834764831845f;
    const unsigned short* Qg = qb + ((size_t)b * Tt + q0) * 128;
    const unsigned short* Kg = kb + (size_t)b * Tt * 128;
    const unsigned short* Vg = vT + (size_t)b * 128 * Tt;

#pragma unroll
    for (int i = 0; i < 8; i++) {
        int dof = (i * 256 + tid) << 4;
        int row = dof >> 8;
        int c16 = (dof >> 4) & 15;
        int s16 = c16 ^ (row & 7);
        __builtin_amdgcn_global_load_lds(
            (const __attribute__((address_space(1))) void*)(Qg + (size_t)row * 128 + s16 * 8),
            (__attribute__((address_space(3))) void*)(Qs + (size_t)(i * 4 + wave) * 512),
            16, 0, 0);
    }

    f32x4 acc_o[2][8] = {};
    float rm[2][4], rl[2][4];
#pragma unroll
    for (int mf = 0; mf < 2; mf++)
#pragma unroll
        for (int rg = 0; rg < 4; rg++) { rm[mf][rg] = -1e30f; rl[mf][rg] = 0.f; }

    const int ktend = min(kv0 + 512, q0 + 128);
    for (int kt = kv0; kt < ktend; kt += 64) {
        if (kt > kv0) __syncthreads();
#pragma unroll
        for (int i = 0; i < 4; i++) {
            int dof = (i * 256 + tid) << 4;
            int row = dof >> 8;
            int c16 = (dof >> 4) & 15;
            int s16 = c16 ^ (row & 7);
            __builtin_amdgcn_global_load_lds(
                (const __attribute__((address_space(1))) void*)(Kg + (size_t)(kt + row) * 128 + s16 * 8),
                (__attribute__((address_space(3))) void*)(Ks + (size_t)(i * 4 + wave) * 512),
                16, 0, 0);
        }
#pragma unroll
        for (int i = 0; i < 4; i++) {
            int dof = (i * 256 + tid) << 4;
            int row = dof >> 7;
            int c16 = (dof >> 4) & 7;
            int s16 = c16 ^ (row & 7);
            __builtin_amdgcn_global_load_lds(
                (const __attribute__((address_space(1))) void*)(Vg + (size_t)row * Tt + kt + s16 * 8),
                (__attribute__((address_space(3))) void*)(Vs + (size_t)(i * 4 + wave) * 512),
                16, 0, 0);
        }
        __syncthreads();

        f32x4 acc_s[2][4] = {};
#pragma unroll
        for (int kk = 0; kk < 4; kk++) {
            bf16x8 a[2], bfr[4];
#pragma unroll
            for (int mf = 0; mf < 2; mf++) {
                int row = wave * 32 + mf * 16 + lr;
                int c16 = (kk * 4 + lg) ^ (row & 7);
                a[mf] = *(const bf16x8*)(Qs + row * 128 + c16 * 8);
            }
#pragma unroll
            for (int nf = 0; nf < 4; nf++) {
                int row = nf * 16 + lr;
                int c16 = (kk * 4 + lg) ^ (row & 7);
                bfr[nf] = *(const bf16x8*)(Ks + row * 128 + c16 * 8);
            }
#pragma unroll
            for (int mf = 0; mf < 2; mf++)
#pragma unroll
                for (int nf = 0; nf < 4; nf++)
                    acc_s[mf][nf] = __builtin_amdgcn_mfma_f32_16x16x32_bf16(a[mf], bfr[nf], acc_s[mf][nf], 0, 0, 0);
        }

#pragma unroll
        for (int mf = 0; mf < 2; mf++) {
            float sv[4][4], pmax[4];
#pragma unroll
            for (int rg = 0; rg < 4; rg++) pmax[rg] = -1e30f;
#pragma unroll
            for (int nf = 0; nf < 4; nf++) {
                int colg = kt + nf * 16 + lr;
#pragma unroll
                for (int rg = 0; rg < 4; rg++) {
                    int rowg = q0 + wave * 32 + mf * 16 + lg * 4 + rg;
                    float s = acc_s[mf][nf][rg] * scale;
                    if (colg > rowg) s = -1e30f;
                    sv[nf][rg] = s;
                    pmax[rg] = fmaxf(pmax[rg], s);
                }
            }
#pragma unroll
            for (int rg = 0; rg < 4; rg++) {
#pragma unroll
                for (int off = 1; off < 16; off <<= 1)
                    pmax[rg] = fmaxf(pmax[rg], __shfl_xor(pmax[rg], off));
                float mnew = fmaxf(rm[mf][rg], pmax[rg]);
                float f = __expf(rm[mf][rg] - mnew);
                rm[mf][rg] = mnew;
#pragma unroll
                for (int nd = 0; nd < 8; nd++) acc_o[mf][nd][rg] *= f;
                float rsum = 0.f;
#pragma unroll
                for (int nf = 0; nf < 4; nf++) {
                    float p = __expf(sv[nf][rg] - mnew);
                    sv[nf][rg] = p;
                    rsum += p;
                }
#pragma unroll
                for (int off = 1; off < 16; off <<= 1) rsum += __shfl_xor(rsum, off);
                rl[mf][rg] = rl[mf][rg] * f + rsum;
                int rloc = mf * 16 + lg * 4 + rg;
#pragma unroll
                for (int nf = 0; nf < 4; nf++) {
                    int col = nf * 16 + lr;
                    int unit = (col >> 3) ^ (rloc & 7);
                    Ps[wave][rloc * 64 + unit * 8 + (col & 7)] = f2bf(sv[nf][rg]);
                }
            }
        }

#pragma unroll
        for (int kk2 = 0; kk2 < 2; kk2++) {
            bf16x8 a[2], bfr[8];
#pragma unroll
            for (int mf = 0; mf < 2; mf++) {
                int row = mf * 16 + lr;
                int c16 = (kk2 * 4 + lg) ^ (row & 7);
                a[mf] = *(const bf16x8*)(&Ps[wave][row * 64 + c16 * 8]);
            }
#pragma unroll
            for (int nd = 0; nd < 8; nd++) {
                int row = nd * 16 + lr;
                int c16 = ((kk2 * 4 + lg) ^ (row & 7)) & 7;
                bfr[nd] = *(const bf16x8*)(Vs + row * 64 + c16 * 8);
            }
#pragma unroll
            for (int mf = 0; mf < 2; mf++)
#pragma unroll
                for (int nd = 0; nd < 8; nd++)
                    acc_o[mf][nd] = __builtin_amdgcn_mfma_f32_16x16x32_bf16(a[mf], bfr[nd], acc_o[mf][nd], 0, 0, 0);
        }
    }

    float* Opb = Op + (((size_t)b * 4 + ch) * Tt) * 128;
    float* mlb = ml + (((size_t)b * 4 + ch) * Tt) * 2;
#pragma unroll
    for (int mf = 0; mf < 2; mf++)
#pragma unroll
        for (int rg = 0; rg < 4; rg++) {
            int rowl = q0 + wave * 32 + mf * 16 + lg * 4 + rg;
#pragma unroll
            for (int nd = 0; nd < 8; nd++)
                Opb[(size_t)rowl * 128 + nd * 16 + lr] = acc_o[mf][nd][rg];
            if (lr == 0) {
                mlb[rowl * 2] = rm[mf][rg];
                mlb[rowl * 2 + 1] = rl[mf][rg];
            }
        }
}

// ---------------- flash combine ----------------
__global__ __launch_bounds__(256) void flash_combine(
    const float* __restrict__ Op, const float* __restrict__ ml,
    const float* __restrict__ rw, const int* __restrict__ onmaskv,
    float* __restrict__ ob, unsigned short* __restrict__ og2) {
    int i = blockIdx.x * 256 + threadIdx.x;
    int n = i >> 7, d = i & 127;
    int rs = n & 2047, b = n >> 11;
    int nch = rs / 512 + 1;
    float ms = -1e30f;
    for (int c = 0; c < nch; c++)
        ms = fmaxf(ms, ml[(((size_t)b * 4 + c) * Tt + rs) * 2]);
    float num = 0.f, den = 0.f;
    for (int c = 0; c < nch; c++) {
        size_t rbase = ((size_t)b * 4 + c) * Tt + rs;
        float mi = ml[rbase * 2], li = ml[rbase * 2 + 1];
        float w = __expf(mi - ms);
        num += w * Op[rbase * 128 + d];
        den += w * li;
    }
    float o = num / den;
    ob[(size_t)n * 128 + d] = o;
    int m = onmaskv[n];
    if (!m) m = 1;
    int e0 = __ffs(m) - 1;
    int m2 = m & (m - 1);
    float w0 = rw[(size_t)n * 16 + e0];
    float w1 = m2 ? rw[(size_t)n * 16 + (__ffs(m2) - 1)] : 0.f;
    og2[(size_t)n * 256 + d] = f2bf(w0 * o);
    og2[(size_t)n * 256 + 128 + d] = f2bf(w1 * o);
}

// ---------------- pair-bucket output GEMM, XCD swizzle over bn tiles ----------------
// 1D grid MAXTILES*16; tile's 16 bn blocks placed at L = r + 8*(bn + 16*tq),
// tile = tq*8 + r -> all bn share L%8 (same XCD) -> A-tile L2-shared.
__global__ __launch_bounds__(256) void gemm_pair(
    const unsigned short* __restrict__ og2,
    const unsigned short* __restrict__ woT,
    const int* __restrict__ ptok, const int4* __restrict__ tiledesc,
    const int* __restrict__ ntile_dev,
    float* __restrict__ out) {
    const int L = blockIdx.x;
    const int r = L & 7, s = L >> 3;
    const int bnidx = s & 15, tq = s >> 4;
    const int tile = tq * 8 + r;
    if (tile >= *ntile_dev) return;
    const int4 td = tiledesc[tile];
    const int ei = td.x >> 4, ej = td.x & 15;
    const int mstart = td.y, mcnt = td.z;
    const int bn = bnidx * 128;
    __shared__ alignas(16) unsigned short As[128 * 64];
    __shared__ alignas(16) unsigned short Bs[128 * 64];
    __shared__ int toks[128];
    const int tid = threadIdx.x;
    if (tid < 128) toks[tid] = ptok[mstart + min(tid, mcnt - 1)];
    const int wave = tid >> 6, lane = tid & 63;
    const int lr = lane & 15, lg = lane >> 4;
    const int wr = (wave >> 1) * 64, wc = (wave & 1) * 64;
    f32x4 acc[4][4] = {};

#pragma unroll
    for (int ck = 0; ck < 4; ck++) {
        const int ebase = (ck < 2 ? ei : ej) * 128 + (ck & 1) * 64;
        const int abase = ck * 64;
        __syncthreads();
#pragma unroll
        for (int q = 0; q < 4; q++) {
            int t = q * 256 + tid;
            int row = t >> 3;
            int kc = (t & 7) << 3;
            __builtin_amdgcn_global_load_lds(
                (const __attribute__((address_space(1))) void*)(og2 + (size_t)toks[row] * 256 + abase + kc),
                (__attribute__((address_space(3))) void*)(As + (q * 4 + wave) * 512),
                16, 0, 0);
        }
#pragma unroll
        for (int q = 0; q < 4; q++) {
            int t = q * 256 + tid;
            int row = t >> 3;
            int kc = (t & 7) << 3;
            __builtin_amdgcn_global_load_lds(
                (const __attribute__((address_space(1))) void*)(woT + (size_t)(bn + row) * 2048 + ebase + kc),
                (__attribute__((address_space(3))) void*)(Bs + (q * 4 + wave) * 512),
                16, 0, 0);
        }
        __syncthreads();
#pragma unroll
        for (int kk = 0; kk < 2; kk++) {
            bf16x8 a[4], b[4];
#pragma unroll
            for (int m = 0; m < 4; m++)
                a[m] = *(const bf16x8*)(As + (wr + m * 16 + lr) * 64 + kk * 32 + lg * 8);
#pragma unroll
            for (int n = 0; n < 4; n++)
                b[n] = *(const bf16x8*)(Bs + (wc + n * 16 + lr) * 64 + kk * 32 + lg * 8);
#pragma unroll
            for (int m = 0; m < 4; m++)
#pragma unroll
                for (int n = 0; n < 4; n++)
                    acc[m][n] = __builtin_amdgcn_mfma_f32_16x16x32_bf16(a[m], b[n], acc[m][n], 0, 0, 0);
        }
    }
#pragma unroll
    for (int m = 0; m < 4; m++)
#pragma unroll
        for (int n = 0; n < 4; n++)
#pragma unroll
            for (int rr2 = 0; rr2 < 4; rr2++) {
                int rowt = wr + m * 16 + lg * 4 + rr2;
                if (rowt < mcnt) {
                    int tok = toks[rowt];
                    out[(size_t)tok * 2048 + bn + wc + n * 16 + lr] = acc[m][n][rr2];
                }
            }
}

// ---------------- rare overflow path ----------------
__global__ __launch_bounds__(256) void overflow_kernel(
    const int* __restrict__ ocnt, const int* __restrict__ olist,
    const float* __restrict__ ob, const unsigned short* __restrict__ woT,
    const float* __restrict__ rw, float* __restrict__ out) {
    const int ne = *ocnt;
    __shared__ float osh[128];
    for (int it = blockIdx.x; it < ne; it += gridDim.x) {
        int n = olist[2 * it], e = olist[2 * it + 1];
        float wgt = rw[(size_t)n * 16 + e];
        if (threadIdx.x < 128) osh[threadIdx.x] = ob[(size_t)n * Dd + threadIdx.x];
        __syncthreads();
#pragma unroll 1
        for (int cc = 0; cc < 8; cc++) {
            int c = threadIdx.x * 8 + cc;
            float a = 0.f;
            for (int k = 0; k < 128; k++)
                a += osh[k] * bf2f(woT[(size_t)c * 2048 + e * 128 + k]);
            atomicAdd(&out[(size_t)n * 2048 + c], wgt * a);
        }
        __syncthreads();
    }
}

extern "C" void kernel_launch(void* const* d_in, const int* in_sizes, int n_in,
                              void* d_out, int out_size, void* d_ws, size_t ws_size,
                              hipStream_t stream) {
    (void)in_sizes; (void)n_in; (void)out_size; (void)ws_size;
    const float* hidden = (const float*)d_in[0];
    const float* sim = (const float*)d_in[1];
    const float* gates = (const float*)d_in[2];
    const float* qp = (const float*)d_in[3];
    const float* kp = (const float*)d_in[4];
    const float* vp = (const float*)d_in[5];
    const float* op = (const float*)d_in[6];
    const int* minex = (const int*)d_in[7];
    float* out = (float*)d_out;

    char* w = (char*)d_ws;
    size_t off = 0;
    auto alloc = [&](size_t bytes) -> char* {
        char* p = w + off;
        off = (off + bytes + 255) & ~(size_t)255;
        return p;
    };
    unsigned short* xb = (unsigned short*)alloc((size_t)Nn * Cch * 2);
    unsigned short* wqkvT = (unsigned short*)alloc((size_t)Ee * 384 * Cch * 2);
    unsigned short* woT = (unsigned short*)alloc((size_t)Cch * Ee * Dd * 2);
    float* rw = (float*)alloc((size_t)Nn * Ee * 4);
    float* sninv = (float*)alloc(256);
    float* simT = (float*)alloc((size_t)Ee * Cch * 4);
    int* cnt = (int*)alloc(256);
    int* onmaskv = (int*)alloc((size_t)Nn * 4);
    int* idx = (int*)alloc((size_t)Ee * CAP * 4);
    int* pos = (int*)alloc((size_t)Nn * 16 * 4);
    int* ptok = (int*)alloc((size_t)Nn * 4);
    int4* tiledesc = (int4*)alloc((size_t)MAXTILES * 16);
    int* ntile_dev = (int*)alloc(256);
    int* ocnt = (int*)alloc(256);
    int* olist = (int*)alloc((size_t)Nn * 14 * 2 * 4);
    char* big = alloc((size_t)Bsz * Tt * Tt * 4);  // Pc (31MB), later Op partials (16.8MB)
    unsigned short* qb = (unsigned short*)alloc((size_t)Nn * Dd * 2);
    unsigned short* kb = (unsigned short*)alloc((size_t)Nn * Dd * 2);
    unsigned short* vb = (unsigned short*)alloc((size_t)Nn * Dd * 2);
    unsigned short* vT = (unsigned short*)alloc((size_t)Bsz * Dd * Tt * 2);
    float* ob = (float*)alloc((size_t)Nn * Dd * 4);
    unsigned short* og2 = (unsigned short*)alloc((size_t)Nn * 256 * 2);
    float* ml = (float*)alloc((size_t)Bsz * 4 * Tt * 2 * 4);
    unsigned short* Pc = (unsigned short*)big;
    float* Op = (float*)big;  // aliases Pc (dead after combine_qkv)

    colnorm_kernel<<<1, 256, 0, stream>>>(sim, sninv);
    simt_kernel<<<(Ee * Cch) / 256, 256, 0, stream>>>(sim, simT);
    gating5_kernel<<<Nn / 32, 1024, 0, stream>>>(hidden, simT, gates, sninv, minex, rw, xb, onmaskv);
    scan_kernel<<<Ee, 256, 0, stream>>>(onmaskv, idx, pos, cnt);
    scan_pair<<<1, 256, 0, stream>>>(onmaskv, ptok, tiledesc, ntile_dev, ocnt, olist);

    // weight transposes (f32 -> bf16) into fused [E][384][C]
    transpose_f32_bf16<<<dim3(Dd / 32, Cch / 32, Ee), 256, 0, stream>>>(
        qp, wqkvT + 0 * Dd * Cch, Cch, Dd, (long)Cch * Dd, (long)384 * Cch);
    transpose_f32_bf16<<<dim3(Dd / 32, Cch / 32, Ee), 256, 0, stream>>>(
        kp, wqkvT + 1 * Dd * Cch, Cch, Dd, (long)Cch * Dd, (long)384 * Cch);
    transpose_f32_bf16<<<dim3(Dd / 32, Cch / 32, Ee), 256, 0, stream>>>(
        vp, wqkvT + 2 * Dd * Cch, Cch, Dd, (long)Cch * Dd, (long)384 * Cch);
    transpose_f32_bf16<<<dim3((Ee * Dd) / 32, Cch / 32, 1), 256, 0, stream>>>(
        op, woT, Ee * Dd, Cch, 0L, 0L);

    // gathered per-expert QKV projection (split-K=2, XCD swizzle), then combine
    gemm_qkv_gather<<<NGRP * 3, 256, 0, stream>>>(xb, wqkvT, idx, cnt, Pc);
    combine_qkv<<<(Nn * 32) / 256, 256, 0, stream>>>(Pc, rw, pos, qb, kb, vb);

    // V transpose per batch
    transpose_u16<<<dim3(Dd / 32, Tt / 32, Bsz), 256, 0, stream>>>(
        vb, vT, Tt, Dd, (long)Tt * Dd, (long)Dd * Tt);

    // flash attention (split-KV) + combine (writes ob and og2)
    flash_kernel<<<dim3(Tt / 128, 4, Bsz), 256, 0, stream>>>(qb, kb, vT, Op, ml);
    flash_combine<<<(Nn * 128) / 256, 256, 0, stream>>>(Op, ml, rw, onmaskv, ob, og2);

    // output projection: pair-bucket grouped GEMM (XCD-swizzled bn tiles)
    gemm_pair<<<MAXTILES * 16, 256, 0, stream>>>(
        og2, woT, ptok, tiledesc, ntile_dev, out);
    overflow_kernel<<<256, 256, 0, stream>>>(ocnt, olist, ob, woT, rw, out);
}

// Round 14
// 282.546 us; speedup vs baseline: 1.5380x; 1.0149x over previous
//
#include <hip/hip_runtime.h>
#include <hip/hip_bf16.h>

#define DEV __device__ __forceinline__

typedef short bf16x8 __attribute__((ext_vector_type(8)));
typedef float f32x4 __attribute__((ext_vector_type(4)));
typedef unsigned short u16x4 __attribute__((ext_vector_type(4)));

static constexpr int Bsz = 4, Tt = 2048, Cch = 2048, Dd = 128, Ee = 16;
static constexpr int Nn = Bsz * Tt;
static constexpr int CAP = 1280;
static constexpr int NSPLIT = 2;
static constexpr size_t PHALF = (size_t)Ee * CAP * 384;
static constexpr int MAXTILES = 320;
static constexpr int MT = CAP / 128;
static constexpr int NGRP = MT * Ee * NSPLIT;

DEV unsigned short f2bf(float v) {
    __hip_bfloat16 h = __float2bfloat16(v);
    return __builtin_bit_cast(unsigned short, h);
}
DEV float bf2f(unsigned short u) {
    unsigned int x = ((unsigned int)u) << 16;
    return __builtin_bit_cast(float, x);
}

// ---------------- sim_matrix column norms ----------------
__global__ __launch_bounds__(256) void colnorm_kernel(const float* __restrict__ sim,
                                                      float* __restrict__ sninv) {
    int e = threadIdx.x & 15, j = threadIdx.x >> 4;
    float ss = 0.f;
    for (int r = j; r < Cch; r += 16) {
        float v = sim[r * Ee + e];
        ss += v * v;
    }
    __shared__ float red[16][17];
    red[j][e] = ss;
    __syncthreads();
    if (threadIdx.x < 16) {
        float s = 0.f;
        for (int t = 0; t < 16; t++) s += red[t][threadIdx.x];
        sninv[threadIdx.x] = 1.f / fmaxf(sqrtf(s), 1e-12f);
    }
}

// ---------------- sim transpose ----------------
__global__ __launch_bounds__(256) void simt_kernel(const float* __restrict__ sim,
                                                   float* __restrict__ simT) {
    int i = blockIdx.x * 256 + threadIdx.x;
    int e = i >> 11, c = i & 2047;
    simT[i] = sim[c * 16 + e];
}

// ---------------- gating: full simT in 128 KiB LDS; 1024 threads ----------------
__global__ __launch_bounds__(1024) void gating5_kernel(
    const float* __restrict__ x, const float* __restrict__ simT,
    const float* __restrict__ gates, const float* __restrict__ sninv,
    const int* __restrict__ minex,
    float* __restrict__ rw, unsigned short* __restrict__ xb,
    int* __restrict__ onmaskv) {
    __shared__ f32x4 ssim[8192];
    const int tid = threadIdx.x;
    const f32x4* stg = (const f32x4*)simT;
#pragma unroll
    for (int i = 0; i < 8; i++) ssim[i * 1024 + tid] = stg[i * 1024 + tid];
    __syncthreads();
    const int wave = tid >> 6, lane = tid & 63;

#pragma unroll 1
    for (int g = 0; g < 2; g++) {
        const int n = blockIdx.x * 32 + g * 16 + wave;
        const f32x4* xr = (const f32x4*)(x + (size_t)n * Cch);
        u16x4* xbr = (u16x4*)(xb + (size_t)n * Cch);
        float ss = 0.f;
        float d[16];
#pragma unroll
        for (int e = 0; e < 16; e++) d[e] = 0.f;

#pragma unroll 2
        for (int it = 0; it < 8; it++) {
            const int i = it * 64 + lane;
            const f32x4 xv = xr[i];
            ss += xv[0] * xv[0] + xv[1] * xv[1] + xv[2] * xv[2] + xv[3] * xv[3];
            u16x4 xc = {f2bf(xv[0]), f2bf(xv[1]), f2bf(xv[2]), f2bf(xv[3])};
            xbr[i] = xc;
#pragma unroll
            for (int e = 0; e < 16; e++) {
                const f32x4 sv = ssim[e * 512 + i];
                d[e] += xv[0] * sv[0] + xv[1] * sv[1] + xv[2] * sv[2] + xv[3] * sv[3];
            }
        }
#pragma unroll
        for (int off = 32; off; off >>= 1) {
            ss += __shfl_down(ss, off);
#pragma unroll
            for (int e = 0; e < 16; e++) d[e] += __shfl_down(d[e], off);
        }
        if (lane == 0) {
            float inv = 1.f / fmaxf(sqrtf(ss), 1e-12f);
            float logit[16];
            int onmask = 0;
#pragma unroll
            for (int e = 0; e < 16; e++) {
                float sg = 1.f / (1.f + __expf(-gates[e]));
                float l = d[e] * inv * sninv[e] - sg;
                logit[e] = l;
                if (l > 0.f) onmask |= (1 << e);
            }
            if (onmask == 0) {
                int k = *minex;
                int ch = 0;
                for (int kk = 0; kk < k; kk++) {
                    float bv = -1e30f;
                    int be = 0;
#pragma unroll
                    for (int e = 0; e < 16; e++)
                        if (!((ch >> e) & 1) && logit[e] > bv) { bv = logit[e]; be = e; }
                    ch |= (1 << be);
                }
                onmask = ch;
            }
            float mx = -1e30f;
#pragma unroll
            for (int e = 0; e < 16; e++)
                if ((onmask >> e) & 1) mx = fmaxf(mx, fmaxf(logit[e], 0.f));
            float pe[16];
            float sum = 0.f;
#pragma unroll
            for (int e = 0; e < 16; e++) {
                pe[e] = ((onmask >> e) & 1) ? __expf(fmaxf(logit[e], 0.f) - mx) : 0.f;
                sum += pe[e];
            }
            float isum = 1.f / sum;
#pragma unroll
            for (int e = 0; e < 16; e++) rw[(size_t)n * 16 + e] = pe[e] * isum;
            onmaskv[n] = onmask;
        }
    }
}

// ---------------- deterministic expert-list scan ----------------
__global__ __launch_bounds__(256) void scan_kernel(
    const int* __restrict__ onmaskv,
    int* __restrict__ idx, int* __restrict__ pos, int* __restrict__ cnt) {
    const int e = blockIdx.x;
    const int tid = threadIdx.x;
    const int base = tid * 32;
    int om[32];
    int c = 0;
#pragma unroll
    for (int i = 0; i < 32; i++) {
        om[i] = (onmaskv[base + i] >> e) & 1;
        c += om[i];
    }
    const int lane = tid & 63, w = tid >> 6;
    int sc = c;
#pragma unroll
    for (int off = 1; off < 64; off <<= 1) {
        int t = __shfl_up(sc, off);
        if (lane >= off) sc += t;
    }
    __shared__ int wsum[4];
    if (lane == 63) wsum[w] = sc;
    __syncthreads();
    int wbase = 0;
    for (int i = 0; i < w; i++) wbase += wsum[i];
    int slot = wbase + sc - c;
#pragma unroll
    for (int i = 0; i < 32; i++) {
        int n = base + i;
        int p = -1;
        if (om[i]) {
            if (slot < CAP) {
                idx[(size_t)e * CAP + slot] = n;
                p = slot;
            }
            slot++;
        }
        pos[(size_t)n * 16 + e] = p;
    }
    if (tid == 255) cnt[e] = slot;
}

// ---------------- pair-bucket scan ----------------
__global__ __launch_bounds__(256) void scan_pair(
    const int* __restrict__ onmaskv,
    int* __restrict__ ptok, int4* __restrict__ tiledesc, int* __restrict__ ntile_dev,
    int* __restrict__ ocnt, int* __restrict__ olist) {
    __shared__ int hist[256], cursor[256];
    __shared__ int wsum[4], wsum2[4];
    const int tid = threadIdx.x;
    if (tid == 0) *ocnt = 0;
    hist[tid] = 0;
    __syncthreads();
    for (int i = 0; i < 32; i++) {
        int n = tid * 32 + i;
        int m = onmaskv[n];
        if (!m) m = 1;
        int e0 = __ffs(m) - 1;
        int m2 = m & (m - 1);
        int e1 = m2 ? (__ffs(m2) - 1) : e0;
        atomicAdd(&hist[e0 * 16 + e1], 1);
        int mrest = m2 & (m2 - 1);
        while (mrest) {
            int e = __ffs(mrest) - 1;
            int s = atomicAdd(ocnt, 1);
            olist[2 * s] = n;
            olist[2 * s + 1] = e;
            mrest &= (mrest - 1);
        }
    }
    __syncthreads();
    const int lane = tid & 63, w = tid >> 6;
    int v = hist[tid];
    int s = v;
#pragma unroll
    for (int off = 1; off < 64; off <<= 1) {
        int t = __shfl_up(s, off);
        if (lane >= off) s += t;
    }
    if (lane == 63) wsum[w] = s;
    __syncthreads();
    int add = 0;
    for (int i = 0; i < w; i++) add += wsum[i];
    int excl = s + add - v;
    cursor[tid] = excl;
    int nt = (v + 127) >> 7;
    int s2 = nt;
#pragma unroll
    for (int off = 1; off < 64; off <<= 1) {
        int t = __shfl_up(s2, off);
        if (lane >= off) s2 += t;
    }
    if (lane == 63) wsum2[w] = s2;
    __syncthreads();
    int add2 = 0;
    for (int i = 0; i < w; i++) add2 += wsum2[i];
    int texcl = s2 + add2 - nt;
    for (int m = 0; m < nt; m++)
        tiledesc[texcl + m] = make_int4(tid, excl + m * 128, min(128, v - m * 128), 0);
    if (tid == 255) *ntile_dev = texcl + nt;
    __syncthreads();
    for (int i = 0; i < 32; i++) {
        int n = tid * 32 + i;
        int m = onmaskv[n];
        if (!m) m = 1;
        int e0 = __ffs(m) - 1;
        int m2 = m & (m - 1);
        int e1 = m2 ? (__ffs(m2) - 1) : e0;
        int slot = atomicAdd(&cursor[e0 * 16 + e1], 1);
        ptok[slot] = n;
    }
}

// ---------------- fused q/k/v weight transpose: [C,D] -> [D,C] per (tensor, expert) ----------------
__global__ __launch_bounds__(256) void transpose_qkv(
    const float* __restrict__ qp, const float* __restrict__ kp,
    const float* __restrict__ vp, unsigned short* __restrict__ wqkvT) {
    const int z = blockIdx.z;
    const int t3 = z >> 4, e = z & 15;
    const float* src = (t3 == 0 ? qp : (t3 == 1 ? kp : vp)) + (size_t)e * Cch * Dd;
    unsigned short* dst = wqkvT + (size_t)e * 384 * Cch + (size_t)t3 * Dd * Cch;
    __shared__ float tile[32][33];
    int bx = blockIdx.x * 32, by = blockIdx.y * 32;
    int tx = threadIdx.x & 31, ty = threadIdx.x >> 5;
#pragma unroll
    for (int i = 0; i < 4; i++)
        tile[ty + i * 8][tx] = src[(size_t)(by + ty + i * 8) * Dd + bx + tx];
    __syncthreads();
#pragma unroll
    for (int i = 0; i < 4; i++)
        dst[(size_t)(bx + ty + i * 8) * Cch + by + tx] = f2bf(tile[tx][ty + i * 8]);
}

__global__ __launch_bounds__(256) void transpose_f32_bf16(
    const float* __restrict__ src, unsigned short* __restrict__ dst,
    int R, int Ccol, long ss, long ds) {
    __shared__ float tile[32][33];
    src += (size_t)blockIdx.z * ss;
    dst += (size_t)blockIdx.z * ds;
    int bx = blockIdx.x * 32, by = blockIdx.y * 32;
    int tx = threadIdx.x & 31, ty = threadIdx.x >> 5;
#pragma unroll
    for (int i = 0; i < 4; i++)
        tile[ty + i * 8][tx] = src[(size_t)(by + ty + i * 8) * Ccol + bx + tx];
    __syncthreads();
#pragma unroll
    for (int i = 0; i < 4; i++)
        dst[(size_t)(bx + ty + i * 8) * R + by + tx] = f2bf(tile[tx][ty + i * 8]);
}

__global__ __launch_bounds__(256) void transpose_u16(
    const unsigned short* __restrict__ src, unsigned short* __restrict__ dst,
    int R, int Ccol, long ss, long ds) {
    __shared__ unsigned short tile[32][33];
    src += (size_t)blockIdx.z * ss;
    dst += (size_t)blockIdx.z * ds;
    int bx = blockIdx.x * 32, by = blockIdx.y * 32;
    int tx = threadIdx.x & 31, ty = threadIdx.x >> 5;
#pragma unroll
    for (int i = 0; i < 4; i++)
        tile[ty + i * 8][tx] = src[(size_t)(by + ty + i * 8) * Ccol + bx + tx];
    __syncthreads();
#pragma unroll
    for (int i = 0; i < 4; i++)
        dst[(size_t)(bx + ty + i * 8) * R + by + tx] = tile[tx][ty + i * 8];
}

// ---------------- gathered QKV projection, split-K=2, XCD swizzle, DOUBLE-BUFFERED prefetch ----------------
// T3 minimum recipe: stage(t+1) issued BEFORE compute(t); single __syncthreads per iter
// (its vmcnt drain lands after the MFMAs, so tile t+1 HBM latency hides under compute).
__global__ __launch_bounds__(256) void gemm_qkv_gather(
    const unsigned short* __restrict__ X, const unsigned short* __restrict__ W,
    const int* __restrict__ idx, const int* __restrict__ cnt,
    unsigned short* __restrict__ P) {
    const int L = blockIdx.x;
    const int r = L & 7, s = L >> 3;
    const int gq = s / 3, j = s - gq * 3;
    const int g = gq * 8 + r;
    const int m = g % MT;
    const int zc = g / MT;
    const int e = zc >> 1, kc2 = zc & 1;
    const int cn = min(cnt[e], CAP);
    const int bm = m * 128;
    if (bm >= cn) return;
    const int bn = j * 128;
    unsigned short* Ph = P + (size_t)kc2 * PHALF;
    __shared__ alignas(16) unsigned short As[2 * 128 * 64];
    __shared__ alignas(16) unsigned short Bs[2 * 128 * 64];
    __shared__ int toks[128];
    const int tid = threadIdx.x;
    if (tid < 128) toks[tid] = idx[(size_t)e * CAP + min(bm + tid, cn - 1)];
    const unsigned short* Wb = W + ((size_t)e * 384 + bn) * Cch;
    const int wave = tid >> 6, lane = tid & 63;
    const int lr = lane & 15, lg = lane >> 4;
    const int wr = (wave >> 1) * 64, wc = (wave & 1) * 64;
    const int kbase = kc2 * 1024;
    f32x4 acc[4][4] = {};

    auto stage = [&](int buf, int k0) {
#pragma unroll
        for (int i = 0; i < 4; i++) {
            int t = i * 256 + tid;
            int row = t >> 3;
            int kc = (t & 7) << 3;
            __builtin_amdgcn_global_load_lds(
                (const __attribute__((address_space(1))) void*)(X + (size_t)toks[row] * Cch + k0 + kc),
                (__attribute__((address_space(3))) void*)(As + buf * 8192 + (i * 4 + wave) * 512),
                16, 0, 0);
        }
#pragma unroll
        for (int i = 0; i < 4; i++) {
            int t = i * 256 + tid;
            int row = t >> 3;
            int kc = (t & 7) << 3;
            __builtin_amdgcn_global_load_lds(
                (const __attribute__((address_space(1))) void*)(Wb + (size_t)row * Cch + k0 + kc),
                (__attribute__((address_space(3))) void*)(Bs + buf * 8192 + (i * 4 + wave) * 512),
                16, 0, 0);
        }
    };

    __syncthreads();        // toks visible to all waves
    stage(0, kbase);
    __syncthreads();        // buf0 loads drained
    int cur = 0;
#pragma unroll 1
    for (int t = 0; t < 16; t++) {
        if (t + 1 < 16) stage(cur ^ 1, kbase + (t + 1) * 64);
        const unsigned short* Ab = As + cur * 8192;
        const unsigned short* Bb = Bs + cur * 8192;
#pragma unroll
        for (int kk = 0; kk < 2; kk++) {
            bf16x8 a[4], b[4];
#pragma unroll
            for (int m2 = 0; m2 < 4; m2++)
                a[m2] = *(const bf16x8*)(Ab + (wr + m2 * 16 + lr) * 64 + kk * 32 + lg * 8);
#pragma unroll
            for (int n = 0; n < 4; n++)
                b[n] = *(const bf16x8*)(Bb + (wc + n * 16 + lr) * 64 + kk * 32 + lg * 8);
#pragma unroll
            for (int m2 = 0; m2 < 4; m2++)
#pragma unroll
                for (int n = 0; n < 4; n++)
                    acc[m2][n] = __builtin_amdgcn_mfma_f32_16x16x32_bf16(a[m2], b[n], acc[m2][n], 0, 0, 0);
        }
        __syncthreads();    // drains t+1 loads; all waves done reading buf cur
        cur ^= 1;
    }
#pragma unroll
    for (int m2 = 0; m2 < 4; m2++)
#pragma unroll
        for (int n = 0; n < 4; n++)
#pragma unroll
            for (int rr = 0; rr < 4; rr++) {
                int slot = bm + wr + m2 * 16 + lg * 4 + rr;
                int col = bn + wc + n * 16 + lr;
                if (slot < cn)
                    Ph[((size_t)e * CAP + slot) * 384 + col] = f2bf(acc[m2][n][rr]);
            }
}

// ---------------- combine q/k/v from NSPLIT split-K partials ----------------
__global__ __launch_bounds__(256) void combine_qkv(
    const unsigned short* __restrict__ P, const float* __restrict__ rw,
    const int* __restrict__ pos,
    unsigned short* __restrict__ qb, unsigned short* __restrict__ kb,
    unsigned short* __restrict__ vb) {
    int i = blockIdx.x * 256 + threadIdx.x;
    int n = i >> 5;
    int d4 = (i & 31) << 2;
    float aq[4] = {}, ak[4] = {}, av[4] = {};
#pragma unroll
    for (int e = 0; e < 16; e++) {
        int p = pos[(size_t)n * 16 + e];
        if (p >= 0) {
            float w = rw[(size_t)n * 16 + e];
            const unsigned short* r0 = P + ((size_t)e * CAP + p) * 384 + d4;
#pragma unroll
            for (int h = 0; h < NSPLIT; h++) {
                const unsigned short* rh = r0 + (size_t)h * PHALF;
                const u16x4 q4 = *(const u16x4*)(rh);
                const u16x4 k4 = *(const u16x4*)(rh + 128);
                const u16x4 v4 = *(const u16x4*)(rh + 256);
#pragma unroll
                for (int jj = 0; jj < 4; jj++) {
                    aq[jj] += w * bf2f(q4[jj]);
                    ak[jj] += w * bf2f(k4[jj]);
                    av[jj] += w * bf2f(v4[jj]);
                }
            }
        }
    }
    u16x4 sq = {f2bf(aq[0]), f2bf(aq[1]), f2bf(aq[2]), f2bf(aq[3])};
    u16x4 sk = {f2bf(ak[0]), f2bf(ak[1]), f2bf(ak[2]), f2bf(ak[3])};
    u16x4 sv = {f2bf(av[0]), f2bf(av[1]), f2bf(av[2]), f2bf(av[3])};
    *(u16x4*)(qb + (size_t)n * Dd + d4) = sq;
    *(u16x4*)(kb + (size_t)n * Dd + d4) = sk;
    *(u16x4*)(vb + (size_t)n * Dd + d4) = sv;
}

// ---------------- flash attention, split-KV ----------------
__global__ __launch_bounds__(256) void flash_kernel(
    const unsigned short* __restrict__ qb, const unsigned short* __restrict__ kb,
    const unsigned short* __restrict__ vT,
    float* __restrict__ Op, float* __restrict__ ml) {
    const int qt = blockIdx.x, ch = blockIdx.y, b = blockIdx.z;
    const int q0 = qt * 128, kv0 = ch * 512;
    if (kv0 > q0 + 127) return;
    __shared__ alignas(16) unsigned short Qs[128 * 128];
    __shared__ alignas(16) unsigned short Ks[64 * 128];
    __shared__ alignas(16) unsigned short Vs[128 * 64];
    __shared__ alignas(16) unsigned short Ps[4][32 * 64];
    const int tid = threadIdx.x;
    const int wave = tid >> 6, lane = tid & 63;
    const int lr = lane & 15, lg = lane >> 4;
    const float scale = 0.08838834764831845f;
    const unsigned short* Qg = qb + ((size_t)b * Tt + q0) * 128;
    const unsigned short* Kg = kb + (size_t)b * Tt * 128;
    const unsigned short* Vg = vT + (size_t)b * 128 * Tt;

#pragma unroll
    for (int i = 0; i < 8; i++) {
        int dof = (i * 256 + tid) << 4;
        int row = dof >> 8;
        int c16 = (dof >> 4) & 15;
        int s16 = c16 ^ (row & 7);
        __builtin_amdgcn_global_load_lds(
            (const __attribute__((address_space(1))) void*)(Qg + (size_t)row * 128 + s16 * 8),
            (__attribute__((address_space(3))) void*)(Qs + (size_t)(i * 4 + wave) * 512),
            16, 0, 0);
    }

    f32x4 acc_o[2][8] = {};
    float rm[2][4], rl[2][4];
#pragma unroll
    for (int mf = 0; mf < 2; mf++)
#pragma unroll
        for (int rg = 0; rg < 4; rg++) { rm[mf][rg] = -1e30f; rl[mf][rg] = 0.f; }

    const int ktend = min(kv0 + 512, q0 + 128);
    for (int kt = kv0; kt < ktend; kt += 64) {
        if (kt > kv0) __syncthreads();
#pragma unroll
        for (int i = 0; i < 4; i++) {
            int dof = (i * 256 + tid) << 4;
            int row = dof >> 8;
            int c16 = (dof >> 4) & 15;
            int s16 = c16 ^ (row & 7);
            __builtin_amdgcn_global_load_lds(
                (const __attribute__((address_space(1))) void*)(Kg + (size_t)(kt + row) * 128 + s16 * 8),
                (__attribute__((address_space(3))) void*)(Ks + (size_t)(i * 4 + wave) * 512),
                16, 0, 0);
        }
#pragma unroll
        for (int i = 0; i < 4; i++) {
            int dof = (i * 256 + tid) << 4;
            int row = dof >> 7;
            int c16 = (dof >> 4) & 7;
            int s16 = c16 ^ (row & 7);
            __builtin_amdgcn_global_load_lds(
                (const __attribute__((address_space(1))) void*)(Vg + (size_t)row * Tt + kt + s16 * 8),
                (__attribute__((address_space(3))) void*)(Vs + (size_t)(i * 4 + wave) * 512),
                16, 0, 0);
        }
        __syncthreads();

        f32x4 acc_s[2][4] = {};
#pragma unroll
        for (int kk = 0; kk < 4; kk++) {
            bf16x8 a[2], bfr[4];
#pragma unroll
            for (int mf = 0; mf < 2; mf++) {
                int row = wave * 32 + mf * 16 + lr;
                int c16 = (kk * 4 + lg) ^ (row & 7);
                a[mf] = *(const bf16x8*)(Qs + row * 128 + c16 * 8);
            }
#pragma unroll
            for (int nf = 0; nf < 4; nf++) {
                int row = nf * 16 + lr;
                int c16 = (kk * 4 + lg) ^ (row & 7);
                bfr[nf] = *(const bf16x8*)(Ks + row * 128 + c16 * 8);
            }
#pragma unroll
            for (int mf = 0; mf < 2; mf++)
#pragma unroll
                for (int nf = 0; nf < 4; nf++)
                    acc_s[mf][nf] = __builtin_amdgcn_mfma_f32_16x16x32_bf16(a[mf], bfr[nf], acc_s[mf][nf], 0, 0, 0);
        }

#pragma unroll
        for (int mf = 0; mf < 2; mf++) {
            float sv[4][4], pmax[4];
#pragma unroll
            for (int rg = 0; rg < 4; rg++) pmax[rg] = -1e30f;
#pragma unroll
            for (int nf = 0; nf < 4; nf++) {
                int colg = kt + nf * 16 + lr;
#pragma unroll
                for (int rg = 0; rg < 4; rg++) {
                    int rowg = q0 + wave * 32 + mf * 16 + lg * 4 + rg;
                    float s = acc_s[mf][nf][rg] * scale;
                    if (colg > rowg) s = -1e30f;
                    sv[nf][rg] = s;
                    pmax[rg] = fmaxf(pmax[rg], s);
                }
            }
#pragma unroll
            for (int rg = 0; rg < 4; rg++) {
#pragma unroll
                for (int off = 1; off < 16; off <<= 1)
                    pmax[rg] = fmaxf(pmax[rg], __shfl_xor(pmax[rg], off));
                float mnew = fmaxf(rm[mf][rg], pmax[rg]);
                float f = __expf(rm[mf][rg] - mnew);
                rm[mf][rg] = mnew;
#pragma unroll
                for (int nd = 0; nd < 8; nd++) acc_o[mf][nd][rg] *= f;
                float rsum = 0.f;
#pragma unroll
                for (int nf = 0; nf < 4; nf++) {
                    float p = __expf(sv[nf][rg] - mnew);
                    sv[nf][rg] = p;
                    rsum += p;
                }
#pragma unroll
                for (int off = 1; off < 16; off <<= 1) rsum += __shfl_xor(rsum, off);
                rl[mf][rg] = rl[mf][rg] * f + rsum;
                int rloc = mf * 16 + lg * 4 + rg;
#pragma unroll
                for (int nf = 0; nf < 4; nf++) {
                    int col = nf * 16 + lr;
                    int unit = (col >> 3) ^ (rloc & 7);
                    Ps[wave][rloc * 64 + unit * 8 + (col & 7)] = f2bf(sv[nf][rg]);
                }
            }
        }

#pragma unroll
        for (int kk2 = 0; kk2 < 2; kk2++) {
            bf16x8 a[2], bfr[8];
#pragma unroll
            for (int mf = 0; mf < 2; mf++) {
                int row = mf * 16 + lr;
                int c16 = (kk2 * 4 + lg) ^ (row & 7);
                a[mf] = *(const bf16x8*)(&Ps[wave][row * 64 + c16 * 8]);
            }
#pragma unroll
            for (int nd = 0; nd < 8; nd++) {
                int row = nd * 16 + lr;
                int c16 = ((kk2 * 4 + lg) ^ (row & 7)) & 7;
                bfr[nd] = *(const bf16x8*)(Vs + row * 64 + c16 * 8);
            }
#pragma unroll
            for (int mf = 0; mf < 2; mf++)
#pragma unroll
                for (int nd = 0; nd < 8; nd++)
                    acc_o[mf][nd] = __builtin_amdgcn_mfma_f32_16x16x32_bf16(a[mf], bfr[nd], acc_o[mf][nd], 0, 0, 0);
        }
    }

    float* Opb = Op + (((size_t)b * 4 + ch) * Tt) * 128;
    float* mlb = ml + (((size_t)b * 4 + ch) * Tt) * 2;
#pragma unroll
    for (int mf = 0; mf < 2; mf++)
#pragma unroll
        for (int rg = 0; rg < 4; rg++) {
            int rowl = q0 + wave * 32 + mf * 16 + lg * 4 + rg;
#pragma unroll
            for (int nd = 0; nd < 8; nd++)
                Opb[(size_t)rowl * 128 + nd * 16 + lr] = acc_o[mf][nd][rg];
            if (lr == 0) {
                mlb[rowl * 2] = rm[mf][rg];
                mlb[rowl * 2 + 1] = rl[mf][rg];
            }
        }
}

// ---------------- flash combine ----------------
__global__ __launch_bounds__(256) void flash_combine(
    const float* __restrict__ Op, const float* __restrict__ ml,
    const float* __restrict__ rw, const int* __restrict__ onmaskv,
    float* __restrict__ ob, unsigned short* __restrict__ og2) {
    int i = blockIdx.x * 256 + threadIdx.x;
    int n = i >> 7, d = i & 127;
    int rs = n & 2047, b = n >> 11;
    int nch = rs / 512 + 1;
    float ms = -1e30f;
    for (int c = 0; c < nch; c++)
        ms = fmaxf(ms, ml[(((size_t)b * 4 + c) * Tt + rs) * 2]);
    float num = 0.f, den = 0.f;
    for (int c = 0; c < nch; c++) {
        size_t rbase = ((size_t)b * 4 + c) * Tt + rs;
        float mi = ml[rbase * 2], li = ml[rbase * 2 + 1];
        float w = __expf(mi - ms);
        num += w * Op[rbase * 128 + d];
        den += w * li;
    }
    float o = num / den;
    ob[(size_t)n * 128 + d] = o;
    int m = onmaskv[n];
    if (!m) m = 1;
    int e0 = __ffs(m) - 1;
    int m2 = m & (m - 1);
    float w0 = rw[(size_t)n * 16 + e0];
    float w1 = m2 ? rw[(size_t)n * 16 + (__ffs(m2) - 1)] : 0.f;
    og2[(size_t)n * 256 + d] = f2bf(w0 * o);
    og2[(size_t)n * 256 + 128 + d] = f2bf(w1 * o);
}

// ---------------- pair-bucket output GEMM, XCD swizzle over bn tiles ----------------
__global__ __launch_bounds__(256) void gemm_pair(
    const unsigned short* __restrict__ og2,
    const unsigned short* __restrict__ woT,
    const int* __restrict__ ptok, const int4* __restrict__ tiledesc,
    const int* __restrict__ ntile_dev,
    float* __restrict__ out) {
    const int L = blockIdx.x;
    const int r = L & 7, s = L >> 3;
    const int bnidx = s & 15, tq = s >> 4;
    const int tile = tq * 8 + r;
    if (tile >= *ntile_dev) return;
    const int4 td = tiledesc[tile];
    const int ei = td.x >> 4, ej = td.x & 15;
    const int mstart = td.y, mcnt = td.z;
    const int bn = bnidx * 128;
    __shared__ alignas(16) unsigned short As[128 * 64];
    __shared__ alignas(16) unsigned short Bs[128 * 64];
    __shared__ int toks[128];
    const int tid = threadIdx.x;
    if (tid < 128) toks[tid] = ptok[mstart + min(tid, mcnt - 1)];
    const int wave = tid >> 6, lane = tid & 63;
    const int lr = lane & 15, lg = lane >> 4;
    const int wr = (wave >> 1) * 64, wc = (wave & 1) * 64;
    f32x4 acc[4][4] = {};

#pragma unroll
    for (int ck = 0; ck < 4; ck++) {
        const int ebase = (ck < 2 ? ei : ej) * 128 + (ck & 1) * 64;
        const int abase = ck * 64;
        __syncthreads();
#pragma unroll
        for (int q = 0; q < 4; q++) {
            int t = q * 256 + tid;
            int row = t >> 3;
            int kc = (t & 7) << 3;
            __builtin_amdgcn_global_load_lds(
                (const __attribute__((address_space(1))) void*)(og2 + (size_t)toks[row] * 256 + abase + kc),
                (__attribute__((address_space(3))) void*)(As + (q * 4 + wave) * 512),
                16, 0, 0);
        }
#pragma unroll
        for (int q = 0; q < 4; q++) {
            int t = q * 256 + tid;
            int row = t >> 3;
            int kc = (t & 7) << 3;
            __builtin_amdgcn_global_load_lds(
                (const __attribute__((address_space(1))) void*)(woT + (size_t)(bn + row) * 2048 + ebase + kc),
                (__attribute__((address_space(3))) void*)(Bs + (q * 4 + wave) * 512),
                16, 0, 0);
        }
        __syncthreads();
#pragma unroll
        for (int kk = 0; kk < 2; kk++) {
            bf16x8 a[4], b[4];
#pragma unroll
            for (int m = 0; m < 4; m++)
                a[m] = *(const bf16x8*)(As + (wr + m * 16 + lr) * 64 + kk * 32 + lg * 8);
#pragma unroll
            for (int n = 0; n < 4; n++)
                b[n] = *(const bf16x8*)(Bs + (wc + n * 16 + lr) * 64 + kk * 32 + lg * 8);
#pragma unroll
            for (int m = 0; m < 4; m++)
#pragma unroll
                for (int n = 0; n < 4; n++)
                    acc[m][n] = __builtin_amdgcn_mfma_f32_16x16x32_bf16(a[m], b[n], acc[m][n], 0, 0, 0);
        }
    }
#pragma unroll
    for (int m = 0; m < 4; m++)
#pragma unroll
        for (int n = 0; n < 4; n++)
#pragma unroll
            for (int rr2 = 0; rr2 < 4; rr2++) {
                int rowt = wr + m * 16 + lg * 4 + rr2;
                if (rowt < mcnt) {
                    int tok = toks[rowt];
                    out[(size_t)tok * 2048 + bn + wc + n * 16 + lr] = acc[m][n][rr2];
                }
            }
}

// ---------------- rare overflow path ----------------
__global__ __launch_bounds__(256) void overflow_kernel(
    const int* __restrict__ ocnt, const int* __restrict__ olist,
    const float* __restrict__ ob, const unsigned short* __restrict__ woT,
    const float* __restrict__ rw, float* __restrict__ out) {
    const int ne = *ocnt;
    __shared__ float osh[128];
    for (int it = blockIdx.x; it < ne; it += gridDim.x) {
        int n = olist[2 * it], e = olist[2 * it + 1];
        float wgt = rw[(size_t)n * 16 + e];
        if (threadIdx.x < 128) osh[threadIdx.x] = ob[(size_t)n * Dd + threadIdx.x];
        __syncthreads();
#pragma unroll 1
        for (int cc = 0; cc < 8; cc++) {
            int c = threadIdx.x * 8 + cc;
            float a = 0.f;
            for (int k = 0; k < 128; k++)
                a += osh[k] * bf2f(woT[(size_t)c * 2048 + e * 128 + k]);
            atomicAdd(&out[(size_t)n * 2048 + c], wgt * a);
        }
        __syncthreads();
    }
}

extern "C" void kernel_launch(void* const* d_in, const int* in_sizes, int n_in,
                              void* d_out, int out_size, void* d_ws, size_t ws_size,
                              hipStream_t stream) {
    (void)in_sizes; (void)n_in; (void)out_size; (void)ws_size;
    const float* hidden = (const float*)d_in[0];
    const float* sim = (const float*)d_in[1];
    const float* gates = (const float*)d_in[2];
    const float* qp = (const float*)d_in[3];
    const float* kp = (const float*)d_in[4];
    const float* vp = (const float*)d_in[5];
    const float* op = (const float*)d_in[6];
    const int* minex = (const int*)d_in[7];
    float* out = (float*)d_out;

    char* w = (char*)d_ws;
    size_t off = 0;
    auto alloc = [&](size_t bytes) -> char* {
        char* p = w + off;
        off = (off + bytes + 255) & ~(size_t)255;
        return p;
    };
    unsigned short* xb = (unsigned short*)alloc((size_t)Nn * Cch * 2);
    unsigned short* wqkvT = (unsigned short*)alloc((size_t)Ee * 384 * Cch * 2);
    unsigned short* woT = (unsigned short*)alloc((size_t)Cch * Ee * Dd * 2);
    float* rw = (float*)alloc((size_t)Nn * Ee * 4);
    float* sninv = (float*)alloc(256);
    float* simT = (float*)alloc((size_t)Ee * Cch * 4);
    int* cnt = (int*)alloc(256);
    int* onmaskv = (int*)alloc((size_t)Nn * 4);
    int* idx = (int*)alloc((size_t)Ee * CAP * 4);
    int* pos = (int*)alloc((size_t)Nn * 16 * 4);
    int* ptok = (int*)alloc((size_t)Nn * 4);
    int4* tiledesc = (int4*)alloc((size_t)MAXTILES * 16);
    int* ntile_dev = (int*)alloc(256);
    int* ocnt = (int*)alloc(256);
    int* olist = (int*)alloc((size_t)Nn * 14 * 2 * 4);
    char* big = alloc((size_t)Bsz * Tt * Tt * 4);
    unsigned short* qb = (unsigned short*)alloc((size_t)Nn * Dd * 2);
    unsigned short* kb = (unsigned short*)alloc((size_t)Nn * Dd * 2);
    unsigned short* vb = (unsigned short*)alloc((size_t)Nn * Dd * 2);
    unsigned short* vT = (unsigned short*)alloc((size_t)Bsz * Dd * Tt * 2);
    float* ob = (float*)alloc((size_t)Nn * Dd * 4);
    unsigned short* og2 = (unsigned short*)alloc((size_t)Nn * 256 * 2);
    float* ml = (float*)alloc((size_t)Bsz * 4 * Tt * 2 * 4);
    unsigned short* Pc = (unsigned short*)big;
    float* Op = (float*)big;

    colnorm_kernel<<<1, 256, 0, stream>>>(sim, sninv);
    simt_kernel<<<(Ee * Cch) / 256, 256, 0, stream>>>(sim, simT);
    gating5_kernel<<<Nn / 32, 1024, 0, stream>>>(hidden, simT, gates, sninv, minex, rw, xb, onmaskv);
    scan_kernel<<<Ee, 256, 0, stream>>>(onmaskv, idx, pos, cnt);
    scan_pair<<<1, 256, 0, stream>>>(onmaskv, ptok, tiledesc, ntile_dev, ocnt, olist);

    // fused q/k/v weight transpose (one launch), then o_proj transpose
    transpose_qkv<<<dim3(Dd / 32, Cch / 32, 48), 256, 0, stream>>>(qp, kp, vp, wqkvT);
    transpose_f32_bf16<<<dim3((Ee * Dd) / 32, Cch / 32, 1), 256, 0, stream>>>(
        op, woT, Ee * Dd, Cch, 0L, 0L);

    // gathered per-expert QKV projection (split-K=2, XCD swizzle, dbuf prefetch), then combine
    gemm_qkv_gather<<<NGRP * 3, 256, 0, stream>>>(xb, wqkvT, idx, cnt, Pc);
    combine_qkv<<<(Nn * 32) / 256, 256, 0, stream>>>(Pc, rw, pos, qb, kb, vb);

    // V transpose per batch
    transpose_u16<<<dim3(Dd / 32, Tt / 32, Bsz), 256, 0, stream>>>(
        vb, vT, Tt, Dd, (long)Tt * Dd, (long)Dd * Tt);

    // flash attention (split-KV) + combine
    flash_kernel<<<dim3(Tt / 128, 4, Bsz), 256, 0, stream>>>(qb, kb, vT, Op, ml);
    flash_combine<<<(Nn * 128) / 256, 256, 0, stream>>>(Op, ml, rw, onmaskv, ob, og2);

    // output projection
    gemm_pair<<<MAXTILES * 16, 256, 0, stream>>>(
        og2, woT, ptok, tiledesc, ntile_dev, out);
    overflow_kernel<<<256, 256, 0, stream>>>(ocnt, olist, ob, woT, rw, out);
}

// Round 15
// 238.816 us; speedup vs baseline: 1.8196x; 1.1831x over previous
//
#include <hip/hip_runtime.h>
#include <hip/hip_bf16.h>

#define DEV __device__ __forceinline__

typedef short bf16x8 __attribute__((ext_vector_type(8)));
typedef float f32x4 __attribute__((ext_vector_type(4)));
typedef unsigned short u16x4 __attribute__((ext_vector_type(4)));

static constexpr int Bsz = 4, Tt = 2048, Cch = 2048, Dd = 128, Ee = 16;
static constexpr int Nn = Bsz * Tt;
static constexpr int CAP = 1280;
static constexpr int MAXTILES = 320;
static constexpr int MT = CAP / 128;        // 10 m-tiles per expert
static constexpr int NGRP = MT * Ee;        // 160 groups (NSPLIT=1); each = 3 column tiles

DEV unsigned short f2bf(float v) {
    __hip_bfloat16 h = __float2bfloat16(v);
    return __builtin_bit_cast(unsigned short, h);
}
DEV float bf2f(unsigned short u) {
    unsigned int x = ((unsigned int)u) << 16;
    return __builtin_bit_cast(float, x);
}

// ---------------- sim transpose ----------------
__global__ __launch_bounds__(256) void simt_kernel(const float* __restrict__ sim,
                                                   float* __restrict__ simT) {
    int i = blockIdx.x * 256 + threadIdx.x;
    int e = i >> 11, c = i & 2047;
    simT[i] = sim[c * 16 + e];
}

// ---------------- gating: full simT in 128 KiB LDS; col-norms computed in-block ----------------
__global__ __launch_bounds__(1024) void gating6_kernel(
    const float* __restrict__ x, const float* __restrict__ simT,
    const float* __restrict__ gates, const int* __restrict__ minex,
    float* __restrict__ rw, unsigned short* __restrict__ xb,
    int* __restrict__ onmaskv) {
    __shared__ f32x4 ssim[8192];
    __shared__ float snv[16];
    const int tid = threadIdx.x;
    const f32x4* stg = (const f32x4*)simT;
#pragma unroll
    for (int i = 0; i < 8; i++) ssim[i * 1024 + tid] = stg[i * 1024 + tid];
    __syncthreads();
    const int wave = tid >> 6, lane = tid & 63;

    // wave w computes expert w's column norm from LDS
    {
        float s = 0.f;
#pragma unroll
        for (int it = 0; it < 8; it++) {
            const f32x4 v = ssim[wave * 512 + it * 64 + lane];
            s += v[0] * v[0] + v[1] * v[1] + v[2] * v[2] + v[3] * v[3];
        }
#pragma unroll
        for (int off = 32; off; off >>= 1) s += __shfl_down(s, off);
        if (lane == 0) snv[wave] = 1.f / fmaxf(sqrtf(s), 1e-12f);
    }
    __syncthreads();

#pragma unroll 1
    for (int g = 0; g < 2; g++) {
        const int n = blockIdx.x * 32 + g * 16 + wave;
        const f32x4* xr = (const f32x4*)(x + (size_t)n * Cch);
        u16x4* xbr = (u16x4*)(xb + (size_t)n * Cch);
        float ss = 0.f;
        float d[16];
#pragma unroll
        for (int e = 0; e < 16; e++) d[e] = 0.f;

#pragma unroll 2
        for (int it = 0; it < 8; it++) {
            const int i = it * 64 + lane;
            const f32x4 xv = xr[i];
            ss += xv[0] * xv[0] + xv[1] * xv[1] + xv[2] * xv[2] + xv[3] * xv[3];
            u16x4 xc = {f2bf(xv[0]), f2bf(xv[1]), f2bf(xv[2]), f2bf(xv[3])};
            xbr[i] = xc;
#pragma unroll
            for (int e = 0; e < 16; e++) {
                const f32x4 sv = ssim[e * 512 + i];
                d[e] += xv[0] * sv[0] + xv[1] * sv[1] + xv[2] * sv[2] + xv[3] * sv[3];
            }
        }
#pragma unroll
        for (int off = 32; off; off >>= 1) {
            ss += __shfl_down(ss, off);
#pragma unroll
            for (int e = 0; e < 16; e++) d[e] += __shfl_down(d[e], off);
        }
        if (lane == 0) {
            float inv = 1.f / fmaxf(sqrtf(ss), 1e-12f);
            float logit[16];
            int onmask = 0;
#pragma unroll
            for (int e = 0; e < 16; e++) {
                float sg = 1.f / (1.f + __expf(-gates[e]));
                float l = d[e] * inv * snv[e] - sg;
                logit[e] = l;
                if (l > 0.f) onmask |= (1 << e);
            }
            if (onmask == 0) {
                int k = *minex;
                int ch = 0;
                for (int kk = 0; kk < k; kk++) {
                    float bv = -1e30f;
                    int be = 0;
#pragma unroll
                    for (int e = 0; e < 16; e++)
                        if (!((ch >> e) & 1) && logit[e] > bv) { bv = logit[e]; be = e; }
                    ch |= (1 << be);
                }
                onmask = ch;
            }
            float mx = -1e30f;
#pragma unroll
            for (int e = 0; e < 16; e++)
                if ((onmask >> e) & 1) mx = fmaxf(mx, fmaxf(logit[e], 0.f));
            float pe[16];
            float sum = 0.f;
#pragma unroll
            for (int e = 0; e < 16; e++) {
                pe[e] = ((onmask >> e) & 1) ? __expf(fmaxf(logit[e], 0.f) - mx) : 0.f;
                sum += pe[e];
            }
            float isum = 1.f / sum;
#pragma unroll
            for (int e = 0; e < 16; e++) rw[(size_t)n * 16 + e] = pe[e] * isum;
            onmaskv[n] = onmask;
        }
    }
}

// ---------------- fused scans: blocks 0-15 = expert lists; block 16 = pair buckets ----------------
__global__ __launch_bounds__(256) void scan_fused(
    const int* __restrict__ onmaskv,
    int* __restrict__ idx, int* __restrict__ pos, int* __restrict__ cnt,
    int* __restrict__ ptok, int4* __restrict__ tiledesc, int* __restrict__ ntile_dev,
    int* __restrict__ ocnt, int* __restrict__ olist) {
    const int tid = threadIdx.x;
    const int lane = tid & 63, w = tid >> 6;
    if (blockIdx.x < 16) {
        const int e = blockIdx.x;
        const int base = tid * 32;
        int om[32];
        int c = 0;
#pragma unroll
        for (int i = 0; i < 32; i++) {
            om[i] = (onmaskv[base + i] >> e) & 1;
            c += om[i];
        }
        int sc = c;
#pragma unroll
        for (int off = 1; off < 64; off <<= 1) {
            int t = __shfl_up(sc, off);
            if (lane >= off) sc += t;
        }
        __shared__ int wsum[4];
        if (lane == 63) wsum[w] = sc;
        __syncthreads();
        int wbase = 0;
        for (int i = 0; i < w; i++) wbase += wsum[i];
        int slot = wbase + sc - c;
#pragma unroll
        for (int i = 0; i < 32; i++) {
            int n = base + i;
            int p = -1;
            if (om[i]) {
                if (slot < CAP) {
                    idx[(size_t)e * CAP + slot] = n;
                    p = slot;
                }
                slot++;
            }
            pos[(size_t)n * 16 + e] = p;
        }
        if (tid == 255) cnt[e] = slot;
        return;
    }
    // pair-bucket scan (single block)
    __shared__ int hist[256], cursor[256];
    __shared__ int wsA[4], wsB[4];
    if (tid == 0) *ocnt = 0;
    hist[tid] = 0;
    __syncthreads();
    for (int i = 0; i < 32; i++) {
        int n = tid * 32 + i;
        int m = onmaskv[n];
        if (!m) m = 1;
        int e0 = __ffs(m) - 1;
        int m2 = m & (m - 1);
        int e1 = m2 ? (__ffs(m2) - 1) : e0;
        atomicAdd(&hist[e0 * 16 + e1], 1);
        int mrest = m2 & (m2 - 1);
        while (mrest) {
            int e = __ffs(mrest) - 1;
            int s = atomicAdd(ocnt, 1);
            olist[2 * s] = n;
            olist[2 * s + 1] = e;
            mrest &= (mrest - 1);
        }
    }
    __syncthreads();
    int v = hist[tid];
    int s = v;
#pragma unroll
    for (int off = 1; off < 64; off <<= 1) {
        int t = __shfl_up(s, off);
        if (lane >= off) s += t;
    }
    if (lane == 63) wsA[w] = s;
    __syncthreads();
    int add = 0;
    for (int i = 0; i < w; i++) add += wsA[i];
    int excl = s + add - v;
    cursor[tid] = excl;
    int nt = (v + 127) >> 7;
    int s2 = nt;
#pragma unroll
    for (int off = 1; off < 64; off <<= 1) {
        int t = __shfl_up(s2, off);
        if (lane >= off) s2 += t;
    }
    if (lane == 63) wsB[w] = s2;
    __syncthreads();
    int add2 = 0;
    for (int i = 0; i < w; i++) add2 += wsB[i];
    int texcl = s2 + add2 - nt;
    for (int m = 0; m < nt; m++)
        tiledesc[texcl + m] = make_int4(tid, excl + m * 128, min(128, v - m * 128), 0);
    if (tid == 255) *ntile_dev = texcl + nt;
    __syncthreads();
    for (int i = 0; i < 32; i++) {
        int n = tid * 32 + i;
        int m = onmaskv[n];
        if (!m) m = 1;
        int e0 = __ffs(m) - 1;
        int m2 = m & (m - 1);
        int e1 = m2 ? (__ffs(m2) - 1) : e0;
        int slot = atomicAdd(&cursor[e0 * 16 + e1], 1);
        ptok[slot] = n;
    }
}

// ---------------- fused q/k/v weight transpose ----------------
__global__ __launch_bounds__(256) void transpose_qkv(
    const float* __restrict__ qp, const float* __restrict__ kp,
    const float* __restrict__ vp, unsigned short* __restrict__ wqkvT) {
    const int z = blockIdx.z;
    const int t3 = z >> 4, e = z & 15;
    const float* src = (t3 == 0 ? qp : (t3 == 1 ? kp : vp)) + (size_t)e * Cch * Dd;
    unsigned short* dst = wqkvT + (size_t)e * 384 * Cch + (size_t)t3 * Dd * Cch;
    __shared__ float tile[32][33];
    int bx = blockIdx.x * 32, by = blockIdx.y * 32;
    int tx = threadIdx.x & 31, ty = threadIdx.x >> 5;
#pragma unroll
    for (int i = 0; i < 4; i++)
        tile[ty + i * 8][tx] = src[(size_t)(by + ty + i * 8) * Dd + bx + tx];
    __syncthreads();
#pragma unroll
    for (int i = 0; i < 4; i++)
        dst[(size_t)(bx + ty + i * 8) * Cch + by + tx] = f2bf(tile[tx][ty + i * 8]);
}

__global__ __launch_bounds__(256) void transpose_f32_bf16(
    const float* __restrict__ src, unsigned short* __restrict__ dst,
    int R, int Ccol, long ss, long ds) {
    __shared__ float tile[32][33];
    src += (size_t)blockIdx.z * ss;
    dst += (size_t)blockIdx.z * ds;
    int bx = blockIdx.x * 32, by = blockIdx.y * 32;
    int tx = threadIdx.x & 31, ty = threadIdx.x >> 5;
#pragma unroll
    for (int i = 0; i < 4; i++)
        tile[ty + i * 8][tx] = src[(size_t)(by + ty + i * 8) * Ccol + bx + tx];
    __syncthreads();
#pragma unroll
    for (int i = 0; i < 4; i++)
        dst[(size_t)(bx + ty + i * 8) * R + by + tx] = f2bf(tile[tx][ty + i * 8]);
}

__global__ __launch_bounds__(256) void transpose_u16(
    const unsigned short* __restrict__ src, unsigned short* __restrict__ dst,
    int R, int Ccol, long ss, long ds) {
    __shared__ unsigned short tile[32][33];
    src += (size_t)blockIdx.z * ss;
    dst += (size_t)blockIdx.z * ds;
    int bx = blockIdx.x * 32, by = blockIdx.y * 32;
    int tx = threadIdx.x & 31, ty = threadIdx.x >> 5;
#pragma unroll
    for (int i = 0; i < 4; i++)
        tile[ty + i * 8][tx] = src[(size_t)(by + ty + i * 8) * Ccol + bx + tx];
    __syncthreads();
#pragma unroll
    for (int i = 0; i < 4; i++)
        dst[(size_t)(bx + ty + i * 8) * R + by + tx] = tile[tx][ty + i * 8];
}

// ---------------- gathered QKV projection, full-K (NSPLIT=1), XCD swizzle, dbuf ----------------
__global__ __launch_bounds__(256) void gemm_qkv_gather(
    const unsigned short* __restrict__ X, const unsigned short* __restrict__ W,
    const int* __restrict__ idx, const int* __restrict__ cnt,
    unsigned short* __restrict__ P) {
    const int L = blockIdx.x;
    const int r = L & 7, s = L >> 3;
    const int gq = s / 3, j = s - gq * 3;
    const int g = gq * 8 + r;
    const int m = g % MT;
    const int e = g / MT;
    const int cn = min(cnt[e], CAP);
    const int bm = m * 128;
    if (bm >= cn) return;
    const int bn = j * 128;
    __shared__ alignas(16) unsigned short As[2 * 128 * 64];
    __shared__ alignas(16) unsigned short Bs[2 * 128 * 64];
    __shared__ int toks[128];
    const int tid = threadIdx.x;
    if (tid < 128) toks[tid] = idx[(size_t)e * CAP + min(bm + tid, cn - 1)];
    const unsigned short* Wb = W + ((size_t)e * 384 + bn) * Cch;
    const int wave = tid >> 6, lane = tid & 63;
    const int lr = lane & 15, lg = lane >> 4;
    const int wr = (wave >> 1) * 64, wc = (wave & 1) * 64;
    f32x4 acc[4][4] = {};

    auto stage = [&](int buf, int k0) {
#pragma unroll
        for (int i = 0; i < 4; i++) {
            int t = i * 256 + tid;
            int row = t >> 3;
            int kc = (t & 7) << 3;
            __builtin_amdgcn_global_load_lds(
                (const __attribute__((address_space(1))) void*)(X + (size_t)toks[row] * Cch + k0 + kc),
                (__attribute__((address_space(3))) void*)(As + buf * 8192 + (i * 4 + wave) * 512),
                16, 0, 0);
        }
#pragma unroll
        for (int i = 0; i < 4; i++) {
            int t = i * 256 + tid;
            int row = t >> 3;
            int kc = (t & 7) << 3;
            __builtin_amdgcn_global_load_lds(
                (const __attribute__((address_space(1))) void*)(Wb + (size_t)row * Cch + k0 + kc),
                (__attribute__((address_space(3))) void*)(Bs + buf * 8192 + (i * 4 + wave) * 512),
                16, 0, 0);
        }
    };

    __syncthreads();
    stage(0, 0);
    __syncthreads();
    int cur = 0;
#pragma unroll 1
    for (int t = 0; t < 32; t++) {
        if (t + 1 < 32) stage(cur ^ 1, (t + 1) * 64);
        const unsigned short* Ab = As + cur * 8192;
        const unsigned short* Bb = Bs + cur * 8192;
#pragma unroll
        for (int kk = 0; kk < 2; kk++) {
            bf16x8 a[4], b[4];
#pragma unroll
            for (int m2 = 0; m2 < 4; m2++)
                a[m2] = *(const bf16x8*)(Ab + (wr + m2 * 16 + lr) * 64 + kk * 32 + lg * 8);
#pragma unroll
            for (int n = 0; n < 4; n++)
                b[n] = *(const bf16x8*)(Bb + (wc + n * 16 + lr) * 64 + kk * 32 + lg * 8);
#pragma unroll
            for (int m2 = 0; m2 < 4; m2++)
#pragma unroll
                for (int n = 0; n < 4; n++)
                    acc[m2][n] = __builtin_amdgcn_mfma_f32_16x16x32_bf16(a[m2], b[n], acc[m2][n], 0, 0, 0);
        }
        __syncthreads();
        cur ^= 1;
    }
#pragma unroll
    for (int m2 = 0; m2 < 4; m2++)
#pragma unroll
        for (int n = 0; n < 4; n++)
#pragma unroll
            for (int rr = 0; rr < 4; rr++) {
                int slot = bm + wr + m2 * 16 + lg * 4 + rr;
                int col = bn + wc + n * 16 + lr;
                if (slot < cn)
                    P[((size_t)e * CAP + slot) * 384 + col] = f2bf(acc[m2][n][rr]);
            }
}

// ---------------- combine q/k/v (single partial) ----------------
__global__ __launch_bounds__(256) void combine_qkv(
    const unsigned short* __restrict__ P, const float* __restrict__ rw,
    const int* __restrict__ pos,
    unsigned short* __restrict__ qb, unsigned short* __restrict__ kb,
    unsigned short* __restrict__ vb) {
    int i = blockIdx.x * 256 + threadIdx.x;
    int n = i >> 5;
    int d4 = (i & 31) << 2;
    float aq[4] = {}, ak[4] = {}, av[4] = {};
#pragma unroll
    for (int e = 0; e < 16; e++) {
        int p = pos[(size_t)n * 16 + e];
        if (p >= 0) {
            float w = rw[(size_t)n * 16 + e];
            const unsigned short* rh = P + ((size_t)e * CAP + p) * 384 + d4;
            const u16x4 q4 = *(const u16x4*)(rh);
            const u16x4 k4 = *(const u16x4*)(rh + 128);
            const u16x4 v4 = *(const u16x4*)(rh + 256);
#pragma unroll
            for (int jj = 0; jj < 4; jj++) {
                aq[jj] += w * bf2f(q4[jj]);
                ak[jj] += w * bf2f(k4[jj]);
                av[jj] += w * bf2f(v4[jj]);
            }
        }
    }
    u16x4 sq = {f2bf(aq[0]), f2bf(aq[1]), f2bf(aq[2]), f2bf(aq[3])};
    u16x4 sk = {f2bf(ak[0]), f2bf(ak[1]), f2bf(ak[2]), f2bf(ak[3])};
    u16x4 sv = {f2bf(av[0]), f2bf(av[1]), f2bf(av[2]), f2bf(av[3])};
    *(u16x4*)(qb + (size_t)n * Dd + d4) = sq;
    *(u16x4*)(kb + (size_t)n * Dd + d4) = sk;
    *(u16x4*)(vb + (size_t)n * Dd + d4) = sv;
}

// ---------------- flash attention, split-KV ----------------
__global__ __launch_bounds__(256) void flash_kernel(
    const unsigned short* __restrict__ qb, const unsigned short* __restrict__ kb,
    const unsigned short* __restrict__ vT,
    float* __restrict__ Op, float* __restrict__ ml) {
    const int qt = blockIdx.x, ch = blockIdx.y, b = blockIdx.z;
    const int q0 = qt * 128, kv0 = ch * 512;
    if (kv0 > q0 + 127) return;
    __shared__ alignas(16) unsigned short Qs[128 * 128];
    __shared__ alignas(16) unsigned short Ks[64 * 128];
    __shared__ alignas(16) unsigned short Vs[128 * 64];
    __shared__ alignas(16) unsigned short Ps[4][32 * 64];
    const int tid = threadIdx.x;
    const int wave = tid >> 6, lane = tid & 63;
    const int lr = lane & 15, lg = lane >> 4;
    const float scale = 0.08838834764831845f;
    const unsigned short* Qg = qb + ((size_t)b * Tt + q0) * 128;
    const unsigned short* Kg = kb + (size_t)b * Tt * 128;
    const unsigned short* Vg = vT + (size_t)b * 128 * Tt;

#pragma unroll
    for (int i = 0; i < 8; i++) {
        int dof = (i * 256 + tid) << 4;
        int row = dof >> 8;
        int c16 = (dof >> 4) & 15;
        int s16 = c16 ^ (row & 7);
        __builtin_amdgcn_global_load_lds(
            (const __attribute__((address_space(1))) void*)(Qg + (size_t)row * 128 + s16 * 8),
            (__attribute__((address_space(3))) void*)(Qs + (size_t)(i * 4 + wave) * 512),
            16, 0, 0);
    }

    f32x4 acc_o[2][8] = {};
    float rm[2][4], rl[2][4];
#pragma unroll
    for (int mf = 0; mf < 2; mf++)
#pragma unroll
        for (int rg = 0; rg < 4; rg++) { rm[mf][rg] = -1e30f; rl[mf][rg] = 0.f; }

    const int ktend = min(kv0 + 512, q0 + 128);
    for (int kt = kv0; kt < ktend; kt += 64) {
        if (kt > kv0) __syncthreads();
#pragma unroll
        for (int i = 0; i < 4; i++) {
            int dof = (i * 256 + tid) << 4;
            int row = dof >> 8;
            int c16 = (dof >> 4) & 15;
            int s16 = c16 ^ (row & 7);
            __builtin_amdgcn_global_load_lds(
                (const __attribute__((address_space(1))) void*)(Kg + (size_t)(kt + row) * 128 + s16 * 8),
                (__attribute__((address_space(3))) void*)(Ks + (size_t)(i * 4 + wave) * 512),
                16, 0, 0);
        }
#pragma unroll
        for (int i = 0; i < 4; i++) {
            int dof = (i * 256 + tid) << 4;
            int row = dof >> 7;
            int c16 = (dof >> 4) & 7;
            int s16 = c16 ^ (row & 7);
            __builtin_amdgcn_global_load_lds(
                (const __attribute__((address_space(1))) void*)(Vg + (size_t)row * Tt + kt + s16 * 8),
                (__attribute__((address_space(3))) void*)(Vs + (size_t)(i * 4 + wave) * 512),
                16, 0, 0);
        }
        __syncthreads();

        f32x4 acc_s[2][4] = {};
#pragma unroll
        for (int kk = 0; kk < 4; kk++) {
            bf16x8 a[2], bfr[4];
#pragma unroll
            for (int mf = 0; mf < 2; mf++) {
                int row = wave * 32 + mf * 16 + lr;
                int c16 = (kk * 4 + lg) ^ (row & 7);
                a[mf] = *(const bf16x8*)(Qs + row * 128 + c16 * 8);
            }
#pragma unroll
            for (int nf = 0; nf < 4; nf++) {
                int row = nf * 16 + lr;
                int c16 = (kk * 4 + lg) ^ (row & 7);
                bfr[nf] = *(const bf16x8*)(Ks + row * 128 + c16 * 8);
            }
#pragma unroll
            for (int mf = 0; mf < 2; mf++)
#pragma unroll
                for (int nf = 0; nf < 4; nf++)
                    acc_s[mf][nf] = __builtin_amdgcn_mfma_f32_16x16x32_bf16(a[mf], bfr[nf], acc_s[mf][nf], 0, 0, 0);
        }

#pragma unroll
        for (int mf = 0; mf < 2; mf++) {
            float sv[4][4], pmax[4];
#pragma unroll
            for (int rg = 0; rg < 4; rg++) pmax[rg] = -1e30f;
#pragma unroll
            for (int nf = 0; nf < 4; nf++) {
                int colg = kt + nf * 16 + lr;
#pragma unroll
                for (int rg = 0; rg < 4; rg++) {
                    int rowg = q0 + wave * 32 + mf * 16 + lg * 4 + rg;
                    float s = acc_s[mf][nf][rg] * scale;
                    if (colg > rowg) s = -1e30f;
                    sv[nf][rg] = s;
                    pmax[rg] = fmaxf(pmax[rg], s);
                }
            }
#pragma unroll
            for (int rg = 0; rg < 4; rg++) {
#pragma unroll
                for (int off = 1; off < 16; off <<= 1)
                    pmax[rg] = fmaxf(pmax[rg], __shfl_xor(pmax[rg], off));
                float mnew = fmaxf(rm[mf][rg], pmax[rg]);
                float f = __expf(rm[mf][rg] - mnew);
                rm[mf][rg] = mnew;
#pragma unroll
                for (int nd = 0; nd < 8; nd++) acc_o[mf][nd][rg] *= f;
                float rsum = 0.f;
#pragma unroll
                for (int nf = 0; nf < 4; nf++) {
                    float p = __expf(sv[nf][rg] - mnew);
                    sv[nf][rg] = p;
                    rsum += p;
                }
#pragma unroll
                for (int off = 1; off < 16; off <<= 1) rsum += __shfl_xor(rsum, off);
                rl[mf][rg] = rl[mf][rg] * f + rsum;
                int rloc = mf * 16 + lg * 4 + rg;
#pragma unroll
                for (int nf = 0; nf < 4; nf++) {
                    int col = nf * 16 + lr;
                    int unit = (col >> 3) ^ (rloc & 7);
                    Ps[wave][rloc * 64 + unit * 8 + (col & 7)] = f2bf(sv[nf][rg]);
                }
            }
        }

#pragma unroll
        for (int kk2 = 0; kk2 < 2; kk2++) {
            bf16x8 a[2], bfr[8];
#pragma unroll
            for (int mf = 0; mf < 2; mf++) {
                int row = mf * 16 + lr;
                int c16 = (kk2 * 4 + lg) ^ (row & 7);
                a[mf] = *(const bf16x8*)(&Ps[wave][row * 64 + c16 * 8]);
            }
#pragma unroll
            for (int nd = 0; nd < 8; nd++) {
                int row = nd * 16 + lr;
                int c16 = ((kk2 * 4 + lg) ^ (row & 7)) & 7;
                bfr[nd] = *(const bf16x8*)(Vs + row * 64 + c16 * 8);
            }
#pragma unroll
            for (int mf = 0; mf < 2; mf++)
#pragma unroll
                for (int nd = 0; nd < 8; nd++)
                    acc_o[mf][nd] = __builtin_amdgcn_mfma_f32_16x16x32_bf16(a[mf], bfr[nd], acc_o[mf][nd], 0, 0, 0);
        }
    }

    float* Opb = Op + (((size_t)b * 4 + ch) * Tt) * 128;
    float* mlb = ml + (((size_t)b * 4 + ch) * Tt) * 2;
#pragma unroll
    for (int mf = 0; mf < 2; mf++)
#pragma unroll
        for (int rg = 0; rg < 4; rg++) {
            int rowl = q0 + wave * 32 + mf * 16 + lg * 4 + rg;
#pragma unroll
            for (int nd = 0; nd < 8; nd++)
                Opb[(size_t)rowl * 128 + nd * 16 + lr] = acc_o[mf][nd][rg];
            if (lr == 0) {
                mlb[rowl * 2] = rm[mf][rg];
                mlb[rowl * 2 + 1] = rl[mf][rg];
            }
        }
}

// ---------------- flash combine ----------------
__global__ __launch_bounds__(256) void flash_combine(
    const float* __restrict__ Op, const float* __restrict__ ml,
    const float* __restrict__ rw, const int* __restrict__ onmaskv,
    float* __restrict__ ob, unsigned short* __restrict__ og2) {
    int i = blockIdx.x * 256 + threadIdx.x;
    int n = i >> 7, d = i & 127;
    int rs = n & 2047, b = n >> 11;
    int nch = rs / 512 + 1;
    float ms = -1e30f;
    for (int c = 0; c < nch; c++)
        ms = fmaxf(ms, ml[(((size_t)b * 4 + c) * Tt + rs) * 2]);
    float num = 0.f, den = 0.f;
    for (int c = 0; c < nch; c++) {
        size_t rbase = ((size_t)b * 4 + c) * Tt + rs;
        float mi = ml[rbase * 2], li = ml[rbase * 2 + 1];
        float w = __expf(mi - ms);
        num += w * Op[rbase * 128 + d];
        den += w * li;
    }
    float o = num / den;
    ob[(size_t)n * 128 + d] = o;
    int m = onmaskv[n];
    if (!m) m = 1;
    int e0 = __ffs(m) - 1;
    int m2 = m & (m - 1);
    float w0 = rw[(size_t)n * 16 + e0];
    float w1 = m2 ? rw[(size_t)n * 16 + (__ffs(m2) - 1)] : 0.f;
    og2[(size_t)n * 256 + d] = f2bf(w0 * o);
    og2[(size_t)n * 256 + 128 + d] = f2bf(w1 * o);
}

// ---------------- pair-bucket output GEMM, XCD swizzle over bn tiles ----------------
__global__ __launch_bounds__(256) void gemm_pair(
    const unsigned short* __restrict__ og2,
    const unsigned short* __restrict__ woT,
    const int* __restrict__ ptok, const int4* __restrict__ tiledesc,
    const int* __restrict__ ntile_dev,
    float* __restrict__ out) {
    const int L = blockIdx.x;
    const int r = L & 7, s = L >> 3;
    const int bnidx = s & 15, tq = s >> 4;
    const int tile = tq * 8 + r;
    if (tile >= *ntile_dev) return;
    const int4 td = tiledesc[tile];
    const int ei = td.x >> 4, ej = td.x & 15;
    const int mstart = td.y, mcnt = td.z;
    const int bn = bnidx * 128;
    __shared__ alignas(16) unsigned short As[128 * 64];
    __shared__ alignas(16) unsigned short Bs[128 * 64];
    __shared__ int toks[128];
    const int tid = threadIdx.x;
    if (tid < 128) toks[tid] = ptok[mstart + min(tid, mcnt - 1)];
    const int wave = tid >> 6, lane = tid & 63;
    const int lr = lane & 15, lg = lane >> 4;
    const int wr = (wave >> 1) * 64, wc = (wave & 1) * 64;
    f32x4 acc[4][4] = {};

#pragma unroll
    for (int ck = 0; ck < 4; ck++) {
        const int ebase = (ck < 2 ? ei : ej) * 128 + (ck & 1) * 64;
        const int abase = ck * 64;
        __syncthreads();
#pragma unroll
        for (int q = 0; q < 4; q++) {
            int t = q * 256 + tid;
            int row = t >> 3;
            int kc = (t & 7) << 3;
            __builtin_amdgcn_global_load_lds(
                (const __attribute__((address_space(1))) void*)(og2 + (size_t)toks[row] * 256 + abase + kc),
                (__attribute__((address_space(3))) void*)(As + (q * 4 + wave) * 512),
                16, 0, 0);
        }
#pragma unroll
        for (int q = 0; q < 4; q++) {
            int t = q * 256 + tid;
            int row = t >> 3;
            int kc = (t & 7) << 3;
            __builtin_amdgcn_global_load_lds(
                (const __attribute__((address_space(1))) void*)(woT + (size_t)(bn + row) * 2048 + ebase + kc),
                (__attribute__((address_space(3))) void*)(Bs + (q * 4 + wave) * 512),
                16, 0, 0);
        }
        __syncthreads();
#pragma unroll
        for (int kk = 0; kk < 2; kk++) {
            bf16x8 a[4], b[4];
#pragma unroll
            for (int m = 0; m < 4; m++)
                a[m] = *(const bf16x8*)(As + (wr + m * 16 + lr) * 64 + kk * 32 + lg * 8);
#pragma unroll
            for (int n = 0; n < 4; n++)
                b[n] = *(const bf16x8*)(Bs + (wc + n * 16 + lr) * 64 + kk * 32 + lg * 8);
#pragma unroll
            for (int m = 0; m < 4; m++)
#pragma unroll
                for (int n = 0; n < 4; n++)
                    acc[m][n] = __builtin_amdgcn_mfma_f32_16x16x32_bf16(a[m], b[n], acc[m][n], 0, 0, 0);
        }
    }
#pragma unroll
    for (int m = 0; m < 4; m++)
#pragma unroll
        for (int n = 0; n < 4; n++)
#pragma unroll
            for (int rr2 = 0; rr2 < 4; rr2++) {
                int rowt = wr + m * 16 + lg * 4 + rr2;
                if (rowt < mcnt) {
                    int tok = toks[rowt];
                    out[(size_t)tok * 2048 + bn + wc + n * 16 + lr] = acc[m][n][rr2];
                }
            }
}

// ---------------- rare overflow path ----------------
__global__ __launch_bounds__(256) void overflow_kernel(
    const int* __restrict__ ocnt, const int* __restrict__ olist,
    const float* __restrict__ ob, const unsigned short* __restrict__ woT,
    const float* __restrict__ rw, float* __restrict__ out) {
    const int ne = *ocnt;
    __shared__ float osh[128];
    for (int it = blockIdx.x; it < ne; it += gridDim.x) {
        int n = olist[2 * it], e = olist[2 * it + 1];
        float wgt = rw[(size_t)n * 16 + e];
        if (threadIdx.x < 128) osh[threadIdx.x] = ob[(size_t)n * Dd + threadIdx.x];
        __syncthreads();
#pragma unroll 1
        for (int cc = 0; cc < 8; cc++) {
            int c = threadIdx.x * 8 + cc;
            float a = 0.f;
            for (int k = 0; k < 128; k++)
                a += osh[k] * bf2f(woT[(size_t)c * 2048 + e * 128 + k]);
            atomicAdd(&out[(size_t)n * 2048 + c], wgt * a);
        }
        __syncthreads();
    }
}

extern "C" void kernel_launch(void* const* d_in, const int* in_sizes, int n_in,
                              void* d_out, int out_size, void* d_ws, size_t ws_size,
                              hipStream_t stream) {
    (void)in_sizes; (void)n_in; (void)out_size; (void)ws_size;
    const float* hidden = (const float*)d_in[0];
    const float* sim = (const float*)d_in[1];
    const float* gates = (const float*)d_in[2];
    const float* qp = (const float*)d_in[3];
    const float* kp = (const float*)d_in[4];
    const float* vp = (const float*)d_in[5];
    const float* op = (const float*)d_in[6];
    const int* minex = (const int*)d_in[7];
    float* out = (float*)d_out;

    char* w = (char*)d_ws;
    size_t off = 0;
    auto alloc = [&](size_t bytes) -> char* {
        char* p = w + off;
        off = (off + bytes + 255) & ~(size_t)255;
        return p;
    };
    unsigned short* xb = (unsigned short*)alloc((size_t)Nn * Cch * 2);
    unsigned short* wqkvT = (unsigned short*)alloc((size_t)Ee * 384 * Cch * 2);
    unsigned short* woT = (unsigned short*)alloc((size_t)Cch * Ee * Dd * 2);
    float* rw = (float*)alloc((size_t)Nn * Ee * 4);
    float* simT = (float*)alloc((size_t)Ee * Cch * 4);
    int* cnt = (int*)alloc(256);
    int* onmaskv = (int*)alloc((size_t)Nn * 4);
    int* idx = (int*)alloc((size_t)Ee * CAP * 4);
    int* pos = (int*)alloc((size_t)Nn * 16 * 4);
    int* ptok = (int*)alloc((size_t)Nn * 4);
    int4* tiledesc = (int4*)alloc((size_t)MAXTILES * 16);
    int* ntile_dev = (int*)alloc(256);
    int* ocnt = (int*)alloc(256);
    int* olist = (int*)alloc((size_t)Nn * 14 * 2 * 4);
    char* big = alloc((size_t)Bsz * Tt * Tt * 4);  // Pc (15.7MB), later Op partials (16.8MB)
    unsigned short* qb = (unsigned short*)alloc((size_t)Nn * Dd * 2);
    unsigned short* kb = (unsigned short*)alloc((size_t)Nn * Dd * 2);
    unsigned short* vb = (unsigned short*)alloc((size_t)Nn * Dd * 2);
    unsigned short* vT = (unsigned short*)alloc((size_t)Bsz * Dd * Tt * 2);
    float* ob = (float*)alloc((size_t)Nn * Dd * 4);
    unsigned short* og2 = (unsigned short*)alloc((size_t)Nn * 256 * 2);
    float* ml = (float*)alloc((size_t)Bsz * 4 * Tt * 2 * 4);
    unsigned short* Pc = (unsigned short*)big;
    float* Op = (float*)big;

    simt_kernel<<<(Ee * Cch) / 256, 256, 0, stream>>>(sim, simT);
    gating6_kernel<<<Nn / 32, 1024, 0, stream>>>(hidden, simT, gates, minex, rw, xb, onmaskv);
    scan_fused<<<17, 256, 0, stream>>>(onmaskv, idx, pos, cnt, ptok, tiledesc, ntile_dev, ocnt, olist);

    // fused q/k/v weight transpose, then o_proj transpose
    transpose_qkv<<<dim3(Dd / 32, Cch / 32, 48), 256, 0, stream>>>(qp, kp, vp, wqkvT);
    transpose_f32_bf16<<<dim3((Ee * Dd) / 32, Cch / 32, 1), 256, 0, stream>>>(
        op, woT, Ee * Dd, Cch, 0L, 0L);

    // gathered per-expert QKV projection (full-K, XCD swizzle, dbuf), then combine
    gemm_qkv_gather<<<NGRP * 3, 256, 0, stream>>>(xb, wqkvT, idx, cnt, Pc);
    combine_qkv<<<(Nn * 32) / 256, 256, 0, stream>>>(Pc, rw, pos, qb, kb, vb);

    // V transpose per batch
    transpose_u16<<<dim3(Dd / 32, Tt / 32, Bsz), 256, 0, stream>>>(
        vb, vT, Tt, Dd, (long)Tt * Dd, (long)Dd * Tt);

    // flash attention (split-KV) + combine
    flash_kernel<<<dim3(Tt / 128, 4, Bsz), 256, 0, stream>>>(qb, kb, vT, Op, ml);
    flash_combine<<<(Nn * 128) / 256, 256, 0, stream>>>(Op, ml, rw, onmaskv, ob, og2);

    // output projection
    gemm_pair<<<MAXTILES * 16, 256, 0, stream>>>(
        og2, woT, ptok, tiledesc, ntile_dev, out);
    overflow_kernel<<<256, 256, 0, stream>>>(ocnt, olist, ob, woT, rw, out);
}

// Round 16
// 236.327 us; speedup vs baseline: 1.8388x; 1.0105x over previous
//
#include <hip/hip_runtime.h>
#include <hip/hip_bf16.h>

#define DEV __device__ __forceinline__

typedef short bf16x8 __attribute__((ext_vector_type(8)));
typedef float f32x4 __attribute__((ext_vector_type(4)));
typedef unsigned short u16x4 __attribute__((ext_vector_type(4)));

static constexpr int Bsz = 4, Tt = 2048, Cch = 2048, Dd = 128, Ee = 16;
static constexpr int Nn = Bsz * Tt;
static constexpr int CAP = 1280;
static constexpr int MAXTILES = 320;
static constexpr int MT = CAP / 128;        // 10 m-tiles per expert
static constexpr int NGRP = MT * Ee;        // 160 groups; grid = 480 = 8 XCD * 2 experts * 30

DEV unsigned short f2bf(float v) {
    __hip_bfloat16 h = __float2bfloat16(v);
    return __builtin_bit_cast(unsigned short, h);
}
DEV float bf2f(unsigned short u) {
    unsigned int x = ((unsigned int)u) << 16;
    return __builtin_bit_cast(float, x);
}

// ---------------- gating: simT built in-LDS from sim (fused transpose); col-norms in-block ----------------
__global__ __launch_bounds__(1024) void gating6_kernel(
    const float* __restrict__ x, const float* __restrict__ sim,
    const float* __restrict__ gates, const int* __restrict__ minex,
    float* __restrict__ rw, unsigned short* __restrict__ xb,
    int* __restrict__ onmaskv) {
    __shared__ alignas(16) float ssimf[32768];  // [e][c] layout, 128 KiB
    __shared__ float snv[16];
    const int tid = threadIdx.x;
    // coalesced read of sim [c][e]; transposing LDS write
#pragma unroll
    for (int i = 0; i < 32; i++) {
        int idx = i * 1024 + tid;
        ssimf[(idx & 15) * 2048 + (idx >> 4)] = sim[idx];
    }
    __syncthreads();
    const int wave = tid >> 6, lane = tid & 63;
    const f32x4* ssim = (const f32x4*)ssimf;

    // wave w computes expert w's column norm from LDS
    {
        float s = 0.f;
#pragma unroll
        for (int it = 0; it < 8; it++) {
            const f32x4 v = ssim[wave * 512 + it * 64 + lane];
            s += v[0] * v[0] + v[1] * v[1] + v[2] * v[2] + v[3] * v[3];
        }
#pragma unroll
        for (int off = 32; off; off >>= 1) s += __shfl_down(s, off);
        if (lane == 0) snv[wave] = 1.f / fmaxf(sqrtf(s), 1e-12f);
    }
    __syncthreads();

#pragma unroll 1
    for (int g = 0; g < 2; g++) {
        const int n = blockIdx.x * 32 + g * 16 + wave;
        const f32x4* xr = (const f32x4*)(x + (size_t)n * Cch);
        u16x4* xbr = (u16x4*)(xb + (size_t)n * Cch);
        float ss = 0.f;
        float d[16];
#pragma unroll
        for (int e = 0; e < 16; e++) d[e] = 0.f;

#pragma unroll 2
        for (int it = 0; it < 8; it++) {
            const int i = it * 64 + lane;
            const f32x4 xv = xr[i];
            ss += xv[0] * xv[0] + xv[1] * xv[1] + xv[2] * xv[2] + xv[3] * xv[3];
            u16x4 xc = {f2bf(xv[0]), f2bf(xv[1]), f2bf(xv[2]), f2bf(xv[3])};
            xbr[i] = xc;
#pragma unroll
            for (int e = 0; e < 16; e++) {
                const f32x4 sv = ssim[e * 512 + i];
                d[e] += xv[0] * sv[0] + xv[1] * sv[1] + xv[2] * sv[2] + xv[3] * sv[3];
            }
        }
#pragma unroll
        for (int off = 32; off; off >>= 1) {
            ss += __shfl_down(ss, off);
#pragma unroll
            for (int e = 0; e < 16; e++) d[e] += __shfl_down(d[e], off);
        }
        if (lane == 0) {
            float inv = 1.f / fmaxf(sqrtf(ss), 1e-12f);
            float logit[16];
            int onmask = 0;
#pragma unroll
            for (int e = 0; e < 16; e++) {
                float sg = 1.f / (1.f + __expf(-gates[e]));
                float l = d[e] * inv * snv[e] - sg;
                logit[e] = l;
                if (l > 0.f) onmask |= (1 << e);
            }
            if (onmask == 0) {
                int k = *minex;
                int ch = 0;
                for (int kk = 0; kk < k; kk++) {
                    float bv = -1e30f;
                    int be = 0;
#pragma unroll
                    for (int e = 0; e < 16; e++)
                        if (!((ch >> e) & 1) && logit[e] > bv) { bv = logit[e]; be = e; }
                    ch |= (1 << be);
                }
                onmask = ch;
            }
            float mx = -1e30f;
#pragma unroll
            for (int e = 0; e < 16; e++)
                if ((onmask >> e) & 1) mx = fmaxf(mx, fmaxf(logit[e], 0.f));
            float pe[16];
            float sum = 0.f;
#pragma unroll
            for (int e = 0; e < 16; e++) {
                pe[e] = ((onmask >> e) & 1) ? __expf(fmaxf(logit[e], 0.f) - mx) : 0.f;
                sum += pe[e];
            }
            float isum = 1.f / sum;
#pragma unroll
            for (int e = 0; e < 16; e++) rw[(size_t)n * 16 + e] = pe[e] * isum;
            onmaskv[n] = onmask;
        }
    }
}

// ---------------- fused scans: blocks 0-15 = expert lists; block 16 = pair buckets ----------------
__global__ __launch_bounds__(256) void scan_fused(
    const int* __restrict__ onmaskv,
    int* __restrict__ idx, int* __restrict__ pos, int* __restrict__ cnt,
    int* __restrict__ ptok, int4* __restrict__ tiledesc, int* __restrict__ ntile_dev,
    int* __restrict__ ocnt, int* __restrict__ olist) {
    const int tid = threadIdx.x;
    const int lane = tid & 63, w = tid >> 6;
    if (blockIdx.x < 16) {
        const int e = blockIdx.x;
        const int base = tid * 32;
        int om[32];
        int c = 0;
#pragma unroll
        for (int i = 0; i < 32; i++) {
            om[i] = (onmaskv[base + i] >> e) & 1;
            c += om[i];
        }
        int sc = c;
#pragma unroll
        for (int off = 1; off < 64; off <<= 1) {
            int t = __shfl_up(sc, off);
            if (lane >= off) sc += t;
        }
        __shared__ int wsum[4];
        if (lane == 63) wsum[w] = sc;
        __syncthreads();
        int wbase = 0;
        for (int i = 0; i < w; i++) wbase += wsum[i];
        int slot = wbase + sc - c;
#pragma unroll
        for (int i = 0; i < 32; i++) {
            int n = base + i;
            int p = -1;
            if (om[i]) {
                if (slot < CAP) {
                    idx[(size_t)e * CAP + slot] = n;
                    p = slot;
                }
                slot++;
            }
            pos[(size_t)n * 16 + e] = p;
        }
        if (tid == 255) cnt[e] = slot;
        return;
    }
    __shared__ int hist[256], cursor[256];
    __shared__ int wsA[4], wsB[4];
    if (tid == 0) *ocnt = 0;
    hist[tid] = 0;
    __syncthreads();
    for (int i = 0; i < 32; i++) {
        int n = tid * 32 + i;
        int m = onmaskv[n];
        if (!m) m = 1;
        int e0 = __ffs(m) - 1;
        int m2 = m & (m - 1);
        int e1 = m2 ? (__ffs(m2) - 1) : e0;
        atomicAdd(&hist[e0 * 16 + e1], 1);
        int mrest = m2 & (m2 - 1);
        while (mrest) {
            int e = __ffs(mrest) - 1;
            int s = atomicAdd(ocnt, 1);
            olist[2 * s] = n;
            olist[2 * s + 1] = e;
            mrest &= (mrest - 1);
        }
    }
    __syncthreads();
    int v = hist[tid];
    int s = v;
#pragma unroll
    for (int off = 1; off < 64; off <<= 1) {
        int t = __shfl_up(s, off);
        if (lane >= off) s += t;
    }
    if (lane == 63) wsA[w] = s;
    __syncthreads();
    int add = 0;
    for (int i = 0; i < w; i++) add += wsA[i];
    int excl = s + add - v;
    cursor[tid] = excl;
    int nt = (v + 127) >> 7;
    int s2 = nt;
#pragma unroll
    for (int off = 1; off < 64; off <<= 1) {
        int t = __shfl_up(s2, off);
        if (lane >= off) s2 += t;
    }
    if (lane == 63) wsB[w] = s2;
    __syncthreads();
    int add2 = 0;
    for (int i = 0; i < w; i++) add2 += wsB[i];
    int texcl = s2 + add2 - nt;
    for (int m = 0; m < nt; m++)
        tiledesc[texcl + m] = make_int4(tid, excl + m * 128, min(128, v - m * 128), 0);
    if (tid == 255) *ntile_dev = texcl + nt;
    __syncthreads();
    for (int i = 0; i < 32; i++) {
        int n = tid * 32 + i;
        int m = onmaskv[n];
        if (!m) m = 1;
        int e0 = __ffs(m) - 1;
        int m2 = m & (m - 1);
        int e1 = m2 ? (__ffs(m2) - 1) : e0;
        int slot = atomicAdd(&cursor[e0 * 16 + e1], 1);
        ptok[slot] = n;
    }
}

// ---------------- fused q/k/v weight transpose ----------------
__global__ __launch_bounds__(256) void transpose_qkv(
    const float* __restrict__ qp, const float* __restrict__ kp,
    const float* __restrict__ vp, unsigned short* __restrict__ wqkvT) {
    const int z = blockIdx.z;
    const int t3 = z >> 4, e = z & 15;
    const float* src = (t3 == 0 ? qp : (t3 == 1 ? kp : vp)) + (size_t)e * Cch * Dd;
    unsigned short* dst = wqkvT + (size_t)e * 384 * Cch + (size_t)t3 * Dd * Cch;
    __shared__ float tile[32][33];
    int bx = blockIdx.x * 32, by = blockIdx.y * 32;
    int tx = threadIdx.x & 31, ty = threadIdx.x >> 5;
#pragma unroll
    for (int i = 0; i < 4; i++)
        tile[ty + i * 8][tx] = src[(size_t)(by + ty + i * 8) * Dd + bx + tx];
    __syncthreads();
#pragma unroll
    for (int i = 0; i < 4; i++)
        dst[(size_t)(bx + ty + i * 8) * Cch + by + tx] = f2bf(tile[tx][ty + i * 8]);
}

__global__ __launch_bounds__(256) void transpose_f32_bf16(
    const float* __restrict__ src, unsigned short* __restrict__ dst,
    int R, int Ccol, long ss, long ds) {
    __shared__ float tile[32][33];
    src += (size_t)blockIdx.z * ss;
    dst += (size_t)blockIdx.z * ds;
    int bx = blockIdx.x * 32, by = blockIdx.y * 32;
    int tx = threadIdx.x & 31, ty = threadIdx.x >> 5;
#pragma unroll
    for (int i = 0; i < 4; i++)
        tile[ty + i * 8][tx] = src[(size_t)(by + ty + i * 8) * Ccol + bx + tx];
    __syncthreads();
#pragma unroll
    for (int i = 0; i < 4; i++)
        dst[(size_t)(bx + ty + i * 8) * R + by + tx] = f2bf(tile[tx][ty + i * 8]);
}

__global__ __launch_bounds__(256) void transpose_u16(
    const unsigned short* __restrict__ src, unsigned short* __restrict__ dst,
    int R, int Ccol, long ss, long ds) {
    __shared__ unsigned short tile[32][33];
    src += (size_t)blockIdx.z * ss;
    dst += (size_t)blockIdx.z * ds;
    int bx = blockIdx.x * 32, by = blockIdx.y * 32;
    int tx = threadIdx.x & 31, ty = threadIdx.x >> 5;
#pragma unroll
    for (int i = 0; i < 4; i++)
        tile[ty + i * 8][tx] = src[(size_t)(by + ty + i * 8) * Ccol + bx + tx];
    __syncthreads();
#pragma unroll
    for (int i = 0; i < 4; i++)
        dst[(size_t)(bx + ty + i * 8) * R + by + tx] = tile[tx][ty + i * 8];
}

// ---------------- gathered QKV projection, full-K, expert->XCD swizzle, dbuf ----------------
// grid 480 = 8 XCDs * 60; XCD r owns experts {2r, 2r+1} -> W[e] fetched into ONE L2.
__global__ __launch_bounds__(256) void gemm_qkv_gather(
    const unsigned short* __restrict__ X, const unsigned short* __restrict__ W,
    const int* __restrict__ idx, const int* __restrict__ cnt,
    unsigned short* __restrict__ P) {
    const int L = blockIdx.x;
    const int r = L & 7, i5 = L >> 3;       // i5 in 0..59
    const int e = r * 2 + (i5 / 30);
    const int rem = i5 % 30;
    const int m = rem % MT;
    const int j = rem / MT;
    const int cn = min(cnt[e], CAP);
    const int bm = m * 128;
    if (bm >= cn) return;
    const int bn = j * 128;
    __shared__ alignas(16) unsigned short As[2 * 128 * 64];
    __shared__ alignas(16) unsigned short Bs[2 * 128 * 64];
    __shared__ int toks[128];
    const int tid = threadIdx.x;
    if (tid < 128) toks[tid] = idx[(size_t)e * CAP + min(bm + tid, cn - 1)];
    const unsigned short* Wb = W + ((size_t)e * 384 + bn) * Cch;
    const int wave = tid >> 6, lane = tid & 63;
    const int lr = lane & 15, lg = lane >> 4;
    const int wr = (wave >> 1) * 64, wc = (wave & 1) * 64;
    f32x4 acc[4][4] = {};

    auto stage = [&](int buf, int k0) {
#pragma unroll
        for (int i = 0; i < 4; i++) {
            int t = i * 256 + tid;
            int row = t >> 3;
            int kc = (t & 7) << 3;
            __builtin_amdgcn_global_load_lds(
                (const __attribute__((address_space(1))) void*)(X + (size_t)toks[row] * Cch + k0 + kc),
                (__attribute__((address_space(3))) void*)(As + buf * 8192 + (i * 4 + wave) * 512),
                16, 0, 0);
        }
#pragma unroll
        for (int i = 0; i < 4; i++) {
            int t = i * 256 + tid;
            int row = t >> 3;
            int kc = (t & 7) << 3;
            __builtin_amdgcn_global_load_lds(
                (const __attribute__((address_space(1))) void*)(Wb + (size_t)row * Cch + k0 + kc),
                (__attribute__((address_space(3))) void*)(Bs + buf * 8192 + (i * 4 + wave) * 512),
                16, 0, 0);
        }
    };

    __syncthreads();
    stage(0, 0);
    __syncthreads();
    int cur = 0;
#pragma unroll 1
    for (int t = 0; t < 32; t++) {
        if (t + 1 < 32) stage(cur ^ 1, (t + 1) * 64);
        const unsigned short* Ab = As + cur * 8192;
        const unsigned short* Bb = Bs + cur * 8192;
#pragma unroll
        for (int kk = 0; kk < 2; kk++) {
            bf16x8 a[4], b[4];
#pragma unroll
            for (int m2 = 0; m2 < 4; m2++)
                a[m2] = *(const bf16x8*)(Ab + (wr + m2 * 16 + lr) * 64 + kk * 32 + lg * 8);
#pragma unroll
            for (int n = 0; n < 4; n++)
                b[n] = *(const bf16x8*)(Bb + (wc + n * 16 + lr) * 64 + kk * 32 + lg * 8);
#pragma unroll
            for (int m2 = 0; m2 < 4; m2++)
#pragma unroll
                for (int n = 0; n < 4; n++)
                    acc[m2][n] = __builtin_amdgcn_mfma_f32_16x16x32_bf16(a[m2], b[n], acc[m2][n], 0, 0, 0);
        }
        __syncthreads();
        cur ^= 1;
    }
#pragma unroll
    for (int m2 = 0; m2 < 4; m2++)
#pragma unroll
        for (int n = 0; n < 4; n++)
#pragma unroll
            for (int rr = 0; rr < 4; rr++) {
                int slot = bm + wr + m2 * 16 + lg * 4 + rr;
                int col = bn + wc + n * 16 + lr;
                if (slot < cn)
                    P[((size_t)e * CAP + slot) * 384 + col] = f2bf(acc[m2][n][rr]);
            }
}

// ---------------- combine q/k/v ----------------
__global__ __launch_bounds__(256) void combine_qkv(
    const unsigned short* __restrict__ P, const float* __restrict__ rw,
    const int* __restrict__ pos,
    unsigned short* __restrict__ qb, unsigned short* __restrict__ kb,
    unsigned short* __restrict__ vb) {
    int i = blockIdx.x * 256 + threadIdx.x;
    int n = i >> 5;
    int d4 = (i & 31) << 2;
    float aq[4] = {}, ak[4] = {}, av[4] = {};
#pragma unroll
    for (int e = 0; e < 16; e++) {
        int p = pos[(size_t)n * 16 + e];
        if (p >= 0) {
            float w = rw[(size_t)n * 16 + e];
            const unsigned short* rh = P + ((size_t)e * CAP + p) * 384 + d4;
            const u16x4 q4 = *(const u16x4*)(rh);
            const u16x4 k4 = *(const u16x4*)(rh + 128);
            const u16x4 v4 = *(const u16x4*)(rh + 256);
#pragma unroll
            for (int jj = 0; jj < 4; jj++) {
                aq[jj] += w * bf2f(q4[jj]);
                ak[jj] += w * bf2f(k4[jj]);
                av[jj] += w * bf2f(v4[jj]);
            }
        }
    }
    u16x4 sq = {f2bf(aq[0]), f2bf(aq[1]), f2bf(aq[2]), f2bf(aq[3])};
    u16x4 sk = {f2bf(ak[0]), f2bf(ak[1]), f2bf(ak[2]), f2bf(ak[3])};
    u16x4 sv = {f2bf(av[0]), f2bf(av[1]), f2bf(av[2]), f2bf(av[3])};
    *(u16x4*)(qb + (size_t)n * Dd + d4) = sq;
    *(u16x4*)(kb + (size_t)n * Dd + d4) = sk;
    *(u16x4*)(vb + (size_t)n * Dd + d4) = sv;
}

// ---------------- flash attention, split-KV ----------------
__global__ __launch_bounds__(256) void flash_kernel(
    const unsigned short* __restrict__ qb, const unsigned short* __restrict__ kb,
    const unsigned short* __restrict__ vT,
    float* __restrict__ Op, float* __restrict__ ml) {
    const int qt = blockIdx.x, ch = blockIdx.y, b = blockIdx.z;
    const int q0 = qt * 128, kv0 = ch * 512;
    if (kv0 > q0 + 127) return;
    __shared__ alignas(16) unsigned short Qs[128 * 128];
    __shared__ alignas(16) unsigned short Ks[64 * 128];
    __shared__ alignas(16) unsigned short Vs[128 * 64];
    __shared__ alignas(16) unsigned short Ps[4][32 * 64];
    const int tid = threadIdx.x;
    const int wave = tid >> 6, lane = tid & 63;
    const int lr = lane & 15, lg = lane >> 4;
    const float scale = 0.08838834764831845f;
    const unsigned short* Qg = qb + ((size_t)b * Tt + q0) * 128;
    const unsigned short* Kg = kb + (size_t)b * Tt * 128;
    const unsigned short* Vg = vT + (size_t)b * 128 * Tt;

#pragma unroll
    for (int i = 0; i < 8; i++) {
        int dof = (i * 256 + tid) << 4;
        int row = dof >> 8;
        int c16 = (dof >> 4) & 15;
        int s16 = c16 ^ (row & 7);
        __builtin_amdgcn_global_load_lds(
            (const __attribute__((address_space(1))) void*)(Qg + (size_t)row * 128 + s16 * 8),
            (__attribute__((address_space(3))) void*)(Qs + (size_t)(i * 4 + wave) * 512),
            16, 0, 0);
    }

    f32x4 acc_o[2][8] = {};
    float rm[2][4], rl[2][4];
#pragma unroll
    for (int mf = 0; mf < 2; mf++)
#pragma unroll
        for (int rg = 0; rg < 4; rg++) { rm[mf][rg] = -1e30f; rl[mf][rg] = 0.f; }

    const int ktend = min(kv0 + 512, q0 + 128);
    for (int kt = kv0; kt < ktend; kt += 64) {
        if (kt > kv0) __syncthreads();
#pragma unroll
        for (int i = 0; i < 4; i++) {
            int dof = (i * 256 + tid) << 4;
            int row = dof >> 8;
            int c16 = (dof >> 4) & 15;
            int s16 = c16 ^ (row & 7);
            __builtin_amdgcn_global_load_lds(
                (const __attribute__((address_space(1))) void*)(Kg + (size_t)(kt + row) * 128 + s16 * 8),
                (__attribute__((address_space(3))) void*)(Ks + (size_t)(i * 4 + wave) * 512),
                16, 0, 0);
        }
#pragma unroll
        for (int i = 0; i < 4; i++) {
            int dof = (i * 256 + tid) << 4;
            int row = dof >> 7;
            int c16 = (dof >> 4) & 7;
            int s16 = c16 ^ (row & 7);
            __builtin_amdgcn_global_load_lds(
                (const __attribute__((address_space(1))) void*)(Vg + (size_t)row * Tt + kt + s16 * 8),
                (__attribute__((address_space(3))) void*)(Vs + (size_t)(i * 4 + wave) * 512),
                16, 0, 0);
        }
        __syncthreads();

        f32x4 acc_s[2][4] = {};
#pragma unroll
        for (int kk = 0; kk < 4; kk++) {
            bf16x8 a[2], bfr[4];
#pragma unroll
            for (int mf = 0; mf < 2; mf++) {
                int row = wave * 32 + mf * 16 + lr;
                int c16 = (kk * 4 + lg) ^ (row & 7);
                a[mf] = *(const bf16x8*)(Qs + row * 128 + c16 * 8);
            }
#pragma unroll
            for (int nf = 0; nf < 4; nf++) {
                int row = nf * 16 + lr;
                int c16 = (kk * 4 + lg) ^ (row & 7);
                bfr[nf] = *(const bf16x8*)(Ks + row * 128 + c16 * 8);
            }
#pragma unroll
            for (int mf = 0; mf < 2; mf++)
#pragma unroll
                for (int nf = 0; nf < 4; nf++)
                    acc_s[mf][nf] = __builtin_amdgcn_mfma_f32_16x16x32_bf16(a[mf], bfr[nf], acc_s[mf][nf], 0, 0, 0);
        }

#pragma unroll
        for (int mf = 0; mf < 2; mf++) {
            float sv[4][4], pmax[4];
#pragma unroll
            for (int rg = 0; rg < 4; rg++) pmax[rg] = -1e30f;
#pragma unroll
            for (int nf = 0; nf < 4; nf++) {
                int colg = kt + nf * 16 + lr;
#pragma unroll
                for (int rg = 0; rg < 4; rg++) {
                    int rowg = q0 + wave * 32 + mf * 16 + lg * 4 + rg;
                    float s = acc_s[mf][nf][rg] * scale;
                    if (colg > rowg) s = -1e30f;
                    sv[nf][rg] = s;
                    pmax[rg] = fmaxf(pmax[rg], s);
                }
            }
#pragma unroll
            for (int rg = 0; rg < 4; rg++) {
#pragma unroll
                for (int off = 1; off < 16; off <<= 1)
                    pmax[rg] = fmaxf(pmax[rg], __shfl_xor(pmax[rg], off));
                float mnew = fmaxf(rm[mf][rg], pmax[rg]);
                float f = __expf(rm[mf][rg] - mnew);
                rm[mf][rg] = mnew;
#pragma unroll
                for (int nd = 0; nd < 8; nd++) acc_o[mf][nd][rg] *= f;
                float rsum = 0.f;
#pragma unroll
                for (int nf = 0; nf < 4; nf++) {
                    float p = __expf(sv[nf][rg] - mnew);
                    sv[nf][rg] = p;
                    rsum += p;
                }
#pragma unroll
                for (int off = 1; off < 16; off <<= 1) rsum += __shfl_xor(rsum, off);
                rl[mf][rg] = rl[mf][rg] * f + rsum;
                int rloc = mf * 16 + lg * 4 + rg;
#pragma unroll
                for (int nf = 0; nf < 4; nf++) {
                    int col = nf * 16 + lr;
                    int unit = (col >> 3) ^ (rloc & 7);
                    Ps[wave][rloc * 64 + unit * 8 + (col & 7)] = f2bf(sv[nf][rg]);
                }
            }
        }

#pragma unroll
        for (int kk2 = 0; kk2 < 2; kk2++) {
            bf16x8 a[2], bfr[8];
#pragma unroll
            for (int mf = 0; mf < 2; mf++) {
                int row = mf * 16 + lr;
                int c16 = (kk2 * 4 + lg) ^ (row & 7);
                a[mf] = *(const bf16x8*)(&Ps[wave][row * 64 + c16 * 8]);
            }
#pragma unroll
            for (int nd = 0; nd < 8; nd++) {
                int row = nd * 16 + lr;
                int c16 = ((kk2 * 4 + lg) ^ (row & 7)) & 7;
                bfr[nd] = *(const bf16x8*)(Vs + row * 64 + c16 * 8);
            }
#pragma unroll
            for (int mf = 0; mf < 2; mf++)
#pragma unroll
                for (int nd = 0; nd < 8; nd++)
                    acc_o[mf][nd] = __builtin_amdgcn_mfma_f32_16x16x32_bf16(a[mf], bfr[nd], acc_o[mf][nd], 0, 0, 0);
        }
    }

    float* Opb = Op + (((size_t)b * 4 + ch) * Tt) * 128;
    float* mlb = ml + (((size_t)b * 4 + ch) * Tt) * 2;
#pragma unroll
    for (int mf = 0; mf < 2; mf++)
#pragma unroll
        for (int rg = 0; rg < 4; rg++) {
            int rowl = q0 + wave * 32 + mf * 16 + lg * 4 + rg;
#pragma unroll
            for (int nd = 0; nd < 8; nd++)
                Opb[(size_t)rowl * 128 + nd * 16 + lr] = acc_o[mf][nd][rg];
            if (lr == 0) {
                mlb[rowl * 2] = rm[mf][rg];
                mlb[rowl * 2 + 1] = rl[mf][rg];
            }
        }
}

// ---------------- flash combine ----------------
__global__ __launch_bounds__(256) void flash_combine(
    const float* __restrict__ Op, const float* __restrict__ ml,
    const float* __restrict__ rw, const int* __restrict__ onmaskv,
    float* __restrict__ ob, unsigned short* __restrict__ og2) {
    int i = blockIdx.x * 256 + threadIdx.x;
    int n = i >> 7, d = i & 127;
    int rs = n & 2047, b = n >> 11;
    int nch = rs / 512 + 1;
    float ms = -1e30f;
    for (int c = 0; c < nch; c++)
        ms = fmaxf(ms, ml[(((size_t)b * 4 + c) * Tt + rs) * 2]);
    float num = 0.f, den = 0.f;
    for (int c = 0; c < nch; c++) {
        size_t rbase = ((size_t)b * 4 + c) * Tt + rs;
        float mi = ml[rbase * 2], li = ml[rbase * 2 + 1];
        float w = __expf(mi - ms);
        num += w * Op[rbase * 128 + d];
        den += w * li;
    }
    float o = num / den;
    ob[(size_t)n * 128 + d] = o;
    int m = onmaskv[n];
    if (!m) m = 1;
    int e0 = __ffs(m) - 1;
    int m2 = m & (m - 1);
    float w0 = rw[(size_t)n * 16 + e0];
    float w1 = m2 ? rw[(size_t)n * 16 + (__ffs(m2) - 1)] : 0.f;
    og2[(size_t)n * 256 + d] = f2bf(w0 * o);
    og2[(size_t)n * 256 + 128 + d] = f2bf(w1 * o);
}

// ---------------- pair-bucket output GEMM, XCD swizzle over bn tiles ----------------
__global__ __launch_bounds__(256) void gemm_pair(
    const unsigned short* __restrict__ og2,
    const unsigned short* __restrict__ woT,
    const int* __restrict__ ptok, const int4* __restrict__ tiledesc,
    const int* __restrict__ ntile_dev,
    float* __restrict__ out) {
    const int L = blockIdx.x;
    const int r = L & 7, s = L >> 3;
    const int bnidx = s & 15, tq = s >> 4;
    const int tile = tq * 8 + r;
    if (tile >= *ntile_dev) return;
    const int4 td = tiledesc[tile];
    const int ei = td.x >> 4, ej = td.x & 15;
    const int mstart = td.y, mcnt = td.z;
    const int bn = bnidx * 128;
    __shared__ alignas(16) unsigned short As[128 * 64];
    __shared__ alignas(16) unsigned short Bs[128 * 64];
    __shared__ int toks[128];
    const int tid = threadIdx.x;
    if (tid < 128) toks[tid] = ptok[mstart + min(tid, mcnt - 1)];
    const int wave = tid >> 6, lane = tid & 63;
    const int lr = lane & 15, lg = lane >> 4;
    const int wr = (wave >> 1) * 64, wc = (wave & 1) * 64;
    f32x4 acc[4][4] = {};

#pragma unroll
    for (int ck = 0; ck < 4; ck++) {
        const int ebase = (ck < 2 ? ei : ej) * 128 + (ck & 1) * 64;
        const int abase = ck * 64;
        __syncthreads();
#pragma unroll
        for (int q = 0; q < 4; q++) {
            int t = q * 256 + tid;
            int row = t >> 3;
            int kc = (t & 7) << 3;
            __builtin_amdgcn_global_load_lds(
                (const __attribute__((address_space(1))) void*)(og2 + (size_t)toks[row] * 256 + abase + kc),
                (__attribute__((address_space(3))) void*)(As + (q * 4 + wave) * 512),
                16, 0, 0);
        }
#pragma unroll
        for (int q = 0; q < 4; q++) {
            int t = q * 256 + tid;
            int row = t >> 3;
            int kc = (t & 7) << 3;
            __builtin_amdgcn_global_load_lds(
                (const __attribute__((address_space(1))) void*)(woT + (size_t)(bn + row) * 2048 + ebase + kc),
                (__attribute__((address_space(3))) void*)(Bs + (q * 4 + wave) * 512),
                16, 0, 0);
        }
        __syncthreads();
#pragma unroll
        for (int kk = 0; kk < 2; kk++) {
            bf16x8 a[4], b[4];
#pragma unroll
            for (int m = 0; m < 4; m++)
                a[m] = *(const bf16x8*)(As + (wr + m * 16 + lr) * 64 + kk * 32 + lg * 8);
#pragma unroll
            for (int n = 0; n < 4; n++)
                b[n] = *(const bf16x8*)(Bs + (wc + n * 16 + lr) * 64 + kk * 32 + lg * 8);
#pragma unroll
            for (int m = 0; m < 4; m++)
#pragma unroll
                for (int n = 0; n < 4; n++)
                    acc[m][n] = __builtin_amdgcn_mfma_f32_16x16x32_bf16(a[m], b[n], acc[m][n], 0, 0, 0);
        }
    }
#pragma unroll
    for (int m = 0; m < 4; m++)
#pragma unroll
        for (int n = 0; n < 4; n++)
#pragma unroll
            for (int rr2 = 0; rr2 < 4; rr2++) {
                int rowt = wr + m * 16 + lg * 4 + rr2;
                if (rowt < mcnt) {
                    int tok = toks[rowt];
                    out[(size_t)tok * 2048 + bn + wc + n * 16 + lr] = acc[m][n][rr2];
                }
            }
}

// ---------------- rare overflow path ----------------
__global__ __launch_bounds__(256) void overflow_kernel(
    const int* __restrict__ ocnt, const int* __restrict__ olist,
    const float* __restrict__ ob, const unsigned short* __restrict__ woT,
    const float* __restrict__ rw, float* __restrict__ out) {
    const int ne = *ocnt;
    __shared__ float osh[128];
    for (int it = blockIdx.x; it < ne; it += gridDim.x) {
        int n = olist[2 * it], e = olist[2 * it + 1];
        float wgt = rw[(size_t)n * 16 + e];
        if (threadIdx.x < 128) osh[threadIdx.x] = ob[(size_t)n * Dd + threadIdx.x];
        __syncthreads();
#pragma unroll 1
        for (int cc = 0; cc < 8; cc++) {
            int c = threadIdx.x * 8 + cc;
            float a = 0.f;
            for (int k = 0; k < 128; k++)
                a += osh[k] * bf2f(woT[(size_t)c * 2048 + e * 128 + k]);
            atomicAdd(&out[(size_t)n * 2048 + c], wgt * a);
        }
        __syncthreads();
    }
}

extern "C" void kernel_launch(void* const* d_in, const int* in_sizes, int n_in,
                              void* d_out, int out_size, void* d_ws, size_t ws_size,
                              hipStream_t stream) {
    (void)in_sizes; (void)n_in; (void)out_size; (void)ws_size;
    const float* hidden = (const float*)d_in[0];
    const float* sim = (const float*)d_in[1];
    const float* gates = (const float*)d_in[2];
    const float* qp = (const float*)d_in[3];
    const float* kp = (const float*)d_in[4];
    const float* vp = (const float*)d_in[5];
    const float* op = (const float*)d_in[6];
    const int* minex = (const int*)d_in[7];
    float* out = (float*)d_out;

    char* w = (char*)d_ws;
    size_t off = 0;
    auto alloc = [&](size_t bytes) -> char* {
        char* p = w + off;
        off = (off + bytes + 255) & ~(size_t)255;
        return p;
    };
    unsigned short* xb = (unsigned short*)alloc((size_t)Nn * Cch * 2);
    unsigned short* wqkvT = (unsigned short*)alloc((size_t)Ee * 384 * Cch * 2);
    unsigned short* woT = (unsigned short*)alloc((size_t)Cch * Ee * Dd * 2);
    float* rw = (float*)alloc((size_t)Nn * Ee * 4);
    int* cnt = (int*)alloc(256);
    int* onmaskv = (int*)alloc((size_t)Nn * 4);
    int* idx = (int*)alloc((size_t)Ee * CAP * 4);
    int* pos = (int*)alloc((size_t)Nn * 16 * 4);
    int* ptok = (int*)alloc((size_t)Nn * 4);
    int4* tiledesc = (int4*)alloc((size_t)MAXTILES * 16);
    int* ntile_dev = (int*)alloc(256);
    int* ocnt = (int*)alloc(256);
    int* olist = (int*)alloc((size_t)Nn * 14 * 2 * 4);
    char* big = alloc((size_t)Bsz * Tt * Tt * 4);  // Pc (15.7MB), later Op partials (16.8MB)
    unsigned short* qb = (unsigned short*)alloc((size_t)Nn * Dd * 2);
    unsigned short* kb = (unsigned short*)alloc((size_t)Nn * Dd * 2);
    unsigned short* vb = (unsigned short*)alloc((size_t)Nn * Dd * 2);
    unsigned short* vT = (unsigned short*)alloc((size_t)Bsz * Dd * Tt * 2);
    float* ob = (float*)alloc((size_t)Nn * Dd * 4);
    unsigned short* og2 = (unsigned short*)alloc((size_t)Nn * 256 * 2);
    float* ml = (float*)alloc((size_t)Bsz * 4 * Tt * 2 * 4);
    unsigned short* Pc = (unsigned short*)big;
    float* Op = (float*)big;

    gating6_kernel<<<Nn / 32, 1024, 0, stream>>>(hidden, sim, gates, minex, rw, xb, onmaskv);
    scan_fused<<<17, 256, 0, stream>>>(onmaskv, idx, pos, cnt, ptok, tiledesc, ntile_dev, ocnt, olist);

    // fused q/k/v weight transpose, then o_proj transpose
    transpose_qkv<<<dim3(Dd / 32, Cch / 32, 48), 256, 0, stream>>>(qp, kp, vp, wqkvT);
    transpose_f32_bf16<<<dim3((Ee * Dd) / 32, Cch / 32, 1), 256, 0, stream>>>(
        op, woT, Ee * Dd, Cch, 0L, 0L);

    // gathered per-expert QKV projection (full-K, expert->XCD swizzle, dbuf), then combine
    gemm_qkv_gather<<<NGRP * 3, 256, 0, stream>>>(xb, wqkvT, idx, cnt, Pc);
    combine_qkv<<<(Nn * 32) / 256, 256, 0, stream>>>(Pc, rw, pos, qb, kb, vb);

    // V transpose per batch
    transpose_u16<<<dim3(Dd / 32, Tt / 32, Bsz), 256, 0, stream>>>(
        vb, vT, Tt, Dd, (long)Tt * Dd, (long)Dd * Tt);

    // flash attention (split-KV) + combine
    flash_kernel<<<dim3(Tt / 128, 4, Bsz), 256, 0, stream>>>(qb, kb, vT, Op, ml);
    flash_combine<<<(Nn * 128) / 256, 256, 0, stream>>>(Op, ml, rw, onmaskv, ob, og2);

    // output projection
    gemm_pair<<<MAXTILES * 16, 256, 0, stream>>>(
        og2, woT, ptok, tiledesc, ntile_dev, out);
    overflow_kernel<<<256, 256, 0, stream>>>(ocnt, olist, ob, woT, rw, out);
}

// Round 17
// 222.163 us; speedup vs baseline: 1.9560x; 1.0638x over previous
//
#include <hip/hip_runtime.h>
#include <hip/hip_bf16.h>

#define DEV __device__ __forceinline__

typedef short bf16x8 __attribute__((ext_vector_type(8)));
typedef float f32x4 __attribute__((ext_vector_type(4)));
typedef unsigned short u16x4 __attribute__((ext_vector_type(4)));

static constexpr int Bsz = 4, Tt = 2048, Cch = 2048, Dd = 128, Ee = 16;
static constexpr int Nn = Bsz * Tt;
static constexpr int CAP = 1280;
static constexpr int MAXTILES = 320;
static constexpr int MT = CAP / 128;
static constexpr int NGRP = MT * Ee;

DEV unsigned short f2bf(float v) {
    __hip_bfloat16 h = __float2bfloat16(v);
    return __builtin_bit_cast(unsigned short, h);
}
DEV float bf2f(unsigned short u) {
    unsigned int x = ((unsigned int)u) << 16;
    return __builtin_bit_cast(float, x);
}

// ---------------- sim transpose ----------------
__global__ __launch_bounds__(256) void simt_kernel(const float* __restrict__ sim,
                                                   float* __restrict__ simT) {
    int i = blockIdx.x * 256 + threadIdx.x;
    int e = i >> 11, c = i & 2047;
    simT[i] = sim[c * 16 + e];
}

// ---------------- gating: simT in 128 KiB LDS (vector staged); 2-token register tile ----------------
__global__ __launch_bounds__(1024) void gating7_kernel(
    const float* __restrict__ x, const float* __restrict__ simT,
    const float* __restrict__ gates, const int* __restrict__ minex,
    float* __restrict__ rw, unsigned short* __restrict__ xb,
    int* __restrict__ onmaskv) {
    __shared__ f32x4 ssim[8192];
    __shared__ float snv[16];
    const int tid = threadIdx.x;
    const f32x4* stg = (const f32x4*)simT;
#pragma unroll
    for (int i = 0; i < 8; i++) ssim[i * 1024 + tid] = stg[i * 1024 + tid];
    __syncthreads();
    const int wave = tid >> 6, lane = tid & 63;

    // wave w computes expert w's column norm from LDS
    {
        float s = 0.f;
#pragma unroll
        for (int it = 0; it < 8; it++) {
            const f32x4 v = ssim[wave * 512 + it * 64 + lane];
            s += v[0] * v[0] + v[1] * v[1] + v[2] * v[2] + v[3] * v[3];
        }
#pragma unroll
        for (int off = 32; off; off >>= 1) s += __shfl_down(s, off);
        if (lane == 0) snv[wave] = 1.f / fmaxf(sqrtf(s), 1e-12f);
    }
    __syncthreads();

    const int n0 = blockIdx.x * 32 + wave * 2;  // 2 tokens per wave
    const f32x4* xr0 = (const f32x4*)(x + (size_t)n0 * Cch);
    const f32x4* xr1 = (const f32x4*)(x + (size_t)(n0 + 1) * Cch);
    u16x4* xb0 = (u16x4*)(xb + (size_t)n0 * Cch);
    u16x4* xb1 = (u16x4*)(xb + (size_t)(n0 + 1) * Cch);
    float ss[2] = {0.f, 0.f};
    float d[2][16];
#pragma unroll
    for (int t = 0; t < 2; t++)
#pragma unroll
        for (int e = 0; e < 16; e++) d[t][e] = 0.f;

#pragma unroll 2
    for (int it = 0; it < 8; it++) {
        const int i = it * 64 + lane;
        const f32x4 xv0 = xr0[i];
        const f32x4 xv1 = xr1[i];
        ss[0] += xv0[0] * xv0[0] + xv0[1] * xv0[1] + xv0[2] * xv0[2] + xv0[3] * xv0[3];
        ss[1] += xv1[0] * xv1[0] + xv1[1] * xv1[1] + xv1[2] * xv1[2] + xv1[3] * xv1[3];
        u16x4 c0 = {f2bf(xv0[0]), f2bf(xv0[1]), f2bf(xv0[2]), f2bf(xv0[3])};
        u16x4 c1 = {f2bf(xv1[0]), f2bf(xv1[1]), f2bf(xv1[2]), f2bf(xv1[3])};
        xb0[i] = c0;
        xb1[i] = c1;
#pragma unroll
        for (int e = 0; e < 16; e++) {
            const f32x4 sv = ssim[e * 512 + i];
            d[0][e] += xv0[0] * sv[0] + xv0[1] * sv[1] + xv0[2] * sv[2] + xv0[3] * sv[3];
            d[1][e] += xv1[0] * sv[0] + xv1[1] * sv[1] + xv1[2] * sv[2] + xv1[3] * sv[3];
        }
    }
#pragma unroll
    for (int off = 32; off; off >>= 1) {
#pragma unroll
        for (int t = 0; t < 2; t++) {
            ss[t] += __shfl_down(ss[t], off);
#pragma unroll
            for (int e = 0; e < 16; e++) d[t][e] += __shfl_down(d[t][e], off);
        }
    }
    if (lane == 0) {
#pragma unroll 1
        for (int t = 0; t < 2; t++) {
            const int n = n0 + t;
            float inv = 1.f / fmaxf(sqrtf(ss[t]), 1e-12f);
            float logit[16];
            int onmask = 0;
#pragma unroll
            for (int e = 0; e < 16; e++) {
                float sg = 1.f / (1.f + __expf(-gates[e]));
                float l = d[t][e] * inv * snv[e] - sg;
                logit[e] = l;
                if (l > 0.f) onmask |= (1 << e);
            }
            if (onmask == 0) {
                int k = *minex;
                int ch = 0;
                for (int kk = 0; kk < k; kk++) {
                    float bv = -1e30f;
                    int be = 0;
#pragma unroll
                    for (int e = 0; e < 16; e++)
                        if (!((ch >> e) & 1) && logit[e] > bv) { bv = logit[e]; be = e; }
                    ch |= (1 << be);
                }
                onmask = ch;
            }
            float mx = -1e30f;
#pragma unroll
            for (int e = 0; e < 16; e++)
                if ((onmask >> e) & 1) mx = fmaxf(mx, fmaxf(logit[e], 0.f));
            float pe[16];
            float sum = 0.f;
#pragma unroll
            for (int e = 0; e < 16; e++) {
                pe[e] = ((onmask >> e) & 1) ? __expf(fmaxf(logit[e], 0.f) - mx) : 0.f;
                sum += pe[e];
            }
            float isum = 1.f / sum;
#pragma unroll
            for (int e = 0; e < 16; e++) rw[(size_t)n * 16 + e] = pe[e] * isum;
            onmaskv[n] = onmask;
        }
    }
}

// ---------------- fused scans: blocks 0-15 = expert lists; block 16 = pair buckets ----------------
__global__ __launch_bounds__(256) void scan_fused(
    const int* __restrict__ onmaskv,
    int* __restrict__ idx, int* __restrict__ pos, int* __restrict__ cnt,
    int* __restrict__ ptok, int4* __restrict__ tiledesc, int* __restrict__ ntile_dev,
    int* __restrict__ ocnt, int* __restrict__ olist) {
    const int tid = threadIdx.x;
    const int lane = tid & 63, w = tid >> 6;
    if (blockIdx.x < 16) {
        const int e = blockIdx.x;
        const int base = tid * 32;
        int om[32];
        int c = 0;
#pragma unroll
        for (int i = 0; i < 32; i++) {
            om[i] = (onmaskv[base + i] >> e) & 1;
            c += om[i];
        }
        int sc = c;
#pragma unroll
        for (int off = 1; off < 64; off <<= 1) {
            int t = __shfl_up(sc, off);
            if (lane >= off) sc += t;
        }
        __shared__ int wsum[4];
        if (lane == 63) wsum[w] = sc;
        __syncthreads();
        int wbase = 0;
        for (int i = 0; i < w; i++) wbase += wsum[i];
        int slot = wbase + sc - c;
#pragma unroll
        for (int i = 0; i < 32; i++) {
            int n = base + i;
            int p = -1;
            if (om[i]) {
                if (slot < CAP) {
                    idx[(size_t)e * CAP + slot] = n;
                    p = slot;
                }
                slot++;
            }
            pos[(size_t)n * 16 + e] = p;
        }
        if (tid == 255) cnt[e] = slot;
        return;
    }
    __shared__ int hist[256], cursor[256];
    __shared__ int wsA[4], wsB[4];
    if (tid == 0) *ocnt = 0;
    hist[tid] = 0;
    __syncthreads();
    for (int i = 0; i < 32; i++) {
        int n = tid * 32 + i;
        int m = onmaskv[n];
        if (!m) m = 1;
        int e0 = __ffs(m) - 1;
        int m2 = m & (m - 1);
        int e1 = m2 ? (__ffs(m2) - 1) : e0;
        atomicAdd(&hist[e0 * 16 + e1], 1);
        int mrest = m2 & (m2 - 1);
        while (mrest) {
            int e = __ffs(mrest) - 1;
            int s = atomicAdd(ocnt, 1);
            olist[2 * s] = n;
            olist[2 * s + 1] = e;
            mrest &= (mrest - 1);
        }
    }
    __syncthreads();
    int v = hist[tid];
    int s = v;
#pragma unroll
    for (int off = 1; off < 64; off <<= 1) {
        int t = __shfl_up(s, off);
        if (lane >= off) s += t;
    }
    if (lane == 63) wsA[w] = s;
    __syncthreads();
    int add = 0;
    for (int i = 0; i < w; i++) add += wsA[i];
    int excl = s + add - v;
    cursor[tid] = excl;
    int nt = (v + 127) >> 7;
    int s2 = nt;
#pragma unroll
    for (int off = 1; off < 64; off <<= 1) {
        int t = __shfl_up(s2, off);
        if (lane >= off) s2 += t;
    }
    if (lane == 63) wsB[w] = s2;
    __syncthreads();
    int add2 = 0;
    for (int i = 0; i < w; i++) add2 += wsB[i];
    int texcl = s2 + add2 - nt;
    for (int m = 0; m < nt; m++)
        tiledesc[texcl + m] = make_int4(tid, excl + m * 128, min(128, v - m * 128), 0);
    if (tid == 255) *ntile_dev = texcl + nt;
    __syncthreads();
    for (int i = 0; i < 32; i++) {
        int n = tid * 32 + i;
        int m = onmaskv[n];
        if (!m) m = 1;
        int e0 = __ffs(m) - 1;
        int m2 = m & (m - 1);
        int e1 = m2 ? (__ffs(m2) - 1) : e0;
        int slot = atomicAdd(&cursor[e0 * 16 + e1], 1);
        ptok[slot] = n;
    }
}

// ---------------- fused q/k/v weight transpose ----------------
__global__ __launch_bounds__(256) void transpose_qkv(
    const float* __restrict__ qp, const float* __restrict__ kp,
    const float* __restrict__ vp, unsigned short* __restrict__ wqkvT) {
    const int z = blockIdx.z;
    const int t3 = z >> 4, e = z & 15;
    const float* src = (t3 == 0 ? qp : (t3 == 1 ? kp : vp)) + (size_t)e * Cch * Dd;
    unsigned short* dst = wqkvT + (size_t)e * 384 * Cch + (size_t)t3 * Dd * Cch;
    __shared__ float tile[32][33];
    int bx = blockIdx.x * 32, by = blockIdx.y * 32;
    int tx = threadIdx.x & 31, ty = threadIdx.x >> 5;
#pragma unroll
    for (int i = 0; i < 4; i++)
        tile[ty + i * 8][tx] = src[(size_t)(by + ty + i * 8) * Dd + bx + tx];
    __syncthreads();
#pragma unroll
    for (int i = 0; i < 4; i++)
        dst[(size_t)(bx + ty + i * 8) * Cch + by + tx] = f2bf(tile[tx][ty + i * 8]);
}

__global__ __launch_bounds__(256) void transpose_f32_bf16(
    const float* __restrict__ src, unsigned short* __restrict__ dst,
    int R, int Ccol, long ss, long ds) {
    __shared__ float tile[32][33];
    src += (size_t)blockIdx.z * ss;
    dst += (size_t)blockIdx.z * ds;
    int bx = blockIdx.x * 32, by = blockIdx.y * 32;
    int tx = threadIdx.x & 31, ty = threadIdx.x >> 5;
#pragma unroll
    for (int i = 0; i < 4; i++)
        tile[ty + i * 8][tx] = src[(size_t)(by + ty + i * 8) * Ccol + bx + tx];
    __syncthreads();
#pragma unroll
    for (int i = 0; i < 4; i++)
        dst[(size_t)(bx + ty + i * 8) * R + by + tx] = f2bf(tile[tx][ty + i * 8]);
}

__global__ __launch_bounds__(256) void transpose_u16(
    const unsigned short* __restrict__ src, unsigned short* __restrict__ dst,
    int R, int Ccol, long ss, long ds) {
    __shared__ unsigned short tile[32][33];
    src += (size_t)blockIdx.z * ss;
    dst += (size_t)blockIdx.z * ds;
    int bx = blockIdx.x * 32, by = blockIdx.y * 32;
    int tx = threadIdx.x & 31, ty = threadIdx.x >> 5;
#pragma unroll
    for (int i = 0; i < 4; i++)
        tile[ty + i * 8][tx] = src[(size_t)(by + ty + i * 8) * Ccol + bx + tx];
    __syncthreads();
#pragma unroll
    for (int i = 0; i < 4; i++)
        dst[(size_t)(bx + ty + i * 8) * R + by + tx] = tile[tx][ty + i * 8];
}

// ---------------- gathered QKV projection: full-K, expert->XCD swizzle, dbuf, T2 LDS swizzle ----------------
// LDS tiles [128][8 units of 16B]; unit u at row r holds global unit u^(r&7) -> ds_read 2-way conflict (free).
__global__ __launch_bounds__(256) void gemm_qkv_gather(
    const unsigned short* __restrict__ X, const unsigned short* __restrict__ W,
    const int* __restrict__ idx, const int* __restrict__ cnt,
    unsigned short* __restrict__ P) {
    const int L = blockIdx.x;
    const int r = L & 7, i5 = L >> 3;
    const int e = r * 2 + (i5 / 30);
    const int rem = i5 % 30;
    const int m = rem % MT;
    const int j = rem / MT;
    const int cn = min(cnt[e], CAP);
    const int bm = m * 128;
    if (bm >= cn) return;
    const int bn = j * 128;
    __shared__ alignas(16) unsigned short As[2 * 128 * 64];
    __shared__ alignas(16) unsigned short Bs[2 * 128 * 64];
    __shared__ int toks[128];
    const int tid = threadIdx.x;
    if (tid < 128) toks[tid] = idx[(size_t)e * CAP + min(bm + tid, cn - 1)];
    const unsigned short* Wb = W + ((size_t)e * 384 + bn) * Cch;
    const int wave = tid >> 6, lane = tid & 63;
    const int lr = lane & 15, lg = lane >> 4;
    const int wr = (wave >> 1) * 64, wc = (wave & 1) * 64;
    f32x4 acc[4][4] = {};

    auto stage = [&](int buf, int k0) {
#pragma unroll
        for (int i = 0; i < 4; i++) {
            int t = i * 256 + tid;
            int row = t >> 3;
            int sc = (t & 7) ^ (row & 7);   // pre-swizzled source unit
            __builtin_amdgcn_global_load_lds(
                (const __attribute__((address_space(1))) void*)(X + (size_t)toks[row] * Cch + k0 + sc * 8),
                (__attribute__((address_space(3))) void*)(As + buf * 8192 + (i * 4 + wave) * 512),
                16, 0, 0);
        }
#pragma unroll
        for (int i = 0; i < 4; i++) {
            int t = i * 256 + tid;
            int row = t >> 3;
            int sc = (t & 7) ^ (row & 7);
            __builtin_amdgcn_global_load_lds(
                (const __attribute__((address_space(1))) void*)(Wb + (size_t)row * Cch + k0 + sc * 8),
                (__attribute__((address_space(3))) void*)(Bs + buf * 8192 + (i * 4 + wave) * 512),
                16, 0, 0);
        }
    };

    __syncthreads();
    stage(0, 0);
    __syncthreads();
    int cur = 0;
#pragma unroll 1
    for (int t = 0; t < 32; t++) {
        if (t + 1 < 32) stage(cur ^ 1, (t + 1) * 64);
        const unsigned short* Ab = As + cur * 8192;
        const unsigned short* Bb = Bs + cur * 8192;
#pragma unroll
        for (int kk = 0; kk < 2; kk++) {
            bf16x8 a[4], b[4];
#pragma unroll
            for (int m2 = 0; m2 < 4; m2++) {
                int row = wr + m2 * 16 + lr;
                int u = (kk * 4 + lg) ^ (row & 7);
                a[m2] = *(const bf16x8*)(Ab + row * 64 + u * 8);
            }
#pragma unroll
            for (int n = 0; n < 4; n++) {
                int row = wc + n * 16 + lr;
                int u = (kk * 4 + lg) ^ (row & 7);
                b[n] = *(const bf16x8*)(Bb + row * 64 + u * 8);
            }
#pragma unroll
            for (int m2 = 0; m2 < 4; m2++)
#pragma unroll
                for (int n = 0; n < 4; n++)
                    acc[m2][n] = __builtin_amdgcn_mfma_f32_16x16x32_bf16(a[m2], b[n], acc[m2][n], 0, 0, 0);
        }
        __syncthreads();
        cur ^= 1;
    }
#pragma unroll
    for (int m2 = 0; m2 < 4; m2++)
#pragma unroll
        for (int n = 0; n < 4; n++)
#pragma unroll
            for (int rr = 0; rr < 4; rr++) {
                int slot = bm + wr + m2 * 16 + lg * 4 + rr;
                int col = bn + wc + n * 16 + lr;
                if (slot < cn)
                    P[((size_t)e * CAP + slot) * 384 + col] = f2bf(acc[m2][n][rr]);
            }
}

// ---------------- combine q/k/v ----------------
__global__ __launch_bounds__(256) void combine_qkv(
    const unsigned short* __restrict__ P, const float* __restrict__ rw,
    const int* __restrict__ pos,
    unsigned short* __restrict__ qb, unsigned short* __restrict__ kb,
    unsigned short* __restrict__ vb) {
    int i = blockIdx.x * 256 + threadIdx.x;
    int n = i >> 5;
    int d4 = (i & 31) << 2;
    float aq[4] = {}, ak[4] = {}, av[4] = {};
#pragma unroll
    for (int e = 0; e < 16; e++) {
        int p = pos[(size_t)n * 16 + e];
        if (p >= 0) {
            float w = rw[(size_t)n * 16 + e];
            const unsigned short* rh = P + ((size_t)e * CAP + p) * 384 + d4;
            const u16x4 q4 = *(const u16x4*)(rh);
            const u16x4 k4 = *(const u16x4*)(rh + 128);
            const u16x4 v4 = *(const u16x4*)(rh + 256);
#pragma unroll
            for (int jj = 0; jj < 4; jj++) {
                aq[jj] += w * bf2f(q4[jj]);
                ak[jj] += w * bf2f(k4[jj]);
                av[jj] += w * bf2f(v4[jj]);
            }
        }
    }
    u16x4 sq = {f2bf(aq[0]), f2bf(aq[1]), f2bf(aq[2]), f2bf(aq[3])};
    u16x4 sk = {f2bf(ak[0]), f2bf(ak[1]), f2bf(ak[2]), f2bf(ak[3])};
    u16x4 sv = {f2bf(av[0]), f2bf(av[1]), f2bf(av[2]), f2bf(av[3])};
    *(u16x4*)(qb + (size_t)n * Dd + d4) = sq;
    *(u16x4*)(kb + (size_t)n * Dd + d4) = sk;
    *(u16x4*)(vb + (size_t)n * Dd + d4) = sv;
}

// ---------------- flash attention, split-KV ----------------
__global__ __launch_bounds__(256) void flash_kernel(
    const unsigned short* __restrict__ qb, const unsigned short* __restrict__ kb,
    const unsigned short* __restrict__ vT,
    float* __restrict__ Op, float* __restrict__ ml) {
    const int qt = blockIdx.x, ch = blockIdx.y, b = blockIdx.z;
    const int q0 = qt * 128, kv0 = ch * 512;
    if (kv0 > q0 + 127) return;
    __shared__ alignas(16) unsigned short Qs[128 * 128];
    __shared__ alignas(16) unsigned short Ks[64 * 128];
    __shared__ alignas(16) unsigned short Vs[128 * 64];
    __shared__ alignas(16) unsigned short Ps[4][32 * 64];
    const int tid = threadIdx.x;
    const int wave = tid >> 6, lane = tid & 63;
    const int lr = lane & 15, lg = lane >> 4;
    const float scale = 0.08838834764831845f;
    const unsigned short* Qg = qb + ((size_t)b * Tt + q0) * 128;
    const unsigned short* Kg = kb + (size_t)b * Tt * 128;
    const unsigned short* Vg = vT + (size_t)b * 128 * Tt;

#pragma unroll
    for (int i = 0; i < 8; i++) {
        int dof = (i * 256 + tid) << 4;
        int row = dof >> 8;
        int c16 = (dof >> 4) & 15;
        int s16 = c16 ^ (row & 7);
        __builtin_amdgcn_global_load_lds(
            (const __attribute__((address_space(1))) void*)(Qg + (size_t)row * 128 + s16 * 8),
            (__attribute__((address_space(3))) void*)(Qs + (size_t)(i * 4 + wave) * 512),
            16, 0, 0);
    }

    f32x4 acc_o[2][8] = {};
    float rm[2][4], rl[2][4];
#pragma unroll
    for (int mf = 0; mf < 2; mf++)
#pragma unroll
        for (int rg = 0; rg < 4; rg++) { rm[mf][rg] = -1e30f; rl[mf][rg] = 0.f; }

    const int ktend = min(kv0 + 512, q0 + 128);
    for (int kt = kv0; kt < ktend; kt += 64) {
        if (kt > kv0) __syncthreads();
#pragma unroll
        for (int i = 0; i < 4; i++) {
            int dof = (i * 256 + tid) << 4;
            int row = dof >> 8;
            int c16 = (dof >> 4) & 15;
            int s16 = c16 ^ (row & 7);
            __builtin_amdgcn_global_load_lds(
                (const __attribute__((address_space(1))) void*)(Kg + (size_t)(kt + row) * 128 + s16 * 8),
                (__attribute__((address_space(3))) void*)(Ks + (size_t)(i * 4 + wave) * 512),
                16, 0, 0);
        }
#pragma unroll
        for (int i = 0; i < 4; i++) {
            int dof = (i * 256 + tid) << 4;
            int row = dof >> 7;
            int c16 = (dof >> 4) & 7;
            int s16 = c16 ^ (row & 7);
            __builtin_amdgcn_global_load_lds(
                (const __attribute__((address_space(1))) void*)(Vg + (size_t)row * Tt + kt + s16 * 8),
                (__attribute__((address_space(3))) void*)(Vs + (size_t)(i * 4 + wave) * 512),
                16, 0, 0);
        }
        __syncthreads();

        f32x4 acc_s[2][4] = {};
#pragma unroll
        for (int kk = 0; kk < 4; kk++) {
            bf16x8 a[2], bfr[4];
#pragma unroll
            for (int mf = 0; mf < 2; mf++) {
                int row = wave * 32 + mf * 16 + lr;
                int c16 = (kk * 4 + lg) ^ (row & 7);
                a[mf] = *(const bf16x8*)(Qs + row * 128 + c16 * 8);
            }
#pragma unroll
            for (int nf = 0; nf < 4; nf++) {
                int row = nf * 16 + lr;
                int c16 = (kk * 4 + lg) ^ (row & 7);
                bfr[nf] = *(const bf16x8*)(Ks + row * 128 + c16 * 8);
            }
#pragma unroll
            for (int mf = 0; mf < 2; mf++)
#pragma unroll
                for (int nf = 0; nf < 4; nf++)
                    acc_s[mf][nf] = __builtin_amdgcn_mfma_f32_16x16x32_bf16(a[mf], bfr[nf], acc_s[mf][nf], 0, 0, 0);
        }

#pragma unroll
        for (int mf = 0; mf < 2; mf++) {
            float sv[4][4], pmax[4];
#pragma unroll
            for (int rg = 0; rg < 4; rg++) pmax[rg] = -1e30f;
#pragma unroll
            for (int nf = 0; nf < 4; nf++) {
                int colg = kt + nf * 16 + lr;
#pragma unroll
                for (int rg = 0; rg < 4; rg++) {
                    int rowg = q0 + wave * 32 + mf * 16 + lg * 4 + rg;
                    float s = acc_s[mf][nf][rg] * scale;
                    if (colg > rowg) s = -1e30f;
                    sv[nf][rg] = s;
                    pmax[rg] = fmaxf(pmax[rg], s);
                }
            }
#pragma unroll
            for (int rg = 0; rg < 4; rg++) {
#pragma unroll
                for (int off = 1; off < 16; off <<= 1)
                    pmax[rg] = fmaxf(pmax[rg], __shfl_xor(pmax[rg], off));
                float mnew = fmaxf(rm[mf][rg], pmax[rg]);
                float f = __expf(rm[mf][rg] - mnew);
                rm[mf][rg] = mnew;
#pragma unroll
                for (int nd = 0; nd < 8; nd++) acc_o[mf][nd][rg] *= f;
                float rsum = 0.f;
#pragma unroll
                for (int nf = 0; nf < 4; nf++) {
                    float p = __expf(sv[nf][rg] - mnew);
                    sv[nf][rg] = p;
                    rsum += p;
                }
#pragma unroll
                for (int off = 1; off < 16; off <<= 1) rsum += __shfl_xor(rsum, off);
                rl[mf][rg] = rl[mf][rg] * f + rsum;
                int rloc = mf * 16 + lg * 4 + rg;
#pragma unroll
                for (int nf = 0; nf < 4; nf++) {
                    int col = nf * 16 + lr;
                    int unit = (col >> 3) ^ (rloc & 7);
                    Ps[wave][rloc * 64 + unit * 8 + (col & 7)] = f2bf(sv[nf][rg]);
                }
            }
        }

#pragma unroll
        for (int kk2 = 0; kk2 < 2; kk2++) {
            bf16x8 a[2], bfr[8];
#pragma unroll
            for (int mf = 0; mf < 2; mf++) {
                int row = mf * 16 + lr;
                int c16 = (kk2 * 4 + lg) ^ (row & 7);
                a[mf] = *(const bf16x8*)(&Ps[wave][row * 64 + c16 * 8]);
            }
#pragma unroll
            for (int nd = 0; nd < 8; nd++) {
                int row = nd * 16 + lr;
                int c16 = ((kk2 * 4 + lg) ^ (row & 7)) & 7;
                bfr[nd] = *(const bf16x8*)(Vs + row * 64 + c16 * 8);
            }
#pragma unroll
            for (int mf = 0; mf < 2; mf++)
#pragma unroll
                for (int nd = 0; nd < 8; nd++)
                    acc_o[mf][nd] = __builtin_amdgcn_mfma_f32_16x16x32_bf16(a[mf], bfr[nd], acc_o[mf][nd], 0, 0, 0);
        }
    }

    float* Opb = Op + (((size_t)b * 4 + ch) * Tt) * 128;
    float* mlb = ml + (((size_t)b * 4 + ch) * Tt) * 2;
#pragma unroll
    for (int mf = 0; mf < 2; mf++)
#pragma unroll
        for (int rg = 0; rg < 4; rg++) {
            int rowl = q0 + wave * 32 + mf * 16 + lg * 4 + rg;
#pragma unroll
            for (int nd = 0; nd < 8; nd++)
                Opb[(size_t)rowl * 128 + nd * 16 + lr] = acc_o[mf][nd][rg];
            if (lr == 0) {
                mlb[rowl * 2] = rm[mf][rg];
                mlb[rowl * 2 + 1] = rl[mf][rg];
            }
        }
}

// ---------------- flash combine ----------------
__global__ __launch_bounds__(256) void flash_combine(
    const float* __restrict__ Op, const float* __restrict__ ml,
    const float* __restrict__ rw, const int* __restrict__ onmaskv,
    float* __restrict__ ob, unsigned short* __restrict__ og2) {
    int i = blockIdx.x * 256 + threadIdx.x;
    int n = i >> 7, d = i & 127;
    int rs = n & 2047, b = n >> 11;
    int nch = rs / 512 + 1;
    float ms = -1e30f;
    for (int c = 0; c < nch; c++)
        ms = fmaxf(ms, ml[(((size_t)b * 4 + c) * Tt + rs) * 2]);
    float num = 0.f, den = 0.f;
    for (int c = 0; c < nch; c++) {
        size_t rbase = ((size_t)b * 4 + c) * Tt + rs;
        float mi = ml[rbase * 2], li = ml[rbase * 2 + 1];
        float w = __expf(mi - ms);
        num += w * Op[rbase * 128 + d];
        den += w * li;
    }
    float o = num / den;
    ob[(size_t)n * 128 + d] = o;
    int m = onmaskv[n];
    if (!m) m = 1;
    int e0 = __ffs(m) - 1;
    int m2 = m & (m - 1);
    float w0 = rw[(size_t)n * 16 + e0];
    float w1 = m2 ? rw[(size_t)n * 16 + (__ffs(m2) - 1)] : 0.f;
    og2[(size_t)n * 256 + d] = f2bf(w0 * o);
    og2[(size_t)n * 256 + 128 + d] = f2bf(w1 * o);
}

// ---------------- pair-bucket output GEMM, XCD swizzle + T2 LDS swizzle ----------------
__global__ __launch_bounds__(256) void gemm_pair(
    const unsigned short* __restrict__ og2,
    const unsigned short* __restrict__ woT,
    const int* __restrict__ ptok, const int4* __restrict__ tiledesc,
    const int* __restrict__ ntile_dev,
    float* __restrict__ out) {
    const int L = blockIdx.x;
    const int r = L & 7, s = L >> 3;
    const int bnidx = s & 15, tq = s >> 4;
    const int tile = tq * 8 + r;
    if (tile >= *ntile_dev) return;
    const int4 td = tiledesc[tile];
    const int ei = td.x >> 4, ej = td.x & 15;
    const int mstart = td.y, mcnt = td.z;
    const int bn = bnidx * 128;
    __shared__ alignas(16) unsigned short As[128 * 64];
    __shared__ alignas(16) unsigned short Bs[128 * 64];
    __shared__ int toks[128];
    const int tid = threadIdx.x;
    if (tid < 128) toks[tid] = ptok[mstart + min(tid, mcnt - 1)];
    const int wave = tid >> 6, lane = tid & 63;
    const int lr = lane & 15, lg = lane >> 4;
    const int wr = (wave >> 1) * 64, wc = (wave & 1) * 64;
    f32x4 acc[4][4] = {};

#pragma unroll
    for (int ck = 0; ck < 4; ck++) {
        const int ebase = (ck < 2 ? ei : ej) * 128 + (ck & 1) * 64;
        const int abase = ck * 64;
        __syncthreads();
#pragma unroll
        for (int q = 0; q < 4; q++) {
            int t = q * 256 + tid;
            int row = t >> 3;
            int sc = (t & 7) ^ (row & 7);
            __builtin_amdgcn_global_load_lds(
                (const __attribute__((address_space(1))) void*)(og2 + (size_t)toks[row] * 256 + abase + sc * 8),
                (__attribute__((address_space(3))) void*)(As + (q * 4 + wave) * 512),
                16, 0, 0);
        }
#pragma unroll
        for (int q = 0; q < 4; q++) {
            int t = q * 256 + tid;
            int row = t >> 3;
            int sc = (t & 7) ^ (row & 7);
            __builtin_amdgcn_global_load_lds(
                (const __attribute__((address_space(1))) void*)(woT + (size_t)(bn + row) * 2048 + ebase + sc * 8),
                (__attribute__((address_space(3))) void*)(Bs + (q * 4 + wave) * 512),
                16, 0, 0);
        }
        __syncthreads();
#pragma unroll
        for (int kk = 0; kk < 2; kk++) {
            bf16x8 a[4], b[4];
#pragma unroll
            for (int m = 0; m < 4; m++) {
                int row = wr + m * 16 + lr;
                int u = (kk * 4 + lg) ^ (row & 7);
                a[m] = *(const bf16x8*)(As + row * 64 + u * 8);
            }
#pragma unroll
            for (int n = 0; n < 4; n++) {
                int row = wc + n * 16 + lr;
                int u = (kk * 4 + lg) ^ (row & 7);
                b[n] = *(const bf16x8*)(Bs + row * 64 + u * 8);
            }
#pragma unroll
            for (int m = 0; m < 4; m++)
#pragma unroll
                for (int n = 0; n < 4; n++)
                    acc[m][n] = __builtin_amdgcn_mfma_f32_16x16x32_bf16(a[m], b[n], acc[m][n], 0, 0, 0);
        }
    }
#pragma unroll
    for (int m = 0; m < 4; m++)
#pragma unroll
        for (int n = 0; n < 4; n++)
#pragma unroll
            for (int rr2 = 0; rr2 < 4; rr2++) {
                int rowt = wr + m * 16 + lg * 4 + rr2;
                if (rowt < mcnt) {
                    int tok = toks[rowt];
                    out[(size_t)tok * 2048 + bn + wc + n * 16 + lr] = acc[m][n][rr2];
                }
            }
}

// ---------------- rare overflow path ----------------
__global__ __launch_bounds__(256) void overflow_kernel(
    const int* __restrict__ ocnt, const int* __restrict__ olist,
    const float* __restrict__ ob, const unsigned short* __restrict__ woT,
    const float* __restrict__ rw, float* __restrict__ out) {
    const int ne = *ocnt;
    __shared__ float osh[128];
    for (int it = blockIdx.x; it < ne; it += gridDim.x) {
        int n = olist[2 * it], e = olist[2 * it + 1];
        float wgt = rw[(size_t)n * 16 + e];
        if (threadIdx.x < 128) osh[threadIdx.x] = ob[(size_t)n * Dd + threadIdx.x];
        __syncthreads();
#pragma unroll 1
        for (int cc = 0; cc < 8; cc++) {
            int c = threadIdx.x * 8 + cc;
            float a = 0.f;
            for (int k = 0; k < 128; k++)
                a += osh[k] * bf2f(woT[(size_t)c * 2048 + e * 128 + k]);
            atomicAdd(&out[(size_t)n * 2048 + c], wgt * a);
        }
        __syncthreads();
    }
}

extern "C" void kernel_launch(void* const* d_in, const int* in_sizes, int n_in,
                              void* d_out, int out_size, void* d_ws, size_t ws_size,
                              hipStream_t stream) {
    (void)in_sizes; (void)n_in; (void)out_size; (void)ws_size;
    const float* hidden = (const float*)d_in[0];
    const float* sim = (const float*)d_in[1];
    const float* gates = (const float*)d_in[2];
    const float* qp = (const float*)d_in[3];
    const float* kp = (const float*)d_in[4];
    const float* vp = (const float*)d_in[5];
    const float* op = (const float*)d_in[6];
    const int* minex = (const int*)d_in[7];
    float* out = (float*)d_out;

    char* w = (char*)d_ws;
    size_t off = 0;
    auto alloc = [&](size_t bytes) -> char* {
        char* p = w + off;
        off = (off + bytes + 255) & ~(size_t)255;
        return p;
    };
    unsigned short* xb = (unsigned short*)alloc((size_t)Nn * Cch * 2);
    unsigned short* wqkvT = (unsigned short*)alloc((size_t)Ee * 384 * Cch * 2);
    unsigned short* woT = (unsigned short*)alloc((size_t)Cch * Ee * Dd * 2);
    float* rw = (float*)alloc((size_t)Nn * Ee * 4);
    float* simT = (float*)alloc((size_t)Ee * Cch * 4);
    int* cnt = (int*)alloc(256);
    int* onmaskv = (int*)alloc((size_t)Nn * 4);
    int* idx = (int*)alloc((size_t)Ee * CAP * 4);
    int* pos = (int*)alloc((size_t)Nn * 16 * 4);
    int* ptok = (int*)alloc((size_t)Nn * 4);
    int4* tiledesc = (int4*)alloc((size_t)MAXTILES * 16);
    int* ntile_dev = (int*)alloc(256);
    int* ocnt = (int*)alloc(256);
    int* olist = (int*)alloc((size_t)Nn * 14 * 2 * 4);
    char* big = alloc((size_t)Bsz * Tt * Tt * 4);
    unsigned short* qb = (unsigned short*)alloc((size_t)Nn * Dd * 2);
    unsigned short* kb = (unsigned short*)alloc((size_t)Nn * Dd * 2);
    unsigned short* vb = (unsigned short*)alloc((size_t)Nn * Dd * 2);
    unsigned short* vT = (unsigned short*)alloc((size_t)Bsz * Dd * Tt * 2);
    float* ob = (float*)alloc((size_t)Nn * Dd * 4);
    unsigned short* og2 = (unsigned short*)alloc((size_t)Nn * 256 * 2);
    float* ml = (float*)alloc((size_t)Bsz * 4 * Tt * 2 * 4);
    unsigned short* Pc = (unsigned short*)big;
    float* Op = (float*)big;

    simt_kernel<<<(Ee * Cch) / 256, 256, 0, stream>>>(sim, simT);
    gating7_kernel<<<Nn / 32, 1024, 0, stream>>>(hidden, simT, gates, minex, rw, xb, onmaskv);
    scan_fused<<<17, 256, 0, stream>>>(onmaskv, idx, pos, cnt, ptok, tiledesc, ntile_dev, ocnt, olist);

    transpose_qkv<<<dim3(Dd / 32, Cch / 32, 48), 256, 0, stream>>>(qp, kp, vp, wqkvT);
    transpose_f32_bf16<<<dim3((Ee * Dd) / 32, Cch / 32, 1), 256, 0, stream>>>(
        op, woT, Ee * Dd, Cch, 0L, 0L);

    gemm_qkv_gather<<<NGRP * 3, 256, 0, stream>>>(xb, wqkvT, idx, cnt, Pc);
    combine_qkv<<<(Nn * 32) / 256, 256, 0, stream>>>(Pc, rw, pos, qb, kb, vb);

    transpose_u16<<<dim3(Dd / 32, Tt / 32, Bsz), 256, 0, stream>>>(
        vb, vT, Tt, Dd, (long)Tt * Dd, (long)Dd * Tt);

    flash_kernel<<<dim3(Tt / 128, 4, Bsz), 256, 0, stream>>>(qb, kb, vT, Op, ml);
    flash_combine<<<(Nn * 128) / 256, 256, 0, stream>>>(Op, ml, rw, onmaskv, ob, og2);

    gemm_pair<<<MAXTILES * 16, 256, 0, stream>>>(
        og2, woT, ptok, tiledesc, ntile_dev, out);
    overflow_kernel<<<256, 256, 0, stream>>>(ocnt, olist, ob, woT, rw, out);
}